// Round 3
// baseline (271.570 us; speedup 1.0000x reference)
//
#include <hip/hip_runtime.h>
#include <math.h>

#define S72 72

typedef __bf16 bf16;
typedef __bf16 bf16x8 __attribute__((ext_vector_type(8)));
typedef __bf16 bf16x4v __attribute__((ext_vector_type(4)));
typedef __bf16 bf16x2v __attribute__((ext_vector_type(2)));
typedef float f32x4 __attribute__((ext_vector_type(4)));

__device__ __forceinline__ float wredsum(float v) {
#pragma unroll
  for (int off = 32; off > 0; off >>= 1) v += __shfl_xor(v, off, 64);
  return v;
}
__device__ __forceinline__ float sigmoidf_(float x) { return 1.f / (1.f + __expf(-x)); }

// swizzled LDS addressing for 64-col planes: row stride 64, 8-elem chunks XOR'd by row&7
__device__ __forceinline__ int sxy(int row, int col) {
  return (row << 6) + ((((col >> 3) ^ (row & 7)) << 3) | (col & 7));
}
__device__ __forceinline__ int sx8(int row, int chunk) {
  return (row << 6) + ((chunk ^ (row & 7)) << 3);
}

// ---------------- fused: RMSNorm + a/b projections  |  weight cast ----------------
__global__ __launch_bounds__(256) void k_pre(const float* __restrict__ h,
    const float* __restrict__ nw, const float* __restrict__ aw,
    const float* __restrict__ bw, const float* __restrict__ dtb,
    const float* __restrict__ alog, bf16* __restrict__ xb,
    float* __restrict__ graw, float* __restrict__ btb,
    const float* __restrict__ qw, const float* __restrict__ kw,
    const float* __restrict__ vw, const float* __restrict__ gw,
    const float* __restrict__ opw, const float* __restrict__ ow,
    bf16* qwb, bf16* kwb, bf16* vwb, bf16* gwb, bf16* opwb, bf16* owb) {
  __shared__ float red[4];
  __shared__ __align__(16) float xs[1024];
  int tid = threadIdx.x;
  if (blockIdx.x >= 2048) {
    // weight cast part (4608 virtual blocks)
    long cb = blockIdx.x - 2048;
    for (long u = cb*256 + tid; u < 2359296; u += 4608l*256) {
      const float* src; bf16* dst; long l;
      if      (u <  262144) { src=qw;  dst=qwb;  l=u; }
      else if (u <  524288) { src=kw;  dst=kwb;  l=u-262144; }
      else if (u < 1048576) { src=vw;  dst=vwb;  l=u-524288; }
      else if (u < 1572864) { src=gw;  dst=gwb;  l=u-1048576; }
      else if (u < 2097152) { src=opw; dst=opwb; l=u-1572864; }
      else                  { src=ow;  dst=owb;  l=u-2097152; }
      float4 s = *(const float4*)(src + l*4);
      bf16x4v b; b[0]=(bf16)s.x; b[1]=(bf16)s.y; b[2]=(bf16)s.z; b[3]=(bf16)s.w;
      *(bf16x4v*)(dst + l*4) = b;
    }
    return;
  }
  int t = blockIdx.x;
  float4 hv = *(const float4*)(h + (size_t)t*1024 + tid*4);
  float ss = hv.x*hv.x + hv.y*hv.y + hv.z*hv.z + hv.w*hv.w;
  float wsum = wredsum(ss);
  if ((tid & 63) == 0) red[tid >> 6] = wsum;
  __syncthreads();
  float tot = red[0] + red[1] + red[2] + red[3];
  float rs = rsqrtf(tot * (1.f/1024.f) + 1e-6f);
  float4 w4 = *(const float4*)(nw + tid*4);
  float4 y;
  y.x = hv.x*rs*w4.x; y.y = hv.y*rs*w4.y; y.z = hv.z*rs*w4.z; y.w = hv.w*rs*w4.w;
  *(float4*)(xs + tid*4) = y;
  bf16x4v b; b[0]=(bf16)y.x; b[1]=(bf16)y.y; b[2]=(bf16)y.z; b[3]=(bf16)y.w;
  *(bf16x4v*)(xb + (size_t)t*1024 + tid*4) = b;
  __syncthreads();
  int wave = tid >> 6, lane = tid & 63;
  const float4* x4 = (const float4*)xs;
#pragma unroll
  for (int hi = 0; hi < 4; ++hi) {
    int hh = wave*4 + hi;
    float sa = 0.f, sb = 0.f;
#pragma unroll
    for (int i = 0; i < 4; ++i) {
      float4 xv = x4[i*64 + lane];
      float4 av = *(const float4*)(aw + hh*1024 + i*256 + lane*4);
      float4 bv = *(const float4*)(bw + hh*1024 + i*256 + lane*4);
      sa += xv.x*av.x + xv.y*av.y + xv.z*av.z + xv.w*av.w;
      sb += xv.x*bv.x + xv.y*bv.y + xv.z*bv.z + xv.w*bv.w;
    }
    sa = wredsum(sa); sb = wredsum(sb);
    if (lane == 0) {
      float ap = sa + dtb[hh];
      float sp = (ap > 20.f) ? ap : log1pf(expf(ap));
      graw[t*16 + hh] = -expf(alog[hh]) * sp;
      btb[t*16 + hh] = 1.f / (1.f + expf(-sb));
    }
  }
}

// ---------------- bf16 MFMA GEMM 128x128 (double-buffered, XOR-swizzled) ----------------
template <typename OutT>
__device__ __forceinline__ void gemm_body(const bf16* __restrict__ A,
    const bf16* __restrict__ B, OutT* __restrict__ C, int N, int K, int m0, int n0) {
  __shared__ bf16 As[2][128*32];
  __shared__ bf16 Bs[2][128*32];
  const int tid = threadIdx.x, lane = tid & 63, wave = tid >> 6;
  const int wm = (wave >> 1) * 64, wn = (wave & 1) * 64;
  const int srow = wave*16 + (lane >> 2);
  const int swl = (((lane & 3) ^ ((lane >> 3) & 3))) * 8;
  const int sdst = (lane & 3) * 8;
  const int quad = lane >> 4, l16 = lane & 15;
  const int sw = (l16 >> 1) & 3;
  f32x4 acc[4][4] = {};
  const int nk = K >> 5;
#pragma unroll
  for (int i = 0; i < 2; ++i) {
    int r = i*64 + srow;
    __builtin_amdgcn_global_load_lds(
      (__attribute__((address_space(1))) void*)(A + (size_t)(m0 + r)*K + swl),
      (__attribute__((address_space(3))) void*)(&As[0][r*32 + sdst]), 16, 0, 0);
    __builtin_amdgcn_global_load_lds(
      (__attribute__((address_space(1))) void*)(B + (size_t)(n0 + r)*K + swl),
      (__attribute__((address_space(3))) void*)(&Bs[0][r*32 + sdst]), 16, 0, 0);
  }
  for (int kt = 0; kt < nk; ++kt) {
    const int cur = kt & 1;
    __syncthreads();
    bf16x8 af[4], bfr[4];
#pragma unroll
    for (int mt = 0; mt < 4; ++mt)
      af[mt] = *(const bf16x8*)(&As[cur][(wm + mt*16 + l16)*32 + (quad ^ sw)*8]);
#pragma unroll
    for (int nt = 0; nt < 4; ++nt)
      bfr[nt] = *(const bf16x8*)(&Bs[cur][(wn + nt*16 + l16)*32 + (quad ^ sw)*8]);
    if (kt + 1 < nk) {
      int k0 = (kt + 1) << 5;
#pragma unroll
      for (int i = 0; i < 2; ++i) {
        int r = i*64 + srow;
        __builtin_amdgcn_global_load_lds(
          (__attribute__((address_space(1))) void*)(A + (size_t)(m0 + r)*K + k0 + swl),
          (__attribute__((address_space(3))) void*)(&As[cur^1][r*32 + sdst]), 16, 0, 0);
        __builtin_amdgcn_global_load_lds(
          (__attribute__((address_space(1))) void*)(B + (size_t)(n0 + r)*K + k0 + swl),
          (__attribute__((address_space(3))) void*)(&Bs[cur^1][r*32 + sdst]), 16, 0, 0);
      }
    }
#pragma unroll
    for (int mt = 0; mt < 4; ++mt)
#pragma unroll
      for (int nt = 0; nt < 4; ++nt)
        acc[mt][nt] = __builtin_amdgcn_mfma_f32_16x16x32_bf16(af[mt], bfr[nt], acc[mt][nt], 0, 0, 0);
  }
#pragma unroll
  for (int mt = 0; mt < 4; ++mt)
#pragma unroll
    for (int nt = 0; nt < 4; ++nt)
#pragma unroll
      for (int r = 0; r < 4; ++r) {
        int row = m0 + wm + mt*16 + quad*4 + r;
        int col = n0 + wn + nt*16 + l16;
        C[(size_t)row*N + col] = (OutT)acc[mt][nt][r];
      }
}

__global__ __launch_bounds__(256) void k_gemm_proj(const bf16* __restrict__ A,
    const bf16* __restrict__ qwb, const bf16* __restrict__ kwb,
    const bf16* __restrict__ vwb, const bf16* __restrict__ gwb,
    bf16* __restrict__ qpre, bf16* __restrict__ kpre,
    bf16* __restrict__ vpre, bf16* __restrict__ gpre) {
  int bx = blockIdx.x;
  const bf16* B; bf16* C; int N, xt;
  if      (bx <  8) { B = qwb; C = qpre; N = 1024; xt = bx; }
  else if (bx < 16) { B = kwb; C = kpre; N = 1024; xt = bx - 8; }
  else if (bx < 32) { B = vwb; C = vpre; N = 2048; xt = bx - 16; }
  else              { B = gwb; C = gpre; N = 2048; xt = bx - 32; }
  gemm_body<bf16>(A, B, C, N, 1024, blockIdx.y*128, xt*128);
}

// ---------------- bf16 MFMA GEMM 128x64 (2x blocks for tail GEMMs) ----------------
template <typename OutT>
__global__ __launch_bounds__(256) void k_gemm_bt64(const bf16* __restrict__ A,
    const bf16* __restrict__ B, OutT* __restrict__ C, int N, int K) {
  __shared__ bf16 As[2][128*32];
  __shared__ bf16 Bs[2][64*32];
  const int tid = threadIdx.x, lane = tid & 63, wave = tid >> 6;
  const int wm = wave * 32;
  const int srow = wave*16 + (lane >> 2);
  const int swl = (((lane & 3) ^ ((lane >> 3) & 3))) * 8;
  const int sdst = (lane & 3) * 8;
  const int quad = lane >> 4, l16 = lane & 15;
  const int sw = (l16 >> 1) & 3;
  const int m0 = blockIdx.y * 128, n0 = blockIdx.x * 64;
  f32x4 acc[2][4] = {};
  const int nk = K >> 5;
#pragma unroll
  for (int i = 0; i < 2; ++i) {
    int r = i*64 + srow;
    __builtin_amdgcn_global_load_lds(
      (__attribute__((address_space(1))) void*)(A + (size_t)(m0 + r)*K + swl),
      (__attribute__((address_space(3))) void*)(&As[0][r*32 + sdst]), 16, 0, 0);
  }
  __builtin_amdgcn_global_load_lds(
    (__attribute__((address_space(1))) void*)(B + (size_t)(n0 + srow)*K + swl),
    (__attribute__((address_space(3))) void*)(&Bs[0][srow*32 + sdst]), 16, 0, 0);
  for (int kt = 0; kt < nk; ++kt) {
    const int cur = kt & 1;
    __syncthreads();
    bf16x8 af[2], bfr[4];
#pragma unroll
    for (int mt = 0; mt < 2; ++mt)
      af[mt] = *(const bf16x8*)(&As[cur][(wm + mt*16 + l16)*32 + (quad ^ sw)*8]);
#pragma unroll
    for (int nt = 0; nt < 4; ++nt)
      bfr[nt] = *(const bf16x8*)(&Bs[cur][(nt*16 + l16)*32 + (quad ^ sw)*8]);
    if (kt + 1 < nk) {
      int k0 = (kt + 1) << 5;
#pragma unroll
      for (int i = 0; i < 2; ++i) {
        int r = i*64 + srow;
        __builtin_amdgcn_global_load_lds(
          (__attribute__((address_space(1))) void*)(A + (size_t)(m0 + r)*K + k0 + swl),
          (__attribute__((address_space(3))) void*)(&As[cur^1][r*32 + sdst]), 16, 0, 0);
      }
      __builtin_amdgcn_global_load_lds(
        (__attribute__((address_space(1))) void*)(B + (size_t)(n0 + srow)*K + k0 + swl),
        (__attribute__((address_space(3))) void*)(&Bs[cur^1][srow*32 + sdst]), 16, 0, 0);
    }
#pragma unroll
    for (int mt = 0; mt < 2; ++mt)
#pragma unroll
      for (int nt = 0; nt < 4; ++nt)
        acc[mt][nt] = __builtin_amdgcn_mfma_f32_16x16x32_bf16(af[mt], bfr[nt], acc[mt][nt], 0, 0, 0);
  }
#pragma unroll
  for (int mt = 0; mt < 2; ++mt)
#pragma unroll
    for (int nt = 0; nt < 4; ++nt)
#pragma unroll
      for (int r = 0; r < 4; ++r) {
        int row = m0 + wm + mt*16 + quad*4 + r;
        int col = n0 + nt*16 + l16;
        C[(size_t)row*N + col] = (OutT)acc[mt][nt][r];
      }
}

// ---------------- MFMA chunked delta-rule pre-pass (conv fused, 2 blocks/CU) ----------------
// 8 stride-64 XOR-swizzled planes + q plane = 73 KB LDS. Plane life-cycle:
//  A:Kr->VT(lo) B:powR0->VT(hi) C:prod0->WR->VlT(lo) D:T2T->VlT(hi)
//  E:powT0->KT  F:powR1->KbT    G:powT1->Pm          H:prod1(Mrow)  Q:qbf
template<int NT>
__device__ __forceinline__ void mm_band(const bf16* A_lds, const bf16* B_lds,
    int w16, int cb, int l16, int quad, f32x4* acc) {
#pragma unroll
  for (int n = 0; n < NT; ++n) { acc[n][0]=0.f; acc[n][1]=0.f; acc[n][2]=0.f; acc[n][3]=0.f; }
#pragma unroll
  for (int kt = 0; kt < 2; ++kt) {
    bf16x8 af = *(const bf16x8*)(A_lds + sx8(w16 + l16, kt*4 + quad));
#pragma unroll
    for (int n = 0; n < NT; ++n) {
      bf16x8 bf = *(const bf16x8*)(B_lds + sx8(cb + n*16 + l16, kt*4 + quad));
      acc[n] = __builtin_amdgcn_mfma_f32_16x16x32_bf16(af, bf, acc[n], 0, 0, 0);
    }
  }
}

__global__ __launch_bounds__(512, 4) void k_prepass(
    const bf16* __restrict__ qpre, const bf16* __restrict__ kpre,
    const bf16* __restrict__ vpre, const float* __restrict__ cqw,
    const float* __restrict__ ckw, const float* __restrict__ cvw,
    const float* __restrict__ graw, const float* __restrict__ beta,
    bf16* __restrict__ EF, float* __restrict__ dSl, float* __restrict__ obuf) {
  const int bx = blockIdx.x, c = bx >> 4, h = bx & 15, tid = threadIdx.x;
  const int t0 = c * 64;
  const int wave = tid >> 6, lane = tid & 63, l16 = lane & 15, quad = lane >> 4;
  const int w16 = (wave >> 1) * 16;
  const int chh = wave & 1;
  const int r0 = wave * 8;

  __shared__ bf16 SM[36864];
  __shared__ float bs[64], bts_s[64], es[64], gms[64];
  bf16* Kr    = SM;            // A
  bf16* powR0 = SM + 4096;     // B
  bf16* prod0 = SM + 8192;     // C
  bf16* T2T   = SM + 12288;    // D
  bf16* powT0 = SM + 16384;    // E
  bf16* powR1 = SM + 20480;    // F
  bf16* powT1 = SM + 24576;    // G
  bf16* prod1 = SM + 28672;    // H
  bf16* qbf   = SM + 32768;    // Q
  bf16* VT   = SM;             // rows 0..127 over A+B
  bf16* VlT  = SM + 8192;      // rows 0..127 over C+D
  bf16* KT   = powT0;
  bf16* KbT  = powR1;
  bf16* Pm   = powT1;
  bf16* WR   = prod0;
  bf16* Mrow = prod1;

  if (tid < 64) {
    float g = graw[(size_t)(t0 + tid)*16 + h];
    float b = g;
#pragma unroll
    for (int off = 1; off < 64; off <<= 1) {
      float p = __shfl_up(b, off, 64);
      if (tid >= off) b += p;
    }
    bs[tid] = b;
    bts_s[tid] = beta[(size_t)(t0 + tid)*16 + h];
    float b63 = __shfl(b, 63, 64);
    es[tid] = __expf(b63 - b);
    gms[tid] = __expf(b);
  }

  // fused conv(K=4)+silu+norms; wave owns rows r0..r0+7, channel = lane
  // all 44 tap loads issued up front so one latency batch covers everything
  float kreg[8], vreg[16];
  {
    float4 wq  = *(const float4*)(cqw + (h*64 + lane)*4);
    float4 wk  = *(const float4*)(ckw + (h*64 + lane)*4);
    float4 wv0 = *(const float4*)(cvw + (h*128 + lane)*4);
    float4 wv1 = *(const float4*)(cvw + (h*128 + 64 + lane)*4);
    float qtv[11], ktv[11], vtv0[11], vtv1[11];
#pragma unroll
    for (int j = 0; j < 11; ++j) {
      int tg = t0 + r0 + j - 3;
      bool ok = tg >= 0;
      qtv[j]  = ok ? (float)qpre[(size_t)tg*1024 + h*64 + lane] : 0.f;
      ktv[j]  = ok ? (float)kpre[(size_t)tg*1024 + h*64 + lane] : 0.f;
      vtv0[j] = ok ? (float)vpre[(size_t)tg*2048 + h*128 + lane] : 0.f;
      vtv1[j] = ok ? (float)vpre[(size_t)tg*2048 + h*128 + 64 + lane] : 0.f;
    }
#pragma unroll
    for (int rr = 0; rr < 8; ++rr) {
      float y = qtv[rr]*wq.x + qtv[rr+1]*wq.y + qtv[rr+2]*wq.z + qtv[rr+3]*wq.w;
      y = y * sigmoidf_(y);
      float ssq = wredsum(y*y);
      y *= rsqrtf(ssq + 1e-6f) * 0.125f;
      qbf[sxy(r0+rr, lane)] = (bf16)y;
    }
#pragma unroll
    for (int rr = 0; rr < 8; ++rr) {
      float y = ktv[rr]*wk.x + ktv[rr+1]*wk.y + ktv[rr+2]*wk.z + ktv[rr+3]*wk.w;
      y = y * sigmoidf_(y);
      // joint (sum, sumsq) butterfly: centered ssq = s2 - s1^2/64
      float s1 = y, s2 = y*y;
#pragma unroll
      for (int off = 32; off > 0; off >>= 1) {
        s1 += __shfl_xor(s1, off, 64);
        s2 += __shfl_xor(s2, off, 64);
      }
      float m = s1 * (1.f/64.f);
      float ssq = s2 - s1*m;
      y -= m;
      y *= rsqrtf(ssq + 1e-6f);
      kreg[rr] = y;
      Kr[sxy(r0+rr, lane)] = (bf16)y;
    }
#pragma unroll
    for (int rr = 0; rr < 8; ++rr) {
      float y0 = vtv0[rr]*wv0.x + vtv0[rr+1]*wv0.y + vtv0[rr+2]*wv0.z + vtv0[rr+3]*wv0.w;
      float y1 = vtv1[rr]*wv1.x + vtv1[rr+1]*wv1.y + vtv1[rr+2]*wv1.z + vtv1[rr+3]*wv1.w;
      vreg[rr]   = y0 * sigmoidf_(y0);
      vreg[8+rr] = y1 * sigmoidf_(y1);
    }
  }
  __syncthreads();

  // A-build: N = -A from K K^T; prod0 = I + N
  {
    f32x4 acc[2];
    mm_band<2>(Kr, Kr, w16, chh*32, l16, quad, acc);
#pragma unroll
    for (int n = 0; n < 2; ++n) {
      int col = chh*32 + n*16 + l16;
      bf16x4v tv;
#pragma unroll
      for (int r = 0; r < 4; ++r) {
        int row = w16 + quad*4 + r;
        float nv = 0.f;
        if (row > col) nv = -bts_s[row] * __expf(bs[row] - bs[col]) * acc[n][r];
        bf16 nb = (bf16)nv;
        powR0[sxy(row, col)] = nb;
        tv[r] = nb;
        prod0[sxy(row, col)] = (row == col) ? (bf16)1.f : nb;
      }
      *(bf16x4v*)(powT0 + sxy(col, w16 + quad*4)) = tv;
    }
  }
  __syncthreads();

  // squaring chain: (I+A)^-1 = prod (I + N^(2^i))
  int pc = 0, rc = 0;
#pragma unroll 1
  for (int i = 1; i <= 5; ++i) {
    bf16* sqA = pc ? powR1 : powR0;
    bf16* sqB = pc ? powT1 : powT0;
    bf16* sqRo = pc ? powR0 : powR1;
    bf16* sqTo = pc ? powT0 : powT1;
    {
      f32x4 acc[2];
      mm_band<2>(sqA, sqB, w16, chh*32, l16, quad, acc);
#pragma unroll
      for (int n = 0; n < 2; ++n) {
        int col = chh*32 + n*16 + l16;
        bf16x4v tv;
#pragma unroll
        for (int r = 0; r < 4; ++r) {
          int row = w16 + quad*4 + r;
          bf16 vb = (bf16)acc[n][r];
          sqRo[sxy(row, col)] = vb;
          tv[r] = vb;
        }
        *(bf16x4v*)(sqTo + sxy(col, w16 + quad*4)) = tv;
      }
    }
    __syncthreads();
    bf16* prA = rc ? prod1 : prod0;
    bf16* prO = rc ? prod0 : prod1;
    {
      f32x4 acc[2];
      mm_band<2>(prA, sqTo, w16, chh*32, l16, quad, acc);
#pragma unroll
      for (int n = 0; n < 2; ++n) {
        int col = chh*32 + n*16 + l16;
        bf16x4v tv;
#pragma unroll
        for (int r = 0; r < 4; ++r) {
          int row = w16 + quad*4 + r;
          float val = acc[n][r] + (float)prA[sxy(row, col)];
          prO[sxy(row, col)] = (bf16)val;
          tv[r] = (bf16)(val * bts_s[col] * gms[col]);
        }
        if (i == 5) *(bf16x4v*)(T2T + sxy(col, w16 + quad*4)) = tv;
      }
    }
    __syncthreads();
    pc ^= 1; rc ^= 1;
  }
  // after chain: Mrow = prod1, pow planes dead

  // KT/KbT from registers; Pm build (reads Kr + qbf)
#pragma unroll
  for (int rr = 0; rr < 8; ++rr) {
    KT[sxy(lane, r0+rr)]  = (bf16)kreg[rr];
    KbT[sxy(lane, r0+rr)] = (bf16)(kreg[rr] * es[r0+rr]);
  }
  {
    f32x4 acc[2];
#pragma unroll
    for (int n = 0; n < 2; ++n) { acc[n][0]=0.f; acc[n][1]=0.f; acc[n][2]=0.f; acc[n][3]=0.f; }
#pragma unroll
    for (int kt = 0; kt < 2; ++kt) {
      bf16x8 af = *(const bf16x8*)(qbf + sx8(w16 + l16, kt*4 + quad));
#pragma unroll
      for (int n = 0; n < 2; ++n) {
        bf16x8 bf = *(const bf16x8*)(Kr + sx8(chh*32 + n*16 + l16, kt*4 + quad));
        acc[n] = __builtin_amdgcn_mfma_f32_16x16x32_bf16(af, bf, acc[n], 0, 0, 0);
      }
    }
#pragma unroll
    for (int n = 0; n < 2; ++n) {
      int col = chh*32 + n*16 + l16;
#pragma unroll
      for (int r = 0; r < 4; ++r) {
        int row = w16 + quad*4 + r;
        float pv = (row >= col) ? __expf(bs[row] - bs[col]) * acc[n][r] : 0.f;
        Pm[sxy(row, col)] = (bf16)pv;
      }
    }
  }
  __syncthreads();

  // W2 = Kbar^T T2 -> WR ; VT from vreg (Kr/powR0 dead)
  {
    f32x4 acc[2];
    mm_band<2>(KbT, T2T, w16, chh*32, l16, quad, acc);
#pragma unroll
    for (int n = 0; n < 2; ++n) {
      int col = chh*32 + n*16 + l16;
#pragma unroll
      for (int r = 0; r < 4; ++r)
        WR[sxy(w16 + quad*4 + r, col)] = (bf16)acc[n][r];
    }
  }
#pragma unroll
  for (int hf = 0; hf < 2; ++hf)
#pragma unroll
    for (int rr = 0; rr < 8; ++rr)
      VT[sxy(hf*64 + lane, r0+rr)] = (bf16)(bts_s[r0+rr] * vreg[hf*8+rr]);
  __syncthreads();
  // E = gamma_C I - W2 K -> EF planes 0/1 (hi/lo)
  {
    f32x4 acc[2];
    mm_band<2>(WR, KT, w16, chh*32, l16, quad, acc);
    float gC = gms[63];
    size_t eb = (size_t)bx * 13824;
#pragma unroll
    for (int n = 0; n < 2; ++n) {
      int col = chh*32 + n*16 + l16;
#pragma unroll
      for (int r = 0; r < 4; ++r) {
        int row = w16 + quad*4 + r;
        float ev = ((row == col) ? gC : 0.f) - acc[n][r];
        bf16 eh = (bf16)ev;
        EF[eb + row*S72 + col] = eh;
        EF[eb + 4608 + row*S72 + col] = (bf16)(ev - (float)eh);
      }
    }
  }
  __syncthreads();
  // R = P T2 -> WR
  {
    f32x4 acc[2];
    mm_band<2>(Pm, T2T, w16, chh*32, l16, quad, acc);
#pragma unroll
    for (int n = 0; n < 2; ++n) {
      int col = chh*32 + n*16 + l16;
#pragma unroll
      for (int r = 0; r < 4; ++r)
        WR[sxy(w16 + quad*4 + r, col)] = (bf16)acc[n][r];
    }
  }
  __syncthreads();
  // F = diag(gamma) Q - R K -> EF plane 2
  {
    f32x4 acc[2];
    mm_band<2>(WR, KT, w16, chh*32, l16, quad, acc);
    size_t eb = (size_t)bx * 13824;
#pragma unroll
    for (int n = 0; n < 2; ++n) {
      int col = chh*32 + n*16 + l16;
#pragma unroll
      for (int r = 0; r < 4; ++r) {
        int row = w16 + quad*4 + r;
        float qv = (float)qbf[sxy(row, col)];
        EF[eb + 9216 + row*S72 + col] = (bf16)(gms[row]*qv - acc[n][r]);
      }
    }
  }
  __syncthreads();   // WR/T2T reads done before VlT overwrites C+D
  // V_loc = M (beta V): write V_loc^T into VlT
  {
    f32x4 acc[4];
    mm_band<4>(Mrow, VT, w16, chh*64, l16, quad, acc);
#pragma unroll
    for (int n = 0; n < 4; ++n) {
      int col = chh*64 + n*16 + l16;
      bf16x4v tv;
#pragma unroll
      for (int r = 0; r < 4; ++r) tv[r] = (bf16)acc[n][r];
      *(bf16x4v*)(VlT + sxy(col, w16 + quad*4)) = tv;
    }
  }
  __syncthreads();
  // dS_loc = Kbar^T V_loc ; O_loc = P V_loc
  {
    f32x4 acc[4];
    mm_band<4>(KbT, VlT, w16, chh*64, l16, quad, acc);
#pragma unroll
    for (int n = 0; n < 4; ++n) {
      int col = chh*64 + n*16 + l16;
#pragma unroll
      for (int r = 0; r < 4; ++r)
        dSl[(size_t)bx*8192 + (size_t)(w16 + quad*4 + r)*128 + col] = acc[n][r];
    }
  }
  {
    f32x4 acc[4];
    mm_band<4>(Pm, VlT, w16, chh*64, l16, quad, acc);
#pragma unroll
    for (int n = 0; n < 4; ++n) {
      int col = chh*64 + n*16 + l16;
#pragma unroll
      for (int r = 0; r < 4; ++r)
        obuf[(size_t)(t0 + w16 + quad*4 + r)*2048 + h*128 + col] = acc[n][r];
    }
  }
}

// ---------------- MFMA sequential recurrence (named-register pipeline, raw barriers) ----
// rule #20 fix: NO runtime-indexed outer arrays. Two named register sets (A/B) and an
// explicit 2-step loop body so every buffer index is a compile-time literal. EF/dSl
// prefetched one chunk ahead global->VGPR; S state double-buffered in LDS (literal 0/1).
#define SEQ_LOAD(Cn, EHx, ELx, FFx, DSx)                                        \
  {                                                                             \
    const bf16* base_ = EF + (size_t)((Cn)*16 + h)*13824 + arow;                \
    _Pragma("unroll")                                                           \
    for (int kt = 0; kt < 2; ++kt) {                                            \
      EHx[kt] = *(const bf16x8*)(base_ + kt*32);                                \
      ELx[kt] = *(const bf16x8*)(base_ + 4608 + kt*32);                         \
      FFx[kt] = *(const bf16x8*)(base_ + 9216 + kt*32);                         \
    }                                                                           \
    const float* db_ = dSl + (size_t)((Cn)*16 + h)*8192 + drow;                 \
    _Pragma("unroll")                                                           \
    for (int nt = 0; nt < 2; ++nt)                                              \
      _Pragma("unroll")                                                         \
      for (int r = 0; r < 4; ++r)                                               \
        DSx[nt*4+r] = db_[(size_t)r*128 + nt*16];                               \
  }

#define SEQ_STEP(Cc, EHc, ELc, FFc, DSc, EHn, ELn, FFn, DSn, SRC, DST)          \
  {                                                                             \
    bf16x8 bh[2][2], bl[2][2];                                                  \
    _Pragma("unroll")                                                           \
    for (int nt = 0; nt < 2; ++nt)                                              \
      _Pragma("unroll")                                                         \
      for (int kt = 0; kt < 2; ++kt) {                                          \
        bh[nt][kt] = *(const bf16x8*)(&Sthi[SRC][(nt*16 + l16)*S72 + kt*32 + quad*8]); \
        bl[nt][kt] = *(const bf16x8*)(&Stlo[SRC][(nt*16 + l16)*S72 + kt*32 + quad*8]); \
      }                                                                         \
    if ((Cc) + 1 < 32) SEQ_LOAD((Cc) + 1, EHn, ELn, FFn, DSn);                  \
    f32x4 a1[2], a2[2], a3[2], o1[2], o2[2];                                    \
    _Pragma("unroll")                                                           \
    for (int nt = 0; nt < 2; ++nt)                                              \
      _Pragma("unroll")                                                         \
      for (int r = 0; r < 4; ++r) {                                             \
        a1[nt][r] = DSc[nt*4+r];                                                \
        a2[nt][r] = 0.f; a3[nt][r] = 0.f; o1[nt][r] = 0.f; o2[nt][r] = 0.f;     \
      }                                                                         \
    _Pragma("unroll")                                                           \
    for (int kt = 0; kt < 2; ++kt)                                              \
      _Pragma("unroll")                                                         \
      for (int nt = 0; nt < 2; ++nt) {                                          \
        a1[nt] = __builtin_amdgcn_mfma_f32_16x16x32_bf16(EHc[kt], bh[nt][kt], a1[nt], 0, 0, 0); \
        a2[nt] = __builtin_amdgcn_mfma_f32_16x16x32_bf16(EHc[kt], bl[nt][kt], a2[nt], 0, 0, 0); \
        a3[nt] = __builtin_amdgcn_mfma_f32_16x16x32_bf16(ELc[kt], bh[nt][kt], a3[nt], 0, 0, 0); \
        o1[nt] = __builtin_amdgcn_mfma_f32_16x16x32_bf16(FFc[kt], bh[nt][kt], o1[nt], 0, 0, 0); \
        o2[nt] = __builtin_amdgcn_mfma_f32_16x16x32_bf16(FFc[kt], bl[nt][kt], o2[nt], 0, 0, 0); \
      }                                                                         \
    {                                                                           \
      int t0c = (Cc)*64;                                                        \
      _Pragma("unroll")                                                         \
      for (int nt = 0; nt < 2; ++nt)                                            \
        _Pragma("unroll")                                                       \
        for (int r = 0; r < 4; ++r)                                             \
          osb[(size_t)(t0c + mb + quad*4 + r)*2048 + h*128 + dq*32 + nt*16 + l16] \
            = o1[nt][r] + o2[nt][r];                                            \
    }                                                                           \
    _Pragma("unroll")                                                           \
    for (int nt = 0; nt < 2; ++nt) {                                            \
      bf16x4v hv, lv;                                                           \
      _Pragma("unroll")                                                         \
      for (int r = 0; r < 4; ++r) {                                             \
        float v = a1[nt][r] + a2[nt][r] + a3[nt][r];                            \
        bf16 hb = (bf16)v;                                                      \
        hv[r] = hb;                                                             \
        lv[r] = (bf16)(v - (float)hb);                                          \
      }                                                                         \
      *(bf16x4v*)(&Sthi[DST][(nt*16 + l16)*S72 + mb + quad*4]) = hv;            \
      *(bf16x4v*)(&Stlo[DST][(nt*16 + l16)*S72 + mb + quad*4]) = lv;            \
    }                                                                           \
    asm volatile("s_waitcnt lgkmcnt(0)" ::: "memory");                          \
    __builtin_amdgcn_s_barrier();                                               \
  }

__global__ __launch_bounds__(256) void k_seq(const bf16* __restrict__ EF,
    const float* __restrict__ dSl, float* __restrict__ osb) {
  const int bid = blockIdx.x;
  const int h = (bid & 7) + 8*((bid >> 3) & 1);
  const int dq = bid >> 4;
  const int tid = threadIdx.x, wave = tid >> 6, lane = tid & 63;
  const int l16 = lane & 15, quad = lane >> 4;
  const int mb = wave * 16;
  __shared__ bf16 Sthi[2][32*S72], Stlo[2][32*S72];
  for (int i = tid; i < 2304; i += 256) { Sthi[0][i] = (bf16)0.f; Stlo[0][i] = (bf16)0.f; }

  const size_t arow = (size_t)(mb + l16)*S72 + quad*8;
  const size_t drow = (size_t)dq*32 + (size_t)(mb + quad*4)*128 + l16;

  bf16x8 ehA[2], elA[2], ffA[2], ehB[2], elB[2], ffB[2];
  float dsA[8], dsB[8];

  SEQ_LOAD(0, ehA, elA, ffA, dsA);
  asm volatile("s_waitcnt lgkmcnt(0)" ::: "memory");
  __builtin_amdgcn_s_barrier();

#pragma unroll 1
  for (int c = 0; c < 32; c += 2) {
    SEQ_STEP(c,     ehA, elA, ffA, dsA, ehB, elB, ffB, dsB, 0, 1);
    SEQ_STEP(c + 1, ehB, elB, ffB, dsB, ehA, elA, ffA, dsA, 1, 0);
  }
}

// ---------------- gated RMSNorm on o = O_loc + O_s, write bf16 ----------------
// 2048 blocks x 256 threads: wave w handles heads 4w..4w+3 (was 32768 x 64-thread blocks)
__global__ __launch_bounds__(256) void k_gatenorm(const float* __restrict__ o,
    const float* __restrict__ os, const bf16* __restrict__ gpre,
    const float* __restrict__ onw, bf16* __restrict__ og) {
  int t = blockIdx.x, wave = threadIdx.x >> 6, lane = threadIdx.x & 63;
  float2 nw = *(const float2*)(onw + lane*2);
#pragma unroll
  for (int hi = 0; hi < 4; ++hi) {
    int hh = wave*4 + hi;
    size_t base = (size_t)t*2048 + hh*128 + lane*2;
    float2 o2 = *(const float2*)(o + base);
    float2 s2 = *(const float2*)(os + base);
    o2.x += s2.x; o2.y += s2.y;
    float ss = wredsum(o2.x*o2.x + o2.y*o2.y);
    float rs = rsqrtf(ss * (1.f/128.f) + 1e-5f);
    bf16x2v g2 = *(const bf16x2v*)(gpre + base);
    float g0 = (float)g2[0], g1 = (float)g2[1];
    float r0 = o2.x * rs * nw.x * (g0 * sigmoidf_(g0));
    float r1 = o2.y * rs * nw.y * (g1 * sigmoidf_(g1));
    bf16x2v b; b[0] = (bf16)r0; b[1] = (bf16)r1;
    *(bf16x2v*)(og + base) = b;
  }
}

extern "C" void kernel_launch(void* const* d_in, const int* in_sizes, int n_in,
                              void* d_out, int out_size, void* d_ws, size_t ws_size,
                              hipStream_t stream) {
  const float* hs   = (const float*)d_in[0];
  const float* nw   = (const float*)d_in[1];
  const float* qw   = (const float*)d_in[2];
  const float* kw   = (const float*)d_in[3];
  const float* vw   = (const float*)d_in[4];
  const float* aw   = (const float*)d_in[5];
  const float* bw   = (const float*)d_in[6];
  const float* gw   = (const float*)d_in[7];
  const float* dtb  = (const float*)d_in[8];
  const float* alog = (const float*)d_in[9];
  const float* cqw  = (const float*)d_in[10];
  const float* ckw  = (const float*)d_in[11];
  const float* cvw  = (const float*)d_in[12];
  const float* onw  = (const float*)d_in[13];
  const float* opw  = (const float*)d_in[14];
  const float* ow   = (const float*)d_in[15];
  float* out = (float*)d_out;

  char* p = (char*)d_ws;
  auto alloc = [&](size_t bytes) { char* r = p; p += (bytes + 255) & ~255ull; return r; };
  bf16*  xb    = (bf16*) alloc((size_t)2048*1024*2);   // } dSl aliases xb..gwb (16 MB,
  bf16*  qwb   = (bf16*) alloc((size_t)1024*1024*2);   // } all dead after k_gemm_proj)
  bf16*  kwb   = (bf16*) alloc((size_t)1024*1024*2);
  bf16*  vwb   = (bf16*) alloc((size_t)2048*1024*2);
  bf16*  gwb   = (bf16*) alloc((size_t)2048*1024*2);
  bf16*  opwb  = (bf16*) alloc((size_t)1024*2048*2);
  bf16*  owb   = (bf16*) alloc((size_t)1024*1024*2);
  bf16*  qpre  = (bf16*) alloc((size_t)2048*1024*2);
  bf16*  kpre  = (bf16*) alloc((size_t)2048*1024*2);
  bf16*  vpre  = (bf16*) alloc((size_t)2048*2048*2);
  bf16*  gpre  = (bf16*) alloc((size_t)2048*2048*2);
  float* graw  = (float*)alloc((size_t)2048*16*4);
  float* btb   = (float*)alloc((size_t)2048*16*4);
  float* ob    = (float*)alloc((size_t)2048*2048*4);
  bf16*  ogb   = (bf16*) alloc((size_t)2048*2048*2);
  bf16*  h1b   = (bf16*) alloc((size_t)2048*1024*2);
  bf16*  EF    = (bf16*) alloc((size_t)512*13824*2);
  float* osb   = (float*)alloc((size_t)512*8192*4);
  float* dSl   = (float*)xb;   // 16 MB over xb..gwb (dead after k_gemm_proj)

  k_pre<<<2048+4608, 256, 0, stream>>>(hs, nw, aw, bw, dtb, alog, xb, graw, btb,
                                       qw, kw, vw, gw, opw, ow,
                                       qwb, kwb, vwb, gwb, opwb, owb);
  k_gemm_proj<<<dim3(48,16,1), 256, 0, stream>>>(xb, qwb, kwb, vwb, gwb, qpre, kpre, vpre, gpre);
  k_prepass<<<512, 512, 0, stream>>>(qpre, kpre, vpre, cqw, ckw, cvw, graw, btb, EF, dSl, ob);
  k_seq<<<64, 256, 0, stream>>>(EF, dSl, osb);
  k_gatenorm<<<2048, 256, 0, stream>>>(ob, osb, gpre, onw, ogb);
  k_gemm_bt64<bf16><<<dim3(16,16,1), 256, 0, stream>>>(ogb, opwb, h1b, 1024, 2048);
  k_gemm_bt64<float><<<dim3(16,16,1), 256, 0, stream>>>(h1b, owb, out, 1024, 1024);
}

// Round 4
// 270.224 us; speedup vs baseline: 1.0050x; 1.0050x over previous
//
#include <hip/hip_runtime.h>
#include <math.h>

#define S72 72

typedef __bf16 bf16;
typedef __bf16 bf16x8 __attribute__((ext_vector_type(8)));
typedef __bf16 bf16x4v __attribute__((ext_vector_type(4)));
typedef __bf16 bf16x2v __attribute__((ext_vector_type(2)));
typedef float f32x4 __attribute__((ext_vector_type(4)));

__device__ __forceinline__ float wredsum(float v) {
#pragma unroll
  for (int off = 32; off > 0; off >>= 1) v += __shfl_xor(v, off, 64);
  return v;
}
__device__ __forceinline__ float sigmoidf_(float x) { return 1.f / (1.f + __expf(-x)); }

// swizzled LDS addressing for 64-col planes: row stride 64, 8-elem chunks XOR'd by row&7
__device__ __forceinline__ int sxy(int row, int col) {
  return (row << 6) + ((((col >> 3) ^ (row & 7)) << 3) | (col & 7));
}
__device__ __forceinline__ int sx8(int row, int chunk) {
  return (row << 6) + ((chunk ^ (row & 7)) << 3);
}

// ---------------- fused: RMSNorm + a/b projections  |  weight cast ----------------
__global__ __launch_bounds__(256) void k_pre(const float* __restrict__ h,
    const float* __restrict__ nw, const float* __restrict__ aw,
    const float* __restrict__ bw, const float* __restrict__ dtb,
    const float* __restrict__ alog, bf16* __restrict__ xb,
    float* __restrict__ graw, float* __restrict__ btb,
    const float* __restrict__ qw, const float* __restrict__ kw,
    const float* __restrict__ vw, const float* __restrict__ gw,
    const float* __restrict__ opw, const float* __restrict__ ow,
    bf16* qwb, bf16* kwb, bf16* vwb, bf16* gwb, bf16* opwb, bf16* owb) {
  __shared__ float red[4];
  __shared__ __align__(16) float xs[1024];
  int tid = threadIdx.x;
  if (blockIdx.x >= 2048) {
    // weight cast part (4608 virtual blocks)
    long cb = blockIdx.x - 2048;
    for (long u = cb*256 + tid; u < 2359296; u += 4608l*256) {
      const float* src; bf16* dst; long l;
      if      (u <  262144) { src=qw;  dst=qwb;  l=u; }
      else if (u <  524288) { src=kw;  dst=kwb;  l=u-262144; }
      else if (u < 1048576) { src=vw;  dst=vwb;  l=u-524288; }
      else if (u < 1572864) { src=gw;  dst=gwb;  l=u-1048576; }
      else if (u < 2097152) { src=opw; dst=opwb; l=u-1572864; }
      else                  { src=ow;  dst=owb;  l=u-2097152; }
      float4 s = *(const float4*)(src + l*4);
      bf16x4v b; b[0]=(bf16)s.x; b[1]=(bf16)s.y; b[2]=(bf16)s.z; b[3]=(bf16)s.w;
      *(bf16x4v*)(dst + l*4) = b;
    }
    return;
  }
  int t = blockIdx.x;
  float4 hv = *(const float4*)(h + (size_t)t*1024 + tid*4);
  float ss = hv.x*hv.x + hv.y*hv.y + hv.z*hv.z + hv.w*hv.w;
  float wsum = wredsum(ss);
  if ((tid & 63) == 0) red[tid >> 6] = wsum;
  __syncthreads();
  float tot = red[0] + red[1] + red[2] + red[3];
  float rs = rsqrtf(tot * (1.f/1024.f) + 1e-6f);
  float4 w4 = *(const float4*)(nw + tid*4);
  float4 y;
  y.x = hv.x*rs*w4.x; y.y = hv.y*rs*w4.y; y.z = hv.z*rs*w4.z; y.w = hv.w*rs*w4.w;
  *(float4*)(xs + tid*4) = y;
  bf16x4v b; b[0]=(bf16)y.x; b[1]=(bf16)y.y; b[2]=(bf16)y.z; b[3]=(bf16)y.w;
  *(bf16x4v*)(xb + (size_t)t*1024 + tid*4) = b;
  __syncthreads();
  int wave = tid >> 6, lane = tid & 63;
  const float4* x4 = (const float4*)xs;
#pragma unroll
  for (int hi = 0; hi < 4; ++hi) {
    int hh = wave*4 + hi;
    float sa = 0.f, sb = 0.f;
#pragma unroll
    for (int i = 0; i < 4; ++i) {
      float4 xv = x4[i*64 + lane];
      float4 av = *(const float4*)(aw + hh*1024 + i*256 + lane*4);
      float4 bv = *(const float4*)(bw + hh*1024 + i*256 + lane*4);
      sa += xv.x*av.x + xv.y*av.y + xv.z*av.z + xv.w*av.w;
      sb += xv.x*bv.x + xv.y*bv.y + xv.z*bv.z + xv.w*bv.w;
    }
    sa = wredsum(sa); sb = wredsum(sb);
    if (lane == 0) {
      float ap = sa + dtb[hh];
      float sp = (ap > 20.f) ? ap : log1pf(expf(ap));
      graw[t*16 + hh] = -expf(alog[hh]) * sp;
      btb[t*16 + hh] = 1.f / (1.f + expf(-sb));
    }
  }
}

// ---------------- bf16 MFMA GEMM 128x128 (double-buffered, XOR-swizzled) ----------------
template <typename OutT>
__device__ __forceinline__ void gemm_body(const bf16* __restrict__ A,
    const bf16* __restrict__ B, OutT* __restrict__ C, int N, int K, int m0, int n0) {
  __shared__ bf16 As[2][128*32];
  __shared__ bf16 Bs[2][128*32];
  const int tid = threadIdx.x, lane = tid & 63, wave = tid >> 6;
  const int wm = (wave >> 1) * 64, wn = (wave & 1) * 64;
  const int srow = wave*16 + (lane >> 2);
  const int swl = (((lane & 3) ^ ((lane >> 3) & 3))) * 8;
  const int sdst = (lane & 3) * 8;
  const int quad = lane >> 4, l16 = lane & 15;
  const int sw = (l16 >> 1) & 3;
  f32x4 acc[4][4] = {};
  const int nk = K >> 5;
#pragma unroll
  for (int i = 0; i < 2; ++i) {
    int r = i*64 + srow;
    __builtin_amdgcn_global_load_lds(
      (__attribute__((address_space(1))) void*)(A + (size_t)(m0 + r)*K + swl),
      (__attribute__((address_space(3))) void*)(&As[0][r*32 + sdst]), 16, 0, 0);
    __builtin_amdgcn_global_load_lds(
      (__attribute__((address_space(1))) void*)(B + (size_t)(n0 + r)*K + swl),
      (__attribute__((address_space(3))) void*)(&Bs[0][r*32 + sdst]), 16, 0, 0);
  }
  for (int kt = 0; kt < nk; ++kt) {
    const int cur = kt & 1;
    __syncthreads();
    bf16x8 af[4], bfr[4];
#pragma unroll
    for (int mt = 0; mt < 4; ++mt)
      af[mt] = *(const bf16x8*)(&As[cur][(wm + mt*16 + l16)*32 + (quad ^ sw)*8]);
#pragma unroll
    for (int nt = 0; nt < 4; ++nt)
      bfr[nt] = *(const bf16x8*)(&Bs[cur][(wn + nt*16 + l16)*32 + (quad ^ sw)*8]);
    if (kt + 1 < nk) {
      int k0 = (kt + 1) << 5;
#pragma unroll
      for (int i = 0; i < 2; ++i) {
        int r = i*64 + srow;
        __builtin_amdgcn_global_load_lds(
          (__attribute__((address_space(1))) void*)(A + (size_t)(m0 + r)*K + k0 + swl),
          (__attribute__((address_space(3))) void*)(&As[cur^1][r*32 + sdst]), 16, 0, 0);
        __builtin_amdgcn_global_load_lds(
          (__attribute__((address_space(1))) void*)(B + (size_t)(n0 + r)*K + k0 + swl),
          (__attribute__((address_space(3))) void*)(&Bs[cur^1][r*32 + sdst]), 16, 0, 0);
      }
    }
#pragma unroll
    for (int mt = 0; mt < 4; ++mt)
#pragma unroll
      for (int nt = 0; nt < 4; ++nt)
        acc[mt][nt] = __builtin_amdgcn_mfma_f32_16x16x32_bf16(af[mt], bfr[nt], acc[mt][nt], 0, 0, 0);
  }
#pragma unroll
  for (int mt = 0; mt < 4; ++mt)
#pragma unroll
    for (int nt = 0; nt < 4; ++nt)
#pragma unroll
      for (int r = 0; r < 4; ++r) {
        int row = m0 + wm + mt*16 + quad*4 + r;
        int col = n0 + wn + nt*16 + l16;
        C[(size_t)row*N + col] = (OutT)acc[mt][nt][r];
      }
}

__global__ __launch_bounds__(256) void k_gemm_proj(const bf16* __restrict__ A,
    const bf16* __restrict__ qwb, const bf16* __restrict__ kwb,
    const bf16* __restrict__ vwb, const bf16* __restrict__ gwb,
    bf16* __restrict__ qpre, bf16* __restrict__ kpre,
    bf16* __restrict__ vpre, bf16* __restrict__ gpre) {
  int bx = blockIdx.x;
  const bf16* B; bf16* C; int N, xt;
  if      (bx <  8) { B = qwb; C = qpre; N = 1024; xt = bx; }
  else if (bx < 16) { B = kwb; C = kpre; N = 1024; xt = bx - 8; }
  else if (bx < 32) { B = vwb; C = vpre; N = 2048; xt = bx - 16; }
  else              { B = gwb; C = gpre; N = 2048; xt = bx - 32; }
  gemm_body<bf16>(A, B, C, N, 1024, blockIdx.y*128, xt*128);
}

// ---------------- bf16 MFMA GEMM 128x64 (2x blocks for tail GEMMs) ----------------
template <typename OutT>
__global__ __launch_bounds__(256) void k_gemm_bt64(const bf16* __restrict__ A,
    const bf16* __restrict__ B, OutT* __restrict__ C, int N, int K) {
  __shared__ bf16 As[2][128*32];
  __shared__ bf16 Bs[2][64*32];
  const int tid = threadIdx.x, lane = tid & 63, wave = tid >> 6;
  const int wm = wave * 32;
  const int srow = wave*16 + (lane >> 2);
  const int swl = (((lane & 3) ^ ((lane >> 3) & 3))) * 8;
  const int sdst = (lane & 3) * 8;
  const int quad = lane >> 4, l16 = lane & 15;
  const int sw = (l16 >> 1) & 3;
  const int m0 = blockIdx.y * 128, n0 = blockIdx.x * 64;
  f32x4 acc[2][4] = {};
  const int nk = K >> 5;
#pragma unroll
  for (int i = 0; i < 2; ++i) {
    int r = i*64 + srow;
    __builtin_amdgcn_global_load_lds(
      (__attribute__((address_space(1))) void*)(A + (size_t)(m0 + r)*K + swl),
      (__attribute__((address_space(3))) void*)(&As[0][r*32 + sdst]), 16, 0, 0);
  }
  __builtin_amdgcn_global_load_lds(
    (__attribute__((address_space(1))) void*)(B + (size_t)(n0 + srow)*K + swl),
    (__attribute__((address_space(3))) void*)(&Bs[0][srow*32 + sdst]), 16, 0, 0);
  for (int kt = 0; kt < nk; ++kt) {
    const int cur = kt & 1;
    __syncthreads();
    bf16x8 af[2], bfr[4];
#pragma unroll
    for (int mt = 0; mt < 2; ++mt)
      af[mt] = *(const bf16x8*)(&As[cur][(wm + mt*16 + l16)*32 + (quad ^ sw)*8]);
#pragma unroll
    for (int nt = 0; nt < 4; ++nt)
      bfr[nt] = *(const bf16x8*)(&Bs[cur][(nt*16 + l16)*32 + (quad ^ sw)*8]);
    if (kt + 1 < nk) {
      int k0 = (kt + 1) << 5;
#pragma unroll
      for (int i = 0; i < 2; ++i) {
        int r = i*64 + srow;
        __builtin_amdgcn_global_load_lds(
          (__attribute__((address_space(1))) void*)(A + (size_t)(m0 + r)*K + k0 + swl),
          (__attribute__((address_space(3))) void*)(&As[cur^1][r*32 + sdst]), 16, 0, 0);
      }
      __builtin_amdgcn_global_load_lds(
        (__attribute__((address_space(1))) void*)(B + (size_t)(n0 + srow)*K + k0 + swl),
        (__attribute__((address_space(3))) void*)(&Bs[cur^1][srow*32 + sdst]), 16, 0, 0);
    }
#pragma unroll
    for (int mt = 0; mt < 2; ++mt)
#pragma unroll
      for (int nt = 0; nt < 4; ++nt)
        acc[mt][nt] = __builtin_amdgcn_mfma_f32_16x16x32_bf16(af[mt], bfr[nt], acc[mt][nt], 0, 0, 0);
  }
#pragma unroll
  for (int mt = 0; mt < 2; ++mt)
#pragma unroll
    for (int nt = 0; nt < 4; ++nt)
#pragma unroll
      for (int r = 0; r < 4; ++r) {
        int row = m0 + wm + mt*16 + quad*4 + r;
        int col = n0 + nt*16 + l16;
        C[(size_t)row*N + col] = (OutT)acc[mt][nt][r];
      }
}

// ---------------- MFMA chunked delta-rule pre-pass (12-barrier choreography) ----------------
// Phase graph exploits commuting powers of the nilpotent N: the prod-update
// P <- P*(I+N^(2^i)) runs IN THE SAME PHASE as the next squaring. Planes:
//  A:Kr->R(ph8)   B:N/M4/M16->VT(lo,ph9)  C:P0/P2/P4/W2->VT(hi,ph9)  D:T2T->VlT(lo)
//  E:N_T/M4T/M16T->KT->VlT(hi)  F:M2/M8->KbT  G:M2T/M8T/M32T->Pm  H:P1/P3/P5(Mrow)  Q:qbf
template<int NT>
__device__ __forceinline__ void mm_band(const bf16* A_lds, const bf16* B_lds,
    int w16, int cb, int l16, int quad, f32x4* acc) {
#pragma unroll
  for (int n = 0; n < NT; ++n) { acc[n][0]=0.f; acc[n][1]=0.f; acc[n][2]=0.f; acc[n][3]=0.f; }
#pragma unroll
  for (int kt = 0; kt < 2; ++kt) {
    bf16x8 af = *(const bf16x8*)(A_lds + sx8(w16 + l16, kt*4 + quad));
#pragma unroll
    for (int n = 0; n < NT; ++n) {
      bf16x8 bf = *(const bf16x8*)(B_lds + sx8(cb + n*16 + l16, kt*4 + quad));
      acc[n] = __builtin_amdgcn_mfma_f32_16x16x32_bf16(af, bf, acc[n], 0, 0, 0);
    }
  }
}

// square: out_rows/out_T = Sr * St (St is transposed operand)
__device__ __forceinline__ void sq_phase(const bf16* Sr, const bf16* St,
    bf16* Ro, bf16* To, int w16, int chh, int l16, int quad) {
  f32x4 acc[2];
  mm_band<2>(Sr, St, w16, chh*32, l16, quad, acc);
#pragma unroll
  for (int n = 0; n < 2; ++n) {
    int col = chh*32 + n*16 + l16;
    bf16x4v tv;
#pragma unroll
    for (int r = 0; r < 4; ++r) {
      int row = w16 + quad*4 + r;
      bf16 vb = (bf16)acc[n][r];
      Ro[sxy(row, col)] = vb;
      tv[r] = vb;
    }
    *(bf16x4v*)(To + sxy(col, w16 + quad*4)) = tv;
  }
}

// prod-update: Po = Pr + Pr*St ; optionally write scaled transpose (T2T)
__device__ __forceinline__ void prod_phase(const bf16* Pr, const bf16* St, bf16* Po,
    bf16* T2o, const float* bts_s, const float* gms,
    int w16, int chh, int l16, int quad) {
  f32x4 acc[2];
  mm_band<2>(Pr, St, w16, chh*32, l16, quad, acc);
#pragma unroll
  for (int n = 0; n < 2; ++n) {
    int col = chh*32 + n*16 + l16;
    bf16x4v tv;
#pragma unroll
    for (int r = 0; r < 4; ++r) {
      int row = w16 + quad*4 + r;
      float val = acc[n][r] + (float)Pr[sxy(row, col)];
      Po[sxy(row, col)] = (bf16)val;
      tv[r] = (bf16)(val * bts_s[col] * gms[col]);
    }
    if (T2o) *(bf16x4v*)(T2o + sxy(col, w16 + quad*4)) = tv;
  }
}

__global__ __launch_bounds__(512, 4) void k_prepass(
    const bf16* __restrict__ qpre, const bf16* __restrict__ kpre,
    const bf16* __restrict__ vpre, const float* __restrict__ cqw,
    const float* __restrict__ ckw, const float* __restrict__ cvw,
    const float* __restrict__ graw, const float* __restrict__ beta,
    bf16* __restrict__ EF, float* __restrict__ dSl, float* __restrict__ obuf) {
  const int bx = blockIdx.x, c = bx >> 4, h = bx & 15, tid = threadIdx.x;
  const int t0 = c * 64;
  const int wave = tid >> 6, lane = tid & 63, l16 = lane & 15, quad = lane >> 4;
  const int w16 = (wave >> 1) * 16;
  const int chh = wave & 1;
  const int r0 = wave * 8;

  __shared__ bf16 SM[36864];
  __shared__ float bs[64], bts_s[64], es[64], gms[64];
  bf16* pA = SM;
  bf16* pB = SM + 4096;
  bf16* pC = SM + 8192;
  bf16* pD = SM + 12288;
  bf16* pE = SM + 16384;
  bf16* pF = SM + 20480;
  bf16* pG = SM + 24576;
  bf16* pH = SM + 28672;
  bf16* pQ = SM + 32768;
  bf16* VTb  = SM + 4096;   // spans B+C (rows 0..127)
  bf16* VlTb = SM + 12288;  // spans D+E (rows 0..127)

  if (tid < 64) {
    float g = graw[(size_t)(t0 + tid)*16 + h];
    float b = g;
#pragma unroll
    for (int off = 1; off < 64; off <<= 1) {
      float p = __shfl_up(b, off, 64);
      if (tid >= off) b += p;
    }
    bs[tid] = b;
    bts_s[tid] = beta[(size_t)(t0 + tid)*16 + h];
    float b63 = __shfl(b, 63, 64);
    es[tid] = __expf(b63 - b);
    gms[tid] = __expf(b);
  }

  // conv(K=4)+silu+norms; wave owns rows r0..r0+7, channel = lane; taps hoisted
  float kreg[8], vreg[16];
  {
    float4 wq  = *(const float4*)(cqw + (h*64 + lane)*4);
    float4 wk  = *(const float4*)(ckw + (h*64 + lane)*4);
    float4 wv0 = *(const float4*)(cvw + (h*128 + lane)*4);
    float4 wv1 = *(const float4*)(cvw + (h*128 + 64 + lane)*4);
    float qtv[11], ktv[11], vtv0[11], vtv1[11];
#pragma unroll
    for (int j = 0; j < 11; ++j) {
      int tg = t0 + r0 + j - 3;
      bool ok = tg >= 0;
      qtv[j]  = ok ? (float)qpre[(size_t)tg*1024 + h*64 + lane] : 0.f;
      ktv[j]  = ok ? (float)kpre[(size_t)tg*1024 + h*64 + lane] : 0.f;
      vtv0[j] = ok ? (float)vpre[(size_t)tg*2048 + h*128 + lane] : 0.f;
      vtv1[j] = ok ? (float)vpre[(size_t)tg*2048 + h*128 + 64 + lane] : 0.f;
    }
#pragma unroll
    for (int rr = 0; rr < 8; ++rr) {
      float y = qtv[rr]*wq.x + qtv[rr+1]*wq.y + qtv[rr+2]*wq.z + qtv[rr+3]*wq.w;
      y = y * sigmoidf_(y);
      float ssq = wredsum(y*y);
      y *= rsqrtf(ssq + 1e-6f) * 0.125f;
      pQ[sxy(r0+rr, lane)] = (bf16)y;
    }
#pragma unroll
    for (int rr = 0; rr < 8; ++rr) {
      float y = ktv[rr]*wk.x + ktv[rr+1]*wk.y + ktv[rr+2]*wk.z + ktv[rr+3]*wk.w;
      y = y * sigmoidf_(y);
      float s1 = y, s2 = y*y;
#pragma unroll
      for (int off = 32; off > 0; off >>= 1) {
        s1 += __shfl_xor(s1, off, 64);
        s2 += __shfl_xor(s2, off, 64);
      }
      float m = s1 * (1.f/64.f);
      float ssq = s2 - s1*m;
      y -= m;
      y *= rsqrtf(ssq + 1e-6f);
      kreg[rr] = y;
      pA[sxy(r0+rr, lane)] = (bf16)y;     // Kr
    }
#pragma unroll
    for (int rr = 0; rr < 8; ++rr) {
      float y0 = vtv0[rr]*wv0.x + vtv0[rr+1]*wv0.y + vtv0[rr+2]*wv0.z + vtv0[rr+3]*wv0.w;
      float y1 = vtv1[rr]*wv1.x + vtv1[rr+1]*wv1.y + vtv1[rr+2]*wv1.z + vtv1[rr+3]*wv1.w;
      vreg[rr]   = y0 * sigmoidf_(y0);
      vreg[8+rr] = y1 * sigmoidf_(y1);
    }
  }
  __syncthreads();   // [1]

  // A-build: N rows->B, N^T->E, P0 = I+N -> C
  {
    f32x4 acc[2];
    mm_band<2>(pA, pA, w16, chh*32, l16, quad, acc);
#pragma unroll
    for (int n = 0; n < 2; ++n) {
      int col = chh*32 + n*16 + l16;
      bf16x4v tv;
#pragma unroll
      for (int r = 0; r < 4; ++r) {
        int row = w16 + quad*4 + r;
        float nv = 0.f;
        if (row > col) nv = -bts_s[row] * __expf(bs[row] - bs[col]) * acc[n][r];
        bf16 nb = (bf16)nv;
        pB[sxy(row, col)] = nb;
        tv[r] = nb;
        pC[sxy(row, col)] = (row == col) ? (bf16)1.f : nb;
      }
      *(bf16x4v*)(pE + sxy(col, w16 + quad*4)) = tv;
    }
  }
  __syncthreads();   // [2]

  // ph1: M2 = N*N -> F,G
  sq_phase(pB, pE, pF, pG, w16, chh, l16, quad);
  __syncthreads();   // [3]
  // ph2: M4 = M2*M2 -> B,E ; P1 = P0 + P0*M2 -> H
  sq_phase(pF, pG, pB, pE, w16, chh, l16, quad);
  prod_phase(pC, pG, pH, nullptr, bts_s, gms, w16, chh, l16, quad);
  __syncthreads();   // [4]
  // ph3: M8 -> F,G ; P2 = P1 + P1*M4 -> C
  sq_phase(pB, pE, pF, pG, w16, chh, l16, quad);
  prod_phase(pH, pE, pC, nullptr, bts_s, gms, w16, chh, l16, quad);
  __syncthreads();   // [5]
  // ph4: M16 -> B,E ; P3 = P2 + P2*M8 -> H
  sq_phase(pF, pG, pB, pE, w16, chh, l16, quad);
  prod_phase(pC, pG, pH, nullptr, bts_s, gms, w16, chh, l16, quad);
  __syncthreads();   // [6]
  // ph5: M32^T -> G ; P4 = P3 + P3*M16 -> C
  {
    f32x4 acc[2];
    mm_band<2>(pB, pE, w16, chh*32, l16, quad, acc);
#pragma unroll
    for (int n = 0; n < 2; ++n) {
      int col = chh*32 + n*16 + l16;
      bf16x4v tv;
#pragma unroll
      for (int r = 0; r < 4; ++r) tv[r] = (bf16)acc[n][r];
      *(bf16x4v*)(pG + sxy(col, w16 + quad*4)) = tv;
    }
  }
  prod_phase(pH, pE, pC, nullptr, bts_s, gms, w16, chh, l16, quad);
  __syncthreads();   // [7]
  // ph6: P5(Mrow) = P4 + P4*M32 -> H + T2T -> D ; KT -> E, KbT -> F (reg-sourced)
  prod_phase(pC, pG, pH, pD, bts_s, gms, w16, chh, l16, quad);
#pragma unroll
  for (int rr = 0; rr < 8; ++rr) {
    pE[sxy(lane, r0+rr)] = (bf16)kreg[rr];
    pF[sxy(lane, r0+rr)] = (bf16)(kreg[rr] * es[r0+rr]);
  }
  __syncthreads();   // [8]
  // ph7: Pm = expf-masked(Q K^T) -> G ; W2 = KbT^T T2 -> C
  {
    f32x4 acc[2];
#pragma unroll
    for (int n = 0; n < 2; ++n) { acc[n][0]=0.f; acc[n][1]=0.f; acc[n][2]=0.f; acc[n][3]=0.f; }
#pragma unroll
    for (int kt = 0; kt < 2; ++kt) {
      bf16x8 af = *(const bf16x8*)(pQ + sx8(w16 + l16, kt*4 + quad));
#pragma unroll
      for (int n = 0; n < 2; ++n) {
        bf16x8 bf = *(const bf16x8*)(pA + sx8(chh*32 + n*16 + l16, kt*4 + quad));
        acc[n] = __builtin_amdgcn_mfma_f32_16x16x32_bf16(af, bf, acc[n], 0, 0, 0);
      }
    }
#pragma unroll
    for (int n = 0; n < 2; ++n) {
      int col = chh*32 + n*16 + l16;
#pragma unroll
      for (int r = 0; r < 4; ++r) {
        int row = w16 + quad*4 + r;
        float pv = (row >= col) ? __expf(bs[row] - bs[col]) * acc[n][r] : 0.f;
        pG[sxy(row, col)] = (bf16)pv;
      }
    }
  }
  {
    f32x4 acc[2];
    mm_band<2>(pF, pD, w16, chh*32, l16, quad, acc);
#pragma unroll
    for (int n = 0; n < 2; ++n) {
      int col = chh*32 + n*16 + l16;
#pragma unroll
      for (int r = 0; r < 4; ++r)
        pC[sxy(w16 + quad*4 + r, col)] = (bf16)acc[n][r];
    }
  }
  __syncthreads();   // [9]
  // ph8: E = gC*I - W2*K -> EF planes 0/1 ; R = Pm*T2 -> A rows
  {
    f32x4 acc[2];
    mm_band<2>(pC, pE, w16, chh*32, l16, quad, acc);
    float gC = gms[63];
    size_t eb = (size_t)bx * 13824;
#pragma unroll
    for (int n = 0; n < 2; ++n) {
      int col = chh*32 + n*16 + l16;
#pragma unroll
      for (int r = 0; r < 4; ++r) {
        int row = w16 + quad*4 + r;
        float ev = ((row == col) ? gC : 0.f) - acc[n][r];
        bf16 eh = (bf16)ev;
        EF[eb + row*S72 + col] = eh;
        EF[eb + 4608 + row*S72 + col] = (bf16)(ev - (float)eh);
      }
    }
  }
  {
    f32x4 acc[2];
    mm_band<2>(pG, pD, w16, chh*32, l16, quad, acc);
#pragma unroll
    for (int n = 0; n < 2; ++n) {
      int col = chh*32 + n*16 + l16;
#pragma unroll
      for (int r = 0; r < 4; ++r)
        pA[sxy(w16 + quad*4 + r, col)] = (bf16)acc[n][r];
    }
  }
  __syncthreads();   // [10]
  // ph9: F = diag(gamma) Q - R K -> EF plane 2 ; VT (beta*V)^T -> B+C
  {
    f32x4 acc[2];
    mm_band<2>(pA, pE, w16, chh*32, l16, quad, acc);
    size_t eb = (size_t)bx * 13824;
#pragma unroll
    for (int n = 0; n < 2; ++n) {
      int col = chh*32 + n*16 + l16;
#pragma unroll
      for (int r = 0; r < 4; ++r) {
        int row = w16 + quad*4 + r;
        float qv = (float)pQ[sxy(row, col)];
        EF[eb + 9216 + row*S72 + col] = (bf16)(gms[row]*qv - acc[n][r]);
      }
    }
  }
#pragma unroll
  for (int hf = 0; hf < 2; ++hf)
#pragma unroll
    for (int rr = 0; rr < 8; ++rr)
      VTb[sxy(hf*64 + lane, r0+rr)] = (bf16)(bts_s[r0+rr] * vreg[hf*8+rr]);
  __syncthreads();   // [11]
  // ph10: V_loc = Mrow (beta V): write V_loc^T -> D+E
  {
    f32x4 acc[4];
    mm_band<4>(pH, VTb, w16, chh*64, l16, quad, acc);
#pragma unroll
    for (int n = 0; n < 4; ++n) {
      int col = chh*64 + n*16 + l16;
      bf16x4v tv;
#pragma unroll
      for (int r = 0; r < 4; ++r) tv[r] = (bf16)acc[n][r];
      *(bf16x4v*)(VlTb + sxy(col, w16 + quad*4)) = tv;
    }
  }
  __syncthreads();   // [12]
  // ph11: dS_loc = KbT^T V_loc ; O_loc = Pm V_loc
  {
    f32x4 acc[4];
    mm_band<4>(pF, VlTb, w16, chh*64, l16, quad, acc);
#pragma unroll
    for (int n = 0; n < 4; ++n) {
      int col = chh*64 + n*16 + l16;
#pragma unroll
      for (int r = 0; r < 4; ++r)
        dSl[(size_t)bx*8192 + (size_t)(w16 + quad*4 + r)*128 + col] = acc[n][r];
    }
  }
  {
    f32x4 acc[4];
    mm_band<4>(pG, VlTb, w16, chh*64, l16, quad, acc);
#pragma unroll
    for (int n = 0; n < 4; ++n) {
      int col = chh*64 + n*16 + l16;
#pragma unroll
      for (int r = 0; r < 4; ++r)
        obuf[(size_t)(t0 + w16 + quad*4 + r)*2048 + h*128 + col] = acc[n][r];
    }
  }
}

// ---------------- MFMA sequential recurrence (named-register pipeline, raw barriers) ----
#define SEQ_LOAD(Cn, EHx, ELx, FFx, DSx)                                        \
  {                                                                             \
    const bf16* base_ = EF + (size_t)((Cn)*16 + h)*13824 + arow;                \
    _Pragma("unroll")                                                           \
    for (int kt = 0; kt < 2; ++kt) {                                            \
      EHx[kt] = *(const bf16x8*)(base_ + kt*32);                                \
      ELx[kt] = *(const bf16x8*)(base_ + 4608 + kt*32);                         \
      FFx[kt] = *(const bf16x8*)(base_ + 9216 + kt*32);                         \
    }                                                                           \
    const float* db_ = dSl + (size_t)((Cn)*16 + h)*8192 + drow;                 \
    _Pragma("unroll")                                                           \
    for (int nt = 0; nt < 2; ++nt)                                              \
      _Pragma("unroll")                                                         \
      for (int r = 0; r < 4; ++r)                                               \
        DSx[nt*4+r] = db_[(size_t)r*128 + nt*16];                               \
  }

#define SEQ_STEP(Cc, EHc, ELc, FFc, DSc, EHn, ELn, FFn, DSn, SRC, DST)          \
  {                                                                             \
    bf16x8 bh[2][2], bl[2][2];                                                  \
    _Pragma("unroll")                                                           \
    for (int nt = 0; nt < 2; ++nt)                                              \
      _Pragma("unroll")                                                         \
      for (int kt = 0; kt < 2; ++kt) {                                          \
        bh[nt][kt] = *(const bf16x8*)(&Sthi[SRC][(nt*16 + l16)*S72 + kt*32 + quad*8]); \
        bl[nt][kt] = *(const bf16x8*)(&Stlo[SRC][(nt*16 + l16)*S72 + kt*32 + quad*8]); \
      }                                                                         \
    if ((Cc) + 1 < 32) SEQ_LOAD((Cc) + 1, EHn, ELn, FFn, DSn);                  \
    f32x4 a1[2], a2[2], a3[2], o1[2], o2[2];                                    \
    _Pragma("unroll")                                                           \
    for (int nt = 0; nt < 2; ++nt)                                              \
      _Pragma("unroll")                                                         \
      for (int r = 0; r < 4; ++r) {                                             \
        a1[nt][r] = DSc[nt*4+r];                                                \
        a2[nt][r] = 0.f; a3[nt][r] = 0.f; o1[nt][r] = 0.f; o2[nt][r] = 0.f;     \
      }                                                                         \
    _Pragma("unroll")                                                           \
    for (int kt = 0; kt < 2; ++kt)                                              \
      _Pragma("unroll")                                                         \
      for (int nt = 0; nt < 2; ++nt) {                                          \
        a1[nt] = __builtin_amdgcn_mfma_f32_16x16x32_bf16(EHc[kt], bh[nt][kt], a1[nt], 0, 0, 0); \
        a2[nt] = __builtin_amdgcn_mfma_f32_16x16x32_bf16(EHc[kt], bl[nt][kt], a2[nt], 0, 0, 0); \
        a3[nt] = __builtin_amdgcn_mfma_f32_16x16x32_bf16(ELc[kt], bh[nt][kt], a3[nt], 0, 0, 0); \
        o1[nt] = __builtin_amdgcn_mfma_f32_16x16x32_bf16(FFc[kt], bh[nt][kt], o1[nt], 0, 0, 0); \
        o2[nt] = __builtin_amdgcn_mfma_f32_16x16x32_bf16(FFc[kt], bl[nt][kt], o2[nt], 0, 0, 0); \
      }                                                                         \
    {                                                                           \
      int t0c = (Cc)*64;                                                        \
      _Pragma("unroll")                                                         \
      for (int nt = 0; nt < 2; ++nt)                                            \
        _Pragma("unroll")                                                       \
        for (int r = 0; r < 4; ++r)                                             \
          osb[(size_t)(t0c + mb + quad*4 + r)*2048 + h*128 + dq*32 + nt*16 + l16] \
            = o1[nt][r] + o2[nt][r];                                            \
    }                                                                           \
    _Pragma("unroll")                                                           \
    for (int nt = 0; nt < 2; ++nt) {                                            \
      bf16x4v hv, lv;                                                           \
      _Pragma("unroll")                                                         \
      for (int r = 0; r < 4; ++r) {                                             \
        float v = a1[nt][r] + a2[nt][r] + a3[nt][r];                            \
        bf16 hb = (bf16)v;                                                      \
        hv[r] = hb;                                                             \
        lv[r] = (bf16)(v - (float)hb);                                          \
      }                                                                         \
      *(bf16x4v*)(&Sthi[DST][(nt*16 + l16)*S72 + mb + quad*4]) = hv;            \
      *(bf16x4v*)(&Stlo[DST][(nt*16 + l16)*S72 + mb + quad*4]) = lv;            \
    }                                                                           \
    asm volatile("s_waitcnt lgkmcnt(0)" ::: "memory");                          \
    __builtin_amdgcn_s_barrier();                                               \
  }

__global__ __launch_bounds__(256) void k_seq(const bf16* __restrict__ EF,
    const float* __restrict__ dSl, float* __restrict__ osb) {
  const int bid = blockIdx.x;
  const int h = (bid & 7) + 8*((bid >> 3) & 1);
  const int dq = bid >> 4;
  const int tid = threadIdx.x, wave = tid >> 6, lane = tid & 63;
  const int l16 = lane & 15, quad = lane >> 4;
  const int mb = wave * 16;
  __shared__ bf16 Sthi[2][32*S72], Stlo[2][32*S72];
  for (int i = tid; i < 2304; i += 256) { Sthi[0][i] = (bf16)0.f; Stlo[0][i] = (bf16)0.f; }

  const size_t arow = (size_t)(mb + l16)*S72 + quad*8;
  const size_t drow = (size_t)dq*32 + (size_t)(mb + quad*4)*128 + l16;

  bf16x8 ehA[2], elA[2], ffA[2], ehB[2], elB[2], ffB[2];
  float dsA[8], dsB[8];

  SEQ_LOAD(0, ehA, elA, ffA, dsA);
  asm volatile("s_waitcnt lgkmcnt(0)" ::: "memory");
  __builtin_amdgcn_s_barrier();

#pragma unroll 1
  for (int c = 0; c < 32; c += 2) {
    SEQ_STEP(c,     ehA, elA, ffA, dsA, ehB, elB, ffB, dsB, 0, 1);
    SEQ_STEP(c + 1, ehB, elB, ffB, dsB, ehA, elA, ffA, dsA, 1, 0);
  }
}

// ---------------- gated RMSNorm on o = O_loc + O_s, write bf16 ----------------
__global__ __launch_bounds__(256) void k_gatenorm(const float* __restrict__ o,
    const float* __restrict__ os, const bf16* __restrict__ gpre,
    const float* __restrict__ onw, bf16* __restrict__ og) {
  int t = blockIdx.x, wave = threadIdx.x >> 6, lane = threadIdx.x & 63;
  float2 nw = *(const float2*)(onw + lane*2);
#pragma unroll
  for (int hi = 0; hi < 4; ++hi) {
    int hh = wave*4 + hi;
    size_t base = (size_t)t*2048 + hh*128 + lane*2;
    float2 o2 = *(const float2*)(o + base);
    float2 s2 = *(const float2*)(os + base);
    o2.x += s2.x; o2.y += s2.y;
    float ss = wredsum(o2.x*o2.x + o2.y*o2.y);
    float rs = rsqrtf(ss * (1.f/128.f) + 1e-5f);
    bf16x2v g2 = *(const bf16x2v*)(gpre + base);
    float g0 = (float)g2[0], g1 = (float)g2[1];
    float r0 = o2.x * rs * nw.x * (g0 * sigmoidf_(g0));
    float r1 = o2.y * rs * nw.y * (g1 * sigmoidf_(g1));
    bf16x2v b; b[0] = (bf16)r0; b[1] = (bf16)r1;
    *(bf16x2v*)(og + base) = b;
  }
}

extern "C" void kernel_launch(void* const* d_in, const int* in_sizes, int n_in,
                              void* d_out, int out_size, void* d_ws, size_t ws_size,
                              hipStream_t stream) {
  const float* hs   = (const float*)d_in[0];
  const float* nw   = (const float*)d_in[1];
  const float* qw   = (const float*)d_in[2];
  const float* kw   = (const float*)d_in[3];
  const float* vw   = (const float*)d_in[4];
  const float* aw   = (const float*)d_in[5];
  const float* bw   = (const float*)d_in[6];
  const float* gw   = (const float*)d_in[7];
  const float* dtb  = (const float*)d_in[8];
  const float* alog = (const float*)d_in[9];
  const float* cqw  = (const float*)d_in[10];
  const float* ckw  = (const float*)d_in[11];
  const float* cvw  = (const float*)d_in[12];
  const float* onw  = (const float*)d_in[13];
  const float* opw  = (const float*)d_in[14];
  const float* ow   = (const float*)d_in[15];
  float* out = (float*)d_out;

  char* p = (char*)d_ws;
  auto alloc = [&](size_t bytes) { char* r = p; p += (bytes + 255) & ~255ull; return r; };
  bf16*  xb    = (bf16*) alloc((size_t)2048*1024*2);   // } dSl aliases xb..gwb (16 MB,
  bf16*  qwb   = (bf16*) alloc((size_t)1024*1024*2);   // } all dead after k_gemm_proj)
  bf16*  kwb   = (bf16*) alloc((size_t)1024*1024*2);
  bf16*  vwb   = (bf16*) alloc((size_t)2048*1024*2);
  bf16*  gwb   = (bf16*) alloc((size_t)2048*1024*2);
  bf16*  opwb  = (bf16*) alloc((size_t)1024*2048*2);
  bf16*  owb   = (bf16*) alloc((size_t)1024*1024*2);
  bf16*  qpre  = (bf16*) alloc((size_t)2048*1024*2);
  bf16*  kpre  = (bf16*) alloc((size_t)2048*1024*2);
  bf16*  vpre  = (bf16*) alloc((size_t)2048*2048*2);
  bf16*  gpre  = (bf16*) alloc((size_t)2048*2048*2);
  float* graw  = (float*)alloc((size_t)2048*16*4);
  float* btb   = (float*)alloc((size_t)2048*16*4);
  float* ob    = (float*)alloc((size_t)2048*2048*4);
  bf16*  ogb   = (bf16*) alloc((size_t)2048*2048*2);
  bf16*  h1b   = (bf16*) alloc((size_t)2048*1024*2);
  bf16*  EF    = (bf16*) alloc((size_t)512*13824*2);
  float* osb   = (float*)alloc((size_t)512*8192*4);
  float* dSl   = (float*)xb;   // 16 MB over xb..gwb (dead after k_gemm_proj)

  k_pre<<<2048+4608, 256, 0, stream>>>(hs, nw, aw, bw, dtb, alog, xb, graw, btb,
                                       qw, kw, vw, gw, opw, ow,
                                       qwb, kwb, vwb, gwb, opwb, owb);
  k_gemm_proj<<<dim3(48,16,1), 256, 0, stream>>>(xb, qwb, kwb, vwb, gwb, qpre, kpre, vpre, gpre);
  k_prepass<<<512, 512, 0, stream>>>(qpre, kpre, vpre, cqw, ckw, cvw, graw, btb, EF, dSl, ob);
  k_seq<<<64, 256, 0, stream>>>(EF, dSl, osb);
  k_gatenorm<<<2048, 256, 0, stream>>>(ob, osb, gpre, onw, ogb);
  k_gemm_bt64<bf16><<<dim3(16,16,1), 256, 0, stream>>>(ogb, opwb, h1b, 1024, 2048);
  k_gemm_bt64<float><<<dim3(16,16,1), 256, 0, stream>>>(h1b, owb, out, 1024, 1024);
}

// Round 5
// 269.319 us; speedup vs baseline: 1.0084x; 1.0034x over previous
//
#include <hip/hip_runtime.h>
#include <math.h>

#define S72 72

typedef __bf16 bf16;
typedef __bf16 bf16x8 __attribute__((ext_vector_type(8)));
typedef __bf16 bf16x4v __attribute__((ext_vector_type(4)));
typedef __bf16 bf16x2v __attribute__((ext_vector_type(2)));
typedef float f32x4 __attribute__((ext_vector_type(4)));

__device__ __forceinline__ float wredsum(float v) {
#pragma unroll
  for (int off = 32; off > 0; off >>= 1) v += __shfl_xor(v, off, 64);
  return v;
}
__device__ __forceinline__ float sigmoidf_(float x) { return 1.f / (1.f + __expf(-x)); }

// swizzled LDS addressing for 64-col planes: row stride 64, 8-elem chunks XOR'd by row&7
__device__ __forceinline__ int sxy(int row, int col) {
  return (row << 6) + ((((col >> 3) ^ (row & 7)) << 3) | (col & 7));
}
__device__ __forceinline__ int sx8(int row, int chunk) {
  return (row << 6) + ((chunk ^ (row & 7)) << 3);
}

// ---------------- fused: RMSNorm + a/b projections  |  weight cast ----------------
__global__ __launch_bounds__(256) void k_pre(const float* __restrict__ h,
    const float* __restrict__ nw, const float* __restrict__ aw,
    const float* __restrict__ bw, const float* __restrict__ dtb,
    const float* __restrict__ alog, bf16* __restrict__ xb,
    float* __restrict__ graw, float* __restrict__ btb,
    const float* __restrict__ qw, const float* __restrict__ kw,
    const float* __restrict__ vw, const float* __restrict__ gw,
    const float* __restrict__ opw, const float* __restrict__ ow,
    bf16* qwb, bf16* kwb, bf16* vwb, bf16* gwb, bf16* opwb, bf16* owb) {
  __shared__ float red[4];
  __shared__ __align__(16) float xs[1024];
  int tid = threadIdx.x;
  if (blockIdx.x >= 2048) {
    // weight cast part (4608 virtual blocks)
    long cb = blockIdx.x - 2048;
    for (long u = cb*256 + tid; u < 2359296; u += 4608l*256) {
      const float* src; bf16* dst; long l;
      if      (u <  262144) { src=qw;  dst=qwb;  l=u; }
      else if (u <  524288) { src=kw;  dst=kwb;  l=u-262144; }
      else if (u < 1048576) { src=vw;  dst=vwb;  l=u-524288; }
      else if (u < 1572864) { src=gw;  dst=gwb;  l=u-1048576; }
      else if (u < 2097152) { src=opw; dst=opwb; l=u-1572864; }
      else                  { src=ow;  dst=owb;  l=u-2097152; }
      float4 s = *(const float4*)(src + l*4);
      bf16x4v b; b[0]=(bf16)s.x; b[1]=(bf16)s.y; b[2]=(bf16)s.z; b[3]=(bf16)s.w;
      *(bf16x4v*)(dst + l*4) = b;
    }
    return;
  }
  int t = blockIdx.x;
  float4 hv = *(const float4*)(h + (size_t)t*1024 + tid*4);
  float ss = hv.x*hv.x + hv.y*hv.y + hv.z*hv.z + hv.w*hv.w;
  float wsum = wredsum(ss);
  if ((tid & 63) == 0) red[tid >> 6] = wsum;
  __syncthreads();
  float tot = red[0] + red[1] + red[2] + red[3];
  float rs = rsqrtf(tot * (1.f/1024.f) + 1e-6f);
  float4 w4 = *(const float4*)(nw + tid*4);
  float4 y;
  y.x = hv.x*rs*w4.x; y.y = hv.y*rs*w4.y; y.z = hv.z*rs*w4.z; y.w = hv.w*rs*w4.w;
  *(float4*)(xs + tid*4) = y;
  bf16x4v b; b[0]=(bf16)y.x; b[1]=(bf16)y.y; b[2]=(bf16)y.z; b[3]=(bf16)y.w;
  *(bf16x4v*)(xb + (size_t)t*1024 + tid*4) = b;
  __syncthreads();
  int wave = tid >> 6, lane = tid & 63;
  const float4* x4 = (const float4*)xs;
#pragma unroll
  for (int hi = 0; hi < 4; ++hi) {
    int hh = wave*4 + hi;
    float sa = 0.f, sb = 0.f;
#pragma unroll
    for (int i = 0; i < 4; ++i) {
      float4 xv = x4[i*64 + lane];
      float4 av = *(const float4*)(aw + hh*1024 + i*256 + lane*4);
      float4 bv = *(const float4*)(bw + hh*1024 + i*256 + lane*4);
      sa += xv.x*av.x + xv.y*av.y + xv.z*av.z + xv.w*av.w;
      sb += xv.x*bv.x + xv.y*bv.y + xv.z*bv.z + xv.w*bv.w;
    }
    sa = wredsum(sa); sb = wredsum(sb);
    if (lane == 0) {
      float ap = sa + dtb[hh];
      float sp = (ap > 20.f) ? ap : log1pf(expf(ap));
      graw[t*16 + hh] = -expf(alog[hh]) * sp;
      btb[t*16 + hh] = 1.f / (1.f + expf(-sb));
    }
  }
}

// ---------------- bf16 MFMA GEMM 128x128 (double-buffered, XOR-swizzled) ----------------
template <typename OutT>
__device__ __forceinline__ void gemm_body(const bf16* __restrict__ A,
    const bf16* __restrict__ B, OutT* __restrict__ C, int N, int K, int m0, int n0) {
  __shared__ bf16 As[2][128*32];
  __shared__ bf16 Bs[2][128*32];
  const int tid = threadIdx.x, lane = tid & 63, wave = tid >> 6;
  const int wm = (wave >> 1) * 64, wn = (wave & 1) * 64;
  const int srow = wave*16 + (lane >> 2);
  const int swl = (((lane & 3) ^ ((lane >> 3) & 3))) * 8;
  const int sdst = (lane & 3) * 8;
  const int quad = lane >> 4, l16 = lane & 15;
  const int sw = (l16 >> 1) & 3;
  f32x4 acc[4][4] = {};
  const int nk = K >> 5;
#pragma unroll
  for (int i = 0; i < 2; ++i) {
    int r = i*64 + srow;
    __builtin_amdgcn_global_load_lds(
      (__attribute__((address_space(1))) void*)(A + (size_t)(m0 + r)*K + swl),
      (__attribute__((address_space(3))) void*)(&As[0][r*32 + sdst]), 16, 0, 0);
    __builtin_amdgcn_global_load_lds(
      (__attribute__((address_space(1))) void*)(B + (size_t)(n0 + r)*K + swl),
      (__attribute__((address_space(3))) void*)(&Bs[0][r*32 + sdst]), 16, 0, 0);
  }
  for (int kt = 0; kt < nk; ++kt) {
    const int cur = kt & 1;
    __syncthreads();
    bf16x8 af[4], bfr[4];
#pragma unroll
    for (int mt = 0; mt < 4; ++mt)
      af[mt] = *(const bf16x8*)(&As[cur][(wm + mt*16 + l16)*32 + (quad ^ sw)*8]);
#pragma unroll
    for (int nt = 0; nt < 4; ++nt)
      bfr[nt] = *(const bf16x8*)(&Bs[cur][(wn + nt*16 + l16)*32 + (quad ^ sw)*8]);
    if (kt + 1 < nk) {
      int k0 = (kt + 1) << 5;
#pragma unroll
      for (int i = 0; i < 2; ++i) {
        int r = i*64 + srow;
        __builtin_amdgcn_global_load_lds(
          (__attribute__((address_space(1))) void*)(A + (size_t)(m0 + r)*K + k0 + swl),
          (__attribute__((address_space(3))) void*)(&As[cur^1][r*32 + sdst]), 16, 0, 0);
        __builtin_amdgcn_global_load_lds(
          (__attribute__((address_space(1))) void*)(B + (size_t)(n0 + r)*K + k0 + swl),
          (__attribute__((address_space(3))) void*)(&Bs[cur^1][r*32 + sdst]), 16, 0, 0);
      }
    }
#pragma unroll
    for (int mt = 0; mt < 4; ++mt)
#pragma unroll
      for (int nt = 0; nt < 4; ++nt)
        acc[mt][nt] = __builtin_amdgcn_mfma_f32_16x16x32_bf16(af[mt], bfr[nt], acc[mt][nt], 0, 0, 0);
  }
#pragma unroll
  for (int mt = 0; mt < 4; ++mt)
#pragma unroll
    for (int nt = 0; nt < 4; ++nt)
#pragma unroll
      for (int r = 0; r < 4; ++r) {
        int row = m0 + wm + mt*16 + quad*4 + r;
        int col = n0 + wn + nt*16 + l16;
        C[(size_t)row*N + col] = (OutT)acc[mt][nt][r];
      }
}

__global__ __launch_bounds__(256) void k_gemm_proj(const bf16* __restrict__ A,
    const bf16* __restrict__ qwb, const bf16* __restrict__ kwb,
    const bf16* __restrict__ vwb, const bf16* __restrict__ gwb,
    bf16* __restrict__ qpre, bf16* __restrict__ kpre,
    bf16* __restrict__ vpre, bf16* __restrict__ gpre) {
  int bx = blockIdx.x;
  const bf16* B; bf16* C; int N, xt;
  if      (bx <  8) { B = qwb; C = qpre; N = 1024; xt = bx; }
  else if (bx < 16) { B = kwb; C = kpre; N = 1024; xt = bx - 8; }
  else if (bx < 32) { B = vwb; C = vpre; N = 2048; xt = bx - 16; }
  else              { B = gwb; C = gpre; N = 2048; xt = bx - 32; }
  gemm_body<bf16>(A, B, C, N, 1024, blockIdx.y*128, xt*128);
}

// ---------------- bf16 MFMA GEMM 128x64 (2x blocks for tail GEMMs) ----------------
template <typename OutT>
__global__ __launch_bounds__(256) void k_gemm_bt64(const bf16* __restrict__ A,
    const bf16* __restrict__ B, OutT* __restrict__ C, int N, int K) {
  __shared__ bf16 As[2][128*32];
  __shared__ bf16 Bs[2][64*32];
  const int tid = threadIdx.x, lane = tid & 63, wave = tid >> 6;
  const int wm = wave * 32;
  const int srow = wave*16 + (lane >> 2);
  const int swl = (((lane & 3) ^ ((lane >> 3) & 3))) * 8;
  const int sdst = (lane & 3) * 8;
  const int quad = lane >> 4, l16 = lane & 15;
  const int sw = (l16 >> 1) & 3;
  const int m0 = blockIdx.y * 128, n0 = blockIdx.x * 64;
  f32x4 acc[2][4] = {};
  const int nk = K >> 5;
#pragma unroll
  for (int i = 0; i < 2; ++i) {
    int r = i*64 + srow;
    __builtin_amdgcn_global_load_lds(
      (__attribute__((address_space(1))) void*)(A + (size_t)(m0 + r)*K + swl),
      (__attribute__((address_space(3))) void*)(&As[0][r*32 + sdst]), 16, 0, 0);
  }
  __builtin_amdgcn_global_load_lds(
    (__attribute__((address_space(1))) void*)(B + (size_t)(n0 + srow)*K + swl),
    (__attribute__((address_space(3))) void*)(&Bs[0][srow*32 + sdst]), 16, 0, 0);
  for (int kt = 0; kt < nk; ++kt) {
    const int cur = kt & 1;
    __syncthreads();
    bf16x8 af[2], bfr[4];
#pragma unroll
    for (int mt = 0; mt < 2; ++mt)
      af[mt] = *(const bf16x8*)(&As[cur][(wm + mt*16 + l16)*32 + (quad ^ sw)*8]);
#pragma unroll
    for (int nt = 0; nt < 4; ++nt)
      bfr[nt] = *(const bf16x8*)(&Bs[cur][(nt*16 + l16)*32 + (quad ^ sw)*8]);
    if (kt + 1 < nk) {
      int k0 = (kt + 1) << 5;
#pragma unroll
      for (int i = 0; i < 2; ++i) {
        int r = i*64 + srow;
        __builtin_amdgcn_global_load_lds(
          (__attribute__((address_space(1))) void*)(A + (size_t)(m0 + r)*K + k0 + swl),
          (__attribute__((address_space(3))) void*)(&As[cur^1][r*32 + sdst]), 16, 0, 0);
      }
      __builtin_amdgcn_global_load_lds(
        (__attribute__((address_space(1))) void*)(B + (size_t)(n0 + srow)*K + k0 + swl),
        (__attribute__((address_space(3))) void*)(&Bs[cur^1][srow*32 + sdst]), 16, 0, 0);
    }
#pragma unroll
    for (int mt = 0; mt < 2; ++mt)
#pragma unroll
      for (int nt = 0; nt < 4; ++nt)
        acc[mt][nt] = __builtin_amdgcn_mfma_f32_16x16x32_bf16(af[mt], bfr[nt], acc[mt][nt], 0, 0, 0);
  }
#pragma unroll
  for (int mt = 0; mt < 2; ++mt)
#pragma unroll
    for (int nt = 0; nt < 4; ++nt)
#pragma unroll
      for (int r = 0; r < 4; ++r) {
        int row = m0 + wm + mt*16 + quad*4 + r;
        int col = n0 + nt*16 + l16;
        C[(size_t)row*N + col] = (OutT)acc[mt][nt][r];
      }
}

// ---------------- MFMA chunked delta-rule pre-pass (r2 structure: 19 barriers) ----------------
// REVERT NOTE (r4 post-mortem): the 12-barrier phase-merged choreography regressed
// 41 -> 57.5 us (same VALU/MFMA busy-time, +16 us stall). This is the r2 version:
// one small matmul per phase. Plane life-cycle:
//  A:Kr->VT(lo) B:powR0->VT(hi) C:prod0->WR->VlT(lo) D:T2T->VlT(hi)
//  E:powT0->KT  F:powR1->KbT    G:powT1->Pm          H:prod1(Mrow)  Q:qbf
template<int NT>
__device__ __forceinline__ void mm_band(const bf16* A_lds, const bf16* B_lds,
    int w16, int cb, int l16, int quad, f32x4* acc) {
#pragma unroll
  for (int n = 0; n < NT; ++n) { acc[n][0]=0.f; acc[n][1]=0.f; acc[n][2]=0.f; acc[n][3]=0.f; }
#pragma unroll
  for (int kt = 0; kt < 2; ++kt) {
    bf16x8 af = *(const bf16x8*)(A_lds + sx8(w16 + l16, kt*4 + quad));
#pragma unroll
    for (int n = 0; n < NT; ++n) {
      bf16x8 bf = *(const bf16x8*)(B_lds + sx8(cb + n*16 + l16, kt*4 + quad));
      acc[n] = __builtin_amdgcn_mfma_f32_16x16x32_bf16(af, bf, acc[n], 0, 0, 0);
    }
  }
}

__global__ __launch_bounds__(512, 4) void k_prepass(
    const bf16* __restrict__ qpre, const bf16* __restrict__ kpre,
    const bf16* __restrict__ vpre, const float* __restrict__ cqw,
    const float* __restrict__ ckw, const float* __restrict__ cvw,
    const float* __restrict__ graw, const float* __restrict__ beta,
    bf16* __restrict__ EF, float* __restrict__ dSl, float* __restrict__ obuf) {
  const int bx = blockIdx.x, c = bx >> 4, h = bx & 15, tid = threadIdx.x;
  const int t0 = c * 64;
  const int wave = tid >> 6, lane = tid & 63, l16 = lane & 15, quad = lane >> 4;
  const int w16 = (wave >> 1) * 16;
  const int chh = wave & 1;
  const int r0 = wave * 8;

  __shared__ bf16 SM[36864];
  __shared__ float bs[64], bts_s[64], es[64], gms[64];
  bf16* Kr    = SM;            // A
  bf16* powR0 = SM + 4096;     // B
  bf16* prod0 = SM + 8192;     // C
  bf16* T2T   = SM + 12288;    // D
  bf16* powT0 = SM + 16384;    // E
  bf16* powR1 = SM + 20480;    // F
  bf16* powT1 = SM + 24576;    // G
  bf16* prod1 = SM + 28672;    // H
  bf16* qbf   = SM + 32768;    // Q
  bf16* VT   = SM;             // rows 0..127 over A+B
  bf16* VlT  = SM + 8192;      // rows 0..127 over C+D
  bf16* KT   = powT0;
  bf16* KbT  = powR1;
  bf16* Pm   = powT1;
  bf16* WR   = prod0;
  bf16* Mrow = prod1;

  // issue all 44 conv tap loads FIRST so their HBM latency overlaps the scan below
  float4 wq  = *(const float4*)(cqw + (h*64 + lane)*4);
  float4 wk  = *(const float4*)(ckw + (h*64 + lane)*4);
  float4 wv0 = *(const float4*)(cvw + (h*128 + lane)*4);
  float4 wv1 = *(const float4*)(cvw + (h*128 + 64 + lane)*4);
  float qtv[11], ktv[11], vtv0[11], vtv1[11];
#pragma unroll
  for (int j = 0; j < 11; ++j) {
    int tg = t0 + r0 + j - 3;
    bool ok = tg >= 0;
    qtv[j]  = ok ? (float)qpre[(size_t)tg*1024 + h*64 + lane] : 0.f;
    ktv[j]  = ok ? (float)kpre[(size_t)tg*1024 + h*64 + lane] : 0.f;
    vtv0[j] = ok ? (float)vpre[(size_t)tg*2048 + h*128 + lane] : 0.f;
    vtv1[j] = ok ? (float)vpre[(size_t)tg*2048 + h*128 + 64 + lane] : 0.f;
  }

  if (tid < 64) {
    float g = graw[(size_t)(t0 + tid)*16 + h];
    float b = g;
#pragma unroll
    for (int off = 1; off < 64; off <<= 1) {
      float p = __shfl_up(b, off, 64);
      if (tid >= off) b += p;
    }
    bs[tid] = b;
    bts_s[tid] = beta[(size_t)(t0 + tid)*16 + h];
    float b63 = __shfl(b, 63, 64);
    es[tid] = __expf(b63 - b);
    gms[tid] = __expf(b);
  }

  // fused conv(K=4)+silu+norms; wave owns rows r0..r0+7, channel = lane
  float kreg[8], vreg[16];
  {
#pragma unroll
    for (int rr = 0; rr < 8; ++rr) {
      float y = qtv[rr]*wq.x + qtv[rr+1]*wq.y + qtv[rr+2]*wq.z + qtv[rr+3]*wq.w;
      y = y * sigmoidf_(y);
      float ssq = wredsum(y*y);
      y *= rsqrtf(ssq + 1e-6f) * 0.125f;
      qbf[sxy(r0+rr, lane)] = (bf16)y;
    }
#pragma unroll
    for (int rr = 0; rr < 8; ++rr) {
      float y = ktv[rr]*wk.x + ktv[rr+1]*wk.y + ktv[rr+2]*wk.z + ktv[rr+3]*wk.w;
      y = y * sigmoidf_(y);
      // joint (sum, sumsq) butterfly: centered ssq = s2 - s1^2/64
      float s1 = y, s2 = y*y;
#pragma unroll
      for (int off = 32; off > 0; off >>= 1) {
        s1 += __shfl_xor(s1, off, 64);
        s2 += __shfl_xor(s2, off, 64);
      }
      float m = s1 * (1.f/64.f);
      float ssq = s2 - s1*m;
      y -= m;
      y *= rsqrtf(ssq + 1e-6f);
      kreg[rr] = y;
      Kr[sxy(r0+rr, lane)] = (bf16)y;
    }
#pragma unroll
    for (int rr = 0; rr < 8; ++rr) {
      float y0 = vtv0[rr]*wv0.x + vtv0[rr+1]*wv0.y + vtv0[rr+2]*wv0.z + vtv0[rr+3]*wv0.w;
      float y1 = vtv1[rr]*wv1.x + vtv1[rr+1]*wv1.y + vtv1[rr+2]*wv1.z + vtv1[rr+3]*wv1.w;
      vreg[rr]   = y0 * sigmoidf_(y0);
      vreg[8+rr] = y1 * sigmoidf_(y1);
    }
  }
  __syncthreads();

  // A-build: N = -A from K K^T; prod0 = I + N
  {
    f32x4 acc[2];
    mm_band<2>(Kr, Kr, w16, chh*32, l16, quad, acc);
#pragma unroll
    for (int n = 0; n < 2; ++n) {
      int col = chh*32 + n*16 + l16;
      bf16x4v tv;
#pragma unroll
      for (int r = 0; r < 4; ++r) {
        int row = w16 + quad*4 + r;
        float nv = 0.f;
        if (row > col) nv = -bts_s[row] * __expf(bs[row] - bs[col]) * acc[n][r];
        bf16 nb = (bf16)nv;
        powR0[sxy(row, col)] = nb;
        tv[r] = nb;
        prod0[sxy(row, col)] = (row == col) ? (bf16)1.f : nb;
      }
      *(bf16x4v*)(powT0 + sxy(col, w16 + quad*4)) = tv;
    }
  }
  __syncthreads();

  // squaring chain: (I+A)^-1 = prod (I + N^(2^i))
  int pc = 0, rc = 0;
#pragma unroll 1
  for (int i = 1; i <= 5; ++i) {
    bf16* sqA = pc ? powR1 : powR0;
    bf16* sqB = pc ? powT1 : powT0;
    bf16* sqRo = pc ? powR0 : powR1;
    bf16* sqTo = pc ? powT0 : powT1;
    {
      f32x4 acc[2];
      mm_band<2>(sqA, sqB, w16, chh*32, l16, quad, acc);
#pragma unroll
      for (int n = 0; n < 2; ++n) {
        int col = chh*32 + n*16 + l16;
        bf16x4v tv;
#pragma unroll
        for (int r = 0; r < 4; ++r) {
          int row = w16 + quad*4 + r;
          bf16 vb = (bf16)acc[n][r];
          sqRo[sxy(row, col)] = vb;
          tv[r] = vb;
        }
        *(bf16x4v*)(sqTo + sxy(col, w16 + quad*4)) = tv;
      }
    }
    __syncthreads();
    bf16* prA = rc ? prod1 : prod0;
    bf16* prO = rc ? prod0 : prod1;
    {
      f32x4 acc[2];
      mm_band<2>(prA, sqTo, w16, chh*32, l16, quad, acc);
#pragma unroll
      for (int n = 0; n < 2; ++n) {
        int col = chh*32 + n*16 + l16;
        bf16x4v tv;
#pragma unroll
        for (int r = 0; r < 4; ++r) {
          int row = w16 + quad*4 + r;
          float val = acc[n][r] + (float)prA[sxy(row, col)];
          prO[sxy(row, col)] = (bf16)val;
          tv[r] = (bf16)(val * bts_s[col] * gms[col]);
        }
        if (i == 5) *(bf16x4v*)(T2T + sxy(col, w16 + quad*4)) = tv;
      }
    }
    __syncthreads();
    pc ^= 1; rc ^= 1;
  }
  // after chain: Mrow = prod1, pow planes dead

  // KT/KbT from registers; Pm build (reads Kr + qbf)
#pragma unroll
  for (int rr = 0; rr < 8; ++rr) {
    KT[sxy(lane, r0+rr)]  = (bf16)kreg[rr];
    KbT[sxy(lane, r0+rr)] = (bf16)(kreg[rr] * es[r0+rr]);
  }
  {
    f32x4 acc[2];
#pragma unroll
    for (int n = 0; n < 2; ++n) { acc[n][0]=0.f; acc[n][1]=0.f; acc[n][2]=0.f; acc[n][3]=0.f; }
#pragma unroll
    for (int kt = 0; kt < 2; ++kt) {
      bf16x8 af = *(const bf16x8*)(qbf + sx8(w16 + l16, kt*4 + quad));
#pragma unroll
      for (int n = 0; n < 2; ++n) {
        bf16x8 bf = *(const bf16x8*)(Kr + sx8(chh*32 + n*16 + l16, kt*4 + quad));
        acc[n] = __builtin_amdgcn_mfma_f32_16x16x32_bf16(af, bf, acc[n], 0, 0, 0);
      }
    }
#pragma unroll
    for (int n = 0; n < 2; ++n) {
      int col = chh*32 + n*16 + l16;
#pragma unroll
      for (int r = 0; r < 4; ++r) {
        int row = w16 + quad*4 + r;
        float pv = (row >= col) ? __expf(bs[row] - bs[col]) * acc[n][r] : 0.f;
        Pm[sxy(row, col)] = (bf16)pv;
      }
    }
  }
  __syncthreads();

  // W2 = Kbar^T T2 -> WR ; VT from vreg (Kr/powR0 dead)
  {
    f32x4 acc[2];
    mm_band<2>(KbT, T2T, w16, chh*32, l16, quad, acc);
#pragma unroll
    for (int n = 0; n < 2; ++n) {
      int col = chh*32 + n*16 + l16;
#pragma unroll
      for (int r = 0; r < 4; ++r)
        WR[sxy(w16 + quad*4 + r, col)] = (bf16)acc[n][r];
    }
  }
#pragma unroll
  for (int hf = 0; hf < 2; ++hf)
#pragma unroll
    for (int rr = 0; rr < 8; ++rr)
      VT[sxy(hf*64 + lane, r0+rr)] = (bf16)(bts_s[r0+rr] * vreg[hf*8+rr]);
  __syncthreads();
  // E = gamma_C I - W2 K -> EF planes 0/1 (hi/lo)
  {
    f32x4 acc[2];
    mm_band<2>(WR, KT, w16, chh*32, l16, quad, acc);
    float gC = gms[63];
    size_t eb = (size_t)bx * 13824;
#pragma unroll
    for (int n = 0; n < 2; ++n) {
      int col = chh*32 + n*16 + l16;
#pragma unroll
      for (int r = 0; r < 4; ++r) {
        int row = w16 + quad*4 + r;
        float ev = ((row == col) ? gC : 0.f) - acc[n][r];
        bf16 eh = (bf16)ev;
        EF[eb + row*S72 + col] = eh;
        EF[eb + 4608 + row*S72 + col] = (bf16)(ev - (float)eh);
      }
    }
  }
  __syncthreads();
  // R = P T2 -> WR
  {
    f32x4 acc[2];
    mm_band<2>(Pm, T2T, w16, chh*32, l16, quad, acc);
#pragma unroll
    for (int n = 0; n < 2; ++n) {
      int col = chh*32 + n*16 + l16;
#pragma unroll
      for (int r = 0; r < 4; ++r)
        WR[sxy(w16 + quad*4 + r, col)] = (bf16)acc[n][r];
    }
  }
  __syncthreads();
  // F = diag(gamma) Q - R K -> EF plane 2
  {
    f32x4 acc[2];
    mm_band<2>(WR, KT, w16, chh*32, l16, quad, acc);
    size_t eb = (size_t)bx * 13824;
#pragma unroll
    for (int n = 0; n < 2; ++n) {
      int col = chh*32 + n*16 + l16;
#pragma unroll
      for (int r = 0; r < 4; ++r) {
        int row = w16 + quad*4 + r;
        float qv = (float)qbf[sxy(row, col)];
        EF[eb + 9216 + row*S72 + col] = (bf16)(gms[row]*qv - acc[n][r]);
      }
    }
  }
  __syncthreads();   // WR/T2T reads done before VlT overwrites C+D
  // V_loc = M (beta V): write V_loc^T into VlT
  {
    f32x4 acc[4];
    mm_band<4>(Mrow, VT, w16, chh*64, l16, quad, acc);
#pragma unroll
    for (int n = 0; n < 4; ++n) {
      int col = chh*64 + n*16 + l16;
      bf16x4v tv;
#pragma unroll
      for (int r = 0; r < 4; ++r) tv[r] = (bf16)acc[n][r];
      *(bf16x4v*)(VlT + sxy(col, w16 + quad*4)) = tv;
    }
  }
  __syncthreads();
  // dS_loc = Kbar^T V_loc ; O_loc = P V_loc
  {
    f32x4 acc[4];
    mm_band<4>(KbT, VlT, w16, chh*64, l16, quad, acc);
#pragma unroll
    for (int n = 0; n < 4; ++n) {
      int col = chh*64 + n*16 + l16;
#pragma unroll
      for (int r = 0; r < 4; ++r)
        dSl[(size_t)bx*8192 + (size_t)(w16 + quad*4 + r)*128 + col] = acc[n][r];
    }
  }
  {
    f32x4 acc[4];
    mm_band<4>(Pm, VlT, w16, chh*64, l16, quad, acc);
#pragma unroll
    for (int n = 0; n < 4; ++n) {
      int col = chh*64 + n*16 + l16;
#pragma unroll
      for (int r = 0; r < 4; ++r)
        obuf[(size_t)(t0 + w16 + quad*4 + r)*2048 + h*128 + col] = acc[n][r];
    }
  }
}

// ---------------- MFMA sequential recurrence (named-register pipeline, raw barriers) ----
#define SEQ_LOAD(Cn, EHx, ELx, FFx, DSx)                                        \
  {                                                                             \
    const bf16* base_ = EF + (size_t)((Cn)*16 + h)*13824 + arow;                \
    _Pragma("unroll")                                                           \
    for (int kt = 0; kt < 2; ++kt) {                                            \
      EHx[kt] = *(const bf16x8*)(base_ + kt*32);                                \
      ELx[kt] = *(const bf16x8*)(base_ + 4608 + kt*32);                         \
      FFx[kt] = *(const bf16x8*)(base_ + 9216 + kt*32);                         \
    }                                                                           \
    const float* db_ = dSl + (size_t)((Cn)*16 + h)*8192 + drow;                 \
    _Pragma("unroll")                                                           \
    for (int nt = 0; nt < 2; ++nt)                                              \
      _Pragma("unroll")                                                         \
      for (int r = 0; r < 4; ++r)                                               \
        DSx[nt*4+r] = db_[(size_t)r*128 + nt*16];                               \
  }

#define SEQ_STEP(Cc, EHc, ELc, FFc, DSc, EHn, ELn, FFn, DSn, SRC, DST)          \
  {                                                                             \
    bf16x8 bh[2][2], bl[2][2];                                                  \
    _Pragma("unroll")                                                           \
    for (int nt = 0; nt < 2; ++nt)                                              \
      _Pragma("unroll")                                                         \
      for (int kt = 0; kt < 2; ++kt) {                                          \
        bh[nt][kt] = *(const bf16x8*)(&Sthi[SRC][(nt*16 + l16)*S72 + kt*32 + quad*8]); \
        bl[nt][kt] = *(const bf16x8*)(&Stlo[SRC][(nt*16 + l16)*S72 + kt*32 + quad*8]); \
      }                                                                         \
    if ((Cc) + 1 < 32) SEQ_LOAD((Cc) + 1, EHn, ELn, FFn, DSn);                  \
    f32x4 a1[2], a2[2], a3[2], o1[2], o2[2];                                    \
    _Pragma("unroll")                                                           \
    for (int nt = 0; nt < 2; ++nt)                                              \
      _Pragma("unroll")                                                         \
      for (int r = 0; r < 4; ++r) {                                             \
        a1[nt][r] = DSc[nt*4+r];                                                \
        a2[nt][r] = 0.f; a3[nt][r] = 0.f; o1[nt][r] = 0.f; o2[nt][r] = 0.f;     \
      }                                                                         \
    _Pragma("unroll")                                                           \
    for (int kt = 0; kt < 2; ++kt)                                              \
      _Pragma("unroll")                                                         \
      for (int nt = 0; nt < 2; ++nt) {                                          \
        a1[nt] = __builtin_amdgcn_mfma_f32_16x16x32_bf16(EHc[kt], bh[nt][kt], a1[nt], 0, 0, 0); \
        a2[nt] = __builtin_amdgcn_mfma_f32_16x16x32_bf16(EHc[kt], bl[nt][kt], a2[nt], 0, 0, 0); \
        a3[nt] = __builtin_amdgcn_mfma_f32_16x16x32_bf16(ELc[kt], bh[nt][kt], a3[nt], 0, 0, 0); \
        o1[nt] = __builtin_amdgcn_mfma_f32_16x16x32_bf16(FFc[kt], bh[nt][kt], o1[nt], 0, 0, 0); \
        o2[nt] = __builtin_amdgcn_mfma_f32_16x16x32_bf16(FFc[kt], bl[nt][kt], o2[nt], 0, 0, 0); \
      }                                                                         \
    {                                                                           \
      int t0c = (Cc)*64;                                                        \
      _Pragma("unroll")                                                         \
      for (int nt = 0; nt < 2; ++nt)                                            \
        _Pragma("unroll")                                                       \
        for (int r = 0; r < 4; ++r)                                             \
          osb[(size_t)(t0c + mb + quad*4 + r)*2048 + h*128 + dq*32 + nt*16 + l16] \
            = o1[nt][r] + o2[nt][r];                                            \
    }                                                                           \
    _Pragma("unroll")                                                           \
    for (int nt = 0; nt < 2; ++nt) {                                            \
      bf16x4v hv, lv;                                                           \
      _Pragma("unroll")                                                         \
      for (int r = 0; r < 4; ++r) {                                             \
        float v = a1[nt][r] + a2[nt][r] + a3[nt][r];                            \
        bf16 hb = (bf16)v;                                                      \
        hv[r] = hb;                                                             \
        lv[r] = (bf16)(v - (float)hb);                                          \
      }                                                                         \
      *(bf16x4v*)(&Sthi[DST][(nt*16 + l16)*S72 + mb + quad*4]) = hv;            \
      *(bf16x4v*)(&Stlo[DST][(nt*16 + l16)*S72 + mb + quad*4]) = lv;            \
    }                                                                           \
    asm volatile("s_waitcnt lgkmcnt(0)" ::: "memory");                          \
    __builtin_amdgcn_s_barrier();                                               \
  }

__global__ __launch_bounds__(256) void k_seq(const bf16* __restrict__ EF,
    const float* __restrict__ dSl, float* __restrict__ osb) {
  const int bid = blockIdx.x;
  const int h = (bid & 7) + 8*((bid >> 3) & 1);
  const int dq = bid >> 4;
  const int tid = threadIdx.x, wave = tid >> 6, lane = tid & 63;
  const int l16 = lane & 15, quad = lane >> 4;
  const int mb = wave * 16;
  __shared__ bf16 Sthi[2][32*S72], Stlo[2][32*S72];
  for (int i = tid; i < 2304; i += 256) { Sthi[0][i] = (bf16)0.f; Stlo[0][i] = (bf16)0.f; }

  const size_t arow = (size_t)(mb + l16)*S72 + quad*8;
  const size_t drow = (size_t)dq*32 + (size_t)(mb + quad*4)*128 + l16;

  bf16x8 ehA[2], elA[2], ffA[2], ehB[2], elB[2], ffB[2];
  float dsA[8], dsB[8];

  SEQ_LOAD(0, ehA, elA, ffA, dsA);
  asm volatile("s_waitcnt lgkmcnt(0)" ::: "memory");
  __builtin_amdgcn_s_barrier();

#pragma unroll 1
  for (int c = 0; c < 32; c += 2) {
    SEQ_STEP(c,     ehA, elA, ffA, dsA, ehB, elB, ffB, dsB, 0, 1);
    SEQ_STEP(c + 1, ehB, elB, ffB, dsB, ehA, elA, ffA, dsA, 1, 0);
  }
}

// ---------------- gated RMSNorm on o = O_loc + O_s, write bf16 ----------------
__global__ __launch_bounds__(256) void k_gatenorm(const float* __restrict__ o,
    const float* __restrict__ os, const bf16* __restrict__ gpre,
    const float* __restrict__ onw, bf16* __restrict__ og) {
  int t = blockIdx.x, wave = threadIdx.x >> 6, lane = threadIdx.x & 63;
  float2 nw = *(const float2*)(onw + lane*2);
#pragma unroll
  for (int hi = 0; hi < 4; ++hi) {
    int hh = wave*4 + hi;
    size_t base = (size_t)t*2048 + hh*128 + lane*2;
    float2 o2 = *(const float2*)(o + base);
    float2 s2 = *(const float2*)(os + base);
    o2.x += s2.x; o2.y += s2.y;
    float ss = wredsum(o2.x*o2.x + o2.y*o2.y);
    float rs = rsqrtf(ss * (1.f/128.f) + 1e-5f);
    bf16x2v g2 = *(const bf16x2v*)(gpre + base);
    float g0 = (float)g2[0], g1 = (float)g2[1];
    float r0 = o2.x * rs * nw.x * (g0 * sigmoidf_(g0));
    float r1 = o2.y * rs * nw.y * (g1 * sigmoidf_(g1));
    bf16x2v b; b[0] = (bf16)r0; b[1] = (bf16)r1;
    *(bf16x2v*)(og + base) = b;
  }
}

extern "C" void kernel_launch(void* const* d_in, const int* in_sizes, int n_in,
                              void* d_out, int out_size, void* d_ws, size_t ws_size,
                              hipStream_t stream) {
  const float* hs   = (const float*)d_in[0];
  const float* nw   = (const float*)d_in[1];
  const float* qw   = (const float*)d_in[2];
  const float* kw   = (const float*)d_in[3];
  const float* vw   = (const float*)d_in[4];
  const float* aw   = (const float*)d_in[5];
  const float* bw   = (const float*)d_in[6];
  const float* gw   = (const float*)d_in[7];
  const float* dtb  = (const float*)d_in[8];
  const float* alog = (const float*)d_in[9];
  const float* cqw  = (const float*)d_in[10];
  const float* ckw  = (const float*)d_in[11];
  const float* cvw  = (const float*)d_in[12];
  const float* onw  = (const float*)d_in[13];
  const float* opw  = (const float*)d_in[14];
  const float* ow   = (const float*)d_in[15];
  float* out = (float*)d_out;

  char* p = (char*)d_ws;
  auto alloc = [&](size_t bytes) { char* r = p; p += (bytes + 255) & ~255ull; return r; };
  bf16*  xb    = (bf16*) alloc((size_t)2048*1024*2);   // } dSl aliases xb..gwb (16 MB,
  bf16*  qwb   = (bf16*) alloc((size_t)1024*1024*2);   // } all dead after k_gemm_proj)
  bf16*  kwb   = (bf16*) alloc((size_t)1024*1024*2);
  bf16*  vwb   = (bf16*) alloc((size_t)2048*1024*2);
  bf16*  gwb   = (bf16*) alloc((size_t)2048*1024*2);
  bf16*  opwb  = (bf16*) alloc((size_t)1024*2048*2);
  bf16*  owb   = (bf16*) alloc((size_t)1024*1024*2);
  bf16*  qpre  = (bf16*) alloc((size_t)2048*1024*2);
  bf16*  kpre  = (bf16*) alloc((size_t)2048*1024*2);
  bf16*  vpre  = (bf16*) alloc((size_t)2048*2048*2);
  bf16*  gpre  = (bf16*) alloc((size_t)2048*2048*2);
  float* graw  = (float*)alloc((size_t)2048*16*4);
  float* btb   = (float*)alloc((size_t)2048*16*4);
  float* ob    = (float*)alloc((size_t)2048*2048*4);
  bf16*  ogb   = (bf16*) alloc((size_t)2048*2048*2);
  bf16*  h1b   = (bf16*) alloc((size_t)2048*1024*2);
  bf16*  EF    = (bf16*) alloc((size_t)512*13824*2);
  float* osb   = (float*)alloc((size_t)512*8192*4);
  float* dSl   = (float*)xb;   // 16 MB over xb..gwb (dead after k_gemm_proj)

  k_pre<<<2048+4608, 256, 0, stream>>>(hs, nw, aw, bw, dtb, alog, xb, graw, btb,
                                       qw, kw, vw, gw, opw, ow,
                                       qwb, kwb, vwb, gwb, opwb, owb);
  k_gemm_proj<<<dim3(48,16,1), 256, 0, stream>>>(xb, qwb, kwb, vwb, gwb, qpre, kpre, vpre, gpre);
  k_prepass<<<512, 512, 0, stream>>>(qpre, kpre, vpre, cqw, ckw, cvw, graw, btb, EF, dSl, ob);
  k_seq<<<64, 256, 0, stream>>>(EF, dSl, osb);
  k_gatenorm<<<2048, 256, 0, stream>>>(ob, osb, gpre, onw, ogb);
  k_gemm_bt64<bf16><<<dim3(16,16,1), 256, 0, stream>>>(ogb, opwb, h1b, 1024, 2048);
  k_gemm_bt64<float><<<dim3(16,16,1), 256, 0, stream>>>(h1b, owb, out, 1024, 1024);
}

// Round 6
// 266.108 us; speedup vs baseline: 1.0205x; 1.0121x over previous
//
#include <hip/hip_runtime.h>
#include <math.h>

#define S72 72

typedef __bf16 bf16;
typedef __bf16 bf16x8 __attribute__((ext_vector_type(8)));
typedef __bf16 bf16x4v __attribute__((ext_vector_type(4)));
typedef __bf16 bf16x2v __attribute__((ext_vector_type(2)));
typedef float f32x4 __attribute__((ext_vector_type(4)));

__device__ __forceinline__ float wredsum(float v) {
#pragma unroll
  for (int off = 32; off > 0; off >>= 1) v += __shfl_xor(v, off, 64);
  return v;
}
__device__ __forceinline__ float sigmoidf_(float x) { return 1.f / (1.f + __expf(-x)); }

// swizzled LDS addressing for 64-col planes: row stride 64, 8-elem chunks XOR'd by row&7
__device__ __forceinline__ int sxy(int row, int col) {
  return (row << 6) + ((((col >> 3) ^ (row & 7)) << 3) | (col & 7));
}
__device__ __forceinline__ int sx8(int row, int chunk) {
  return (row << 6) + ((chunk ^ (row & 7)) << 3);
}

// ---------------- fused: RMSNorm + a/b projections  |  weight cast ----------------
__global__ __launch_bounds__(256) void k_pre(const float* __restrict__ h,
    const float* __restrict__ nw, const float* __restrict__ aw,
    const float* __restrict__ bw, const float* __restrict__ dtb,
    const float* __restrict__ alog, bf16* __restrict__ xb,
    float* __restrict__ graw, float* __restrict__ btb,
    const float* __restrict__ qw, const float* __restrict__ kw,
    const float* __restrict__ vw, const float* __restrict__ gw,
    const float* __restrict__ opw, const float* __restrict__ ow,
    bf16* qwb, bf16* kwb, bf16* vwb, bf16* gwb, bf16* opwb, bf16* owb) {
  __shared__ float red[4];
  __shared__ __align__(16) float xs[1024];
  int tid = threadIdx.x;
  if (blockIdx.x >= 2048) {
    // weight cast part (4608 virtual blocks)
    long cb = blockIdx.x - 2048;
    for (long u = cb*256 + tid; u < 2359296; u += 4608l*256) {
      const float* src; bf16* dst; long l;
      if      (u <  262144) { src=qw;  dst=qwb;  l=u; }
      else if (u <  524288) { src=kw;  dst=kwb;  l=u-262144; }
      else if (u < 1048576) { src=vw;  dst=vwb;  l=u-524288; }
      else if (u < 1572864) { src=gw;  dst=gwb;  l=u-1048576; }
      else if (u < 2097152) { src=opw; dst=opwb; l=u-1572864; }
      else                  { src=ow;  dst=owb;  l=u-2097152; }
      float4 s = *(const float4*)(src + l*4);
      bf16x4v b; b[0]=(bf16)s.x; b[1]=(bf16)s.y; b[2]=(bf16)s.z; b[3]=(bf16)s.w;
      *(bf16x4v*)(dst + l*4) = b;
    }
    return;
  }
  int t = blockIdx.x;
  float4 hv = *(const float4*)(h + (size_t)t*1024 + tid*4);
  float ss = hv.x*hv.x + hv.y*hv.y + hv.z*hv.z + hv.w*hv.w;
  float wsum = wredsum(ss);
  if ((tid & 63) == 0) red[tid >> 6] = wsum;
  __syncthreads();
  float tot = red[0] + red[1] + red[2] + red[3];
  float rs = rsqrtf(tot * (1.f/1024.f) + 1e-6f);
  float4 w4 = *(const float4*)(nw + tid*4);
  float4 y;
  y.x = hv.x*rs*w4.x; y.y = hv.y*rs*w4.y; y.z = hv.z*rs*w4.z; y.w = hv.w*rs*w4.w;
  *(float4*)(xs + tid*4) = y;
  bf16x4v b; b[0]=(bf16)y.x; b[1]=(bf16)y.y; b[2]=(bf16)y.z; b[3]=(bf16)y.w;
  *(bf16x4v*)(xb + (size_t)t*1024 + tid*4) = b;
  __syncthreads();
  int wave = tid >> 6, lane = tid & 63;
  const float4* x4 = (const float4*)xs;
#pragma unroll
  for (int hi = 0; hi < 4; ++hi) {
    int hh = wave*4 + hi;
    float sa = 0.f, sb = 0.f;
#pragma unroll
    for (int i = 0; i < 4; ++i) {
      float4 xv = x4[i*64 + lane];
      float4 av = *(const float4*)(aw + hh*1024 + i*256 + lane*4);
      float4 bv = *(const float4*)(bw + hh*1024 + i*256 + lane*4);
      sa += xv.x*av.x + xv.y*av.y + xv.z*av.z + xv.w*av.w;
      sb += xv.x*bv.x + xv.y*bv.y + xv.z*bv.z + xv.w*bv.w;
    }
    sa = wredsum(sa); sb = wredsum(sb);
    if (lane == 0) {
      float ap = sa + dtb[hh];
      float sp = (ap > 20.f) ? ap : log1pf(expf(ap));
      graw[t*16 + hh] = -expf(alog[hh]) * sp;
      btb[t*16 + hh] = 1.f / (1.f + expf(-sb));
    }
  }
}

// ---------------- bf16 MFMA GEMM 256x256 / BK=64 / 4-phase schedule (T3+T4+T5) --------
// 8 waves (2M x 4N), per-wave 128x64 output. LDS 128 KB: [buf][A/B][half 128rows][64col].
// Per K-tile: 4 phases = C-quadrants (mh,nh) = (0,0),(0,1),(1,1),(1,0); each phase
// {ds_read frags | stage half-tiles of kt+1} -> s_barrier -> lgkmcnt(0)+sched_barrier
// -> setprio(1) -> 16 MFMA -> setprio(0) -> s_barrier. All of kt+1's staging issues in
// phases 0-1, so the single end-of-tile vmcnt(0) is >=2 phases (~1200cy) after last
// issue -> drain is free (unlike 128x128 2-phase where issue-to-drain ~300cy < HBM 900).
// Swizzle: LDS[row][c] = G[row][c ^ (row&7)] (source-side), read at c = want ^ (l16&7).
#define PROJ_STAGE_HALF(BUF, MAT, HALF, GBASE)                                   \
  { _Pragma("unroll")                                                            \
    for (int rd_ = 0; rd_ < 2; ++rd_) {                                          \
      int row_ = srow + rd_*64;                                                  \
      __builtin_amdgcn_global_load_lds(                                          \
        (__attribute__((address_space(1))) void*)((GBASE) + (size_t)row_*1024 + ((schk ^ (row_ & 7))*8)), \
        (__attribute__((address_space(3))) void*)(&S[BUF][MAT][HALF][row_*64 + schk*8]), \
        16, 0, 0);                                                               \
    } }

#define PROJ_LDA(BUF, MT, KS) \
  (*(const bf16x8*)(&S[BUF][0][(wm + (MT)*16) >> 7][((wm + (MT)*16 + l16) & 127)*64 + ((((KS)*4 + quad) ^ (l16 & 7))*8)]))
#define PROJ_LDB(BUF, NT, KS) \
  (*(const bf16x8*)(&S[BUF][1][(wn + (NT)*16) >> 7][((wn + (NT)*16 + l16) & 127)*64 + ((((KS)*4 + quad) ^ (l16 & 7))*8)]))

__global__ __launch_bounds__(512, 2) void k_gemm_proj(const bf16* __restrict__ A,
    const bf16* __restrict__ qwb, const bf16* __restrict__ kwb,
    const bf16* __restrict__ vwb, const bf16* __restrict__ gwb,
    bf16* __restrict__ qpre, bf16* __restrict__ kpre,
    bf16* __restrict__ vpre, bf16* __restrict__ gpre) {
  // XCD-aware remap: dispatch index d -> XCD d%8; same-XCD blocks share one A row-panel
  const int d = blockIdx.y * 24 + blockIdx.x;    // 192 blocks, 192%8==0 -> bijective
  const int by = d & 7, bx = d >> 3;
  const bf16* B; bf16* C; int N, xt;
  if      (bx <  4) { B = qwb; C = qpre; N = 1024; xt = bx; }
  else if (bx <  8) { B = kwb; C = kpre; N = 1024; xt = bx - 4; }
  else if (bx < 16) { B = vwb; C = vpre; N = 2048; xt = bx - 8; }
  else              { B = gwb; C = gpre; N = 2048; xt = bx - 16; }
  const int m0 = by * 256, n0 = xt * 256;

  __shared__ bf16 S[2][2][2][128*64];   // 131072 B

  const int tid = threadIdx.x, lane = tid & 63, wave = tid >> 6;
  const int l16 = lane & 15, quad = lane >> 4;
  const int wm = (wave >> 2) * 128, wn = (wave & 3) * 64;
  const int srow = tid >> 3, schk = tid & 7;

  f32x4 acc[8][4] = {};

  // prologue: stage tile 0 into buf 0, drain once
  PROJ_STAGE_HALF(0, 0, 0, A + (size_t)m0*1024);
  PROJ_STAGE_HALF(0, 0, 1, A + (size_t)(m0+128)*1024);
  PROJ_STAGE_HALF(0, 1, 0, B + (size_t)n0*1024);
  PROJ_STAGE_HALF(0, 1, 1, B + (size_t)(n0+128)*1024);
  asm volatile("s_waitcnt vmcnt(0)" ::: "memory");
  __builtin_amdgcn_sched_barrier(0);
  __builtin_amdgcn_s_barrier();

#pragma unroll 1
  for (int kt = 0; kt < 16; ++kt) {
    const int cur = kt & 1, nxt = cur ^ 1;
    const bool pf = (kt + 1 < 16);
    const size_t knext = (size_t)(kt + 1) * 64;
    bf16x8 af[4][2], b0[2][2], b1[2][2];

    // ---- phase 0: quadrant (mh0, nh0); stage A halves of kt+1 ----
#pragma unroll
    for (int m = 0; m < 4; ++m) { af[m][0] = PROJ_LDA(cur, m, 0); af[m][1] = PROJ_LDA(cur, m, 1); }
#pragma unroll
    for (int n = 0; n < 2; ++n) { b0[n][0] = PROJ_LDB(cur, n, 0); b0[n][1] = PROJ_LDB(cur, n, 1); }
    if (pf) {
      PROJ_STAGE_HALF(nxt, 0, 0, A + (size_t)m0*1024 + knext);
      PROJ_STAGE_HALF(nxt, 0, 1, A + (size_t)(m0+128)*1024 + knext);
    }
    __builtin_amdgcn_s_barrier();
    asm volatile("s_waitcnt lgkmcnt(0)" ::: "memory");
    __builtin_amdgcn_sched_barrier(0);
    __builtin_amdgcn_s_setprio(1);
#pragma unroll
    for (int ks = 0; ks < 2; ++ks)
#pragma unroll
      for (int m = 0; m < 4; ++m)
#pragma unroll
        for (int n = 0; n < 2; ++n)
          acc[m][n] = __builtin_amdgcn_mfma_f32_16x16x32_bf16(af[m][ks], b0[n][ks], acc[m][n], 0, 0, 0);
    __builtin_amdgcn_s_setprio(0);
    __builtin_amdgcn_s_barrier();

    // ---- phase 1: quadrant (mh0, nh1); stage B halves of kt+1 ----
#pragma unroll
    for (int n = 0; n < 2; ++n) { b1[n][0] = PROJ_LDB(cur, 2+n, 0); b1[n][1] = PROJ_LDB(cur, 2+n, 1); }
    if (pf) {
      PROJ_STAGE_HALF(nxt, 1, 0, B + (size_t)n0*1024 + knext);
      PROJ_STAGE_HALF(nxt, 1, 1, B + (size_t)(n0+128)*1024 + knext);
    }
    __builtin_amdgcn_s_barrier();
    asm volatile("s_waitcnt lgkmcnt(0)" ::: "memory");
    __builtin_amdgcn_sched_barrier(0);
    __builtin_amdgcn_s_setprio(1);
#pragma unroll
    for (int ks = 0; ks < 2; ++ks)
#pragma unroll
      for (int m = 0; m < 4; ++m)
#pragma unroll
        for (int n = 0; n < 2; ++n)
          acc[m][2+n] = __builtin_amdgcn_mfma_f32_16x16x32_bf16(af[m][ks], b1[n][ks], acc[m][2+n], 0, 0, 0);
    __builtin_amdgcn_s_setprio(0);
    __builtin_amdgcn_s_barrier();

    // ---- phase 2: quadrant (mh1, nh1); reload A frags for mt 4..7 ----
#pragma unroll
    for (int m = 0; m < 4; ++m) { af[m][0] = PROJ_LDA(cur, 4+m, 0); af[m][1] = PROJ_LDA(cur, 4+m, 1); }
    __builtin_amdgcn_s_barrier();
    asm volatile("s_waitcnt lgkmcnt(0)" ::: "memory");
    __builtin_amdgcn_sched_barrier(0);
    __builtin_amdgcn_s_setprio(1);
#pragma unroll
    for (int ks = 0; ks < 2; ++ks)
#pragma unroll
      for (int m = 0; m < 4; ++m)
#pragma unroll
        for (int n = 0; n < 2; ++n)
          acc[4+m][2+n] = __builtin_amdgcn_mfma_f32_16x16x32_bf16(af[m][ks], b1[n][ks], acc[4+m][2+n], 0, 0, 0);
    __builtin_amdgcn_s_setprio(0);
    __builtin_amdgcn_s_barrier();

    // ---- phase 3: quadrant (mh1, nh0); end-of-tile vmcnt (loads issued >=2 phases ago) ----
    __builtin_amdgcn_s_setprio(1);
#pragma unroll
    for (int ks = 0; ks < 2; ++ks)
#pragma unroll
      for (int m = 0; m < 4; ++m)
#pragma unroll
        for (int n = 0; n < 2; ++n)
          acc[4+m][n] = __builtin_amdgcn_mfma_f32_16x16x32_bf16(af[m][ks], b0[n][ks], acc[4+m][n], 0, 0, 0);
    __builtin_amdgcn_s_setprio(0);
    if (pf) {
      asm volatile("s_waitcnt vmcnt(0)" ::: "memory");
      __builtin_amdgcn_sched_barrier(0);
    }
    __builtin_amdgcn_s_barrier();
  }

#pragma unroll
  for (int mt = 0; mt < 8; ++mt)
#pragma unroll
    for (int nt = 0; nt < 4; ++nt)
#pragma unroll
      for (int r = 0; r < 4; ++r) {
        int row = m0 + wm + mt*16 + quad*4 + r;
        int col = n0 + wn + nt*16 + l16;
        C[(size_t)row*N + col] = (bf16)acc[mt][nt][r];
      }
}

// ---------------- bf16 MFMA GEMM 128x64 (2x blocks for tail GEMMs) ----------------
template <typename OutT>
__global__ __launch_bounds__(256) void k_gemm_bt64(const bf16* __restrict__ A,
    const bf16* __restrict__ B, OutT* __restrict__ C, int N, int K) {
  __shared__ bf16 As[2][128*32];
  __shared__ bf16 Bs[2][64*32];
  const int tid = threadIdx.x, lane = tid & 63, wave = tid >> 6;
  const int wm = wave * 32;
  const int srow = wave*16 + (lane >> 2);
  const int swl = (((lane & 3) ^ ((lane >> 3) & 3))) * 8;
  const int sdst = (lane & 3) * 8;
  const int quad = lane >> 4, l16 = lane & 15;
  const int sw = (l16 >> 1) & 3;
  const int m0 = blockIdx.y * 128, n0 = blockIdx.x * 64;
  f32x4 acc[2][4] = {};
  const int nk = K >> 5;
#pragma unroll
  for (int i = 0; i < 2; ++i) {
    int r = i*64 + srow;
    __builtin_amdgcn_global_load_lds(
      (__attribute__((address_space(1))) void*)(A + (size_t)(m0 + r)*K + swl),
      (__attribute__((address_space(3))) void*)(&As[0][r*32 + sdst]), 16, 0, 0);
  }
  __builtin_amdgcn_global_load_lds(
    (__attribute__((address_space(1))) void*)(B + (size_t)(n0 + srow)*K + swl),
    (__attribute__((address_space(3))) void*)(&Bs[0][srow*32 + sdst]), 16, 0, 0);
  for (int kt = 0; kt < nk; ++kt) {
    const int cur = kt & 1;
    __syncthreads();
    bf16x8 af[2], bfr[4];
#pragma unroll
    for (int mt = 0; mt < 2; ++mt)
      af[mt] = *(const bf16x8*)(&As[cur][(wm + mt*16 + l16)*32 + (quad ^ sw)*8]);
#pragma unroll
    for (int nt = 0; nt < 4; ++nt)
      bfr[nt] = *(const bf16x8*)(&Bs[cur][(nt*16 + l16)*32 + (quad ^ sw)*8]);
    if (kt + 1 < nk) {
      int k0 = (kt + 1) << 5;
#pragma unroll
      for (int i = 0; i < 2; ++i) {
        int r = i*64 + srow;
        __builtin_amdgcn_global_load_lds(
          (__attribute__((address_space(1))) void*)(A + (size_t)(m0 + r)*K + k0 + swl),
          (__attribute__((address_space(3))) void*)(&As[cur^1][r*32 + sdst]), 16, 0, 0);
      }
      __builtin_amdgcn_global_load_lds(
        (__attribute__((address_space(1))) void*)(B + (size_t)(n0 + srow)*K + k0 + swl),
        (__attribute__((address_space(3))) void*)(&Bs[cur^1][srow*32 + sdst]), 16, 0, 0);
    }
#pragma unroll
    for (int mt = 0; mt < 2; ++mt)
#pragma unroll
      for (int nt = 0; nt < 4; ++nt)
        acc[mt][nt] = __builtin_amdgcn_mfma_f32_16x16x32_bf16(af[mt], bfr[nt], acc[mt][nt], 0, 0, 0);
  }
#pragma unroll
  for (int mt = 0; mt < 2; ++mt)
#pragma unroll
    for (int nt = 0; nt < 4; ++nt)
#pragma unroll
      for (int r = 0; r < 4; ++r) {
        int row = m0 + wm + mt*16 + quad*4 + r;
        int col = n0 + nt*16 + l16;
        C[(size_t)row*N + col] = (OutT)acc[mt][nt][r];
      }
}

// ---------------- MFMA chunked delta-rule pre-pass (r2 structure: 19 barriers) ----------------
template<int NT>
__device__ __forceinline__ void mm_band(const bf16* A_lds, const bf16* B_lds,
    int w16, int cb, int l16, int quad, f32x4* acc) {
#pragma unroll
  for (int n = 0; n < NT; ++n) { acc[n][0]=0.f; acc[n][1]=0.f; acc[n][2]=0.f; acc[n][3]=0.f; }
#pragma unroll
  for (int kt = 0; kt < 2; ++kt) {
    bf16x8 af = *(const bf16x8*)(A_lds + sx8(w16 + l16, kt*4 + quad));
#pragma unroll
    for (int n = 0; n < NT; ++n) {
      bf16x8 bf = *(const bf16x8*)(B_lds + sx8(cb + n*16 + l16, kt*4 + quad));
      acc[n] = __builtin_amdgcn_mfma_f32_16x16x32_bf16(af, bf, acc[n], 0, 0, 0);
    }
  }
}

__global__ __launch_bounds__(512, 4) void k_prepass(
    const bf16* __restrict__ qpre, const bf16* __restrict__ kpre,
    const bf16* __restrict__ vpre, const float* __restrict__ cqw,
    const float* __restrict__ ckw, const float* __restrict__ cvw,
    const float* __restrict__ graw, const float* __restrict__ beta,
    bf16* __restrict__ EF, float* __restrict__ dSl, float* __restrict__ obuf) {
  const int bx = blockIdx.x, c = bx >> 4, h = bx & 15, tid = threadIdx.x;
  const int t0 = c * 64;
  const int wave = tid >> 6, lane = tid & 63, l16 = lane & 15, quad = lane >> 4;
  const int w16 = (wave >> 1) * 16;
  const int chh = wave & 1;
  const int r0 = wave * 8;

  __shared__ bf16 SM[36864];
  __shared__ float bs[64], bts_s[64], es[64], gms[64];
  bf16* Kr    = SM;            // A
  bf16* powR0 = SM + 4096;     // B
  bf16* prod0 = SM + 8192;     // C
  bf16* T2T   = SM + 12288;    // D
  bf16* powT0 = SM + 16384;    // E
  bf16* powR1 = SM + 20480;    // F
  bf16* powT1 = SM + 24576;    // G
  bf16* prod1 = SM + 28672;    // H
  bf16* qbf   = SM + 32768;    // Q
  bf16* VT   = SM;             // rows 0..127 over A+B
  bf16* VlT  = SM + 8192;      // rows 0..127 over C+D
  bf16* KT   = powT0;
  bf16* KbT  = powR1;
  bf16* Pm   = powT1;
  bf16* WR   = prod0;
  bf16* Mrow = prod1;

  // issue all 44 conv tap loads FIRST so their HBM latency overlaps the scan below
  float4 wq  = *(const float4*)(cqw + (h*64 + lane)*4);
  float4 wk  = *(const float4*)(ckw + (h*64 + lane)*4);
  float4 wv0 = *(const float4*)(cvw + (h*128 + lane)*4);
  float4 wv1 = *(const float4*)(cvw + (h*128 + 64 + lane)*4);
  float qtv[11], ktv[11], vtv0[11], vtv1[11];
#pragma unroll
  for (int j = 0; j < 11; ++j) {
    int tg = t0 + r0 + j - 3;
    bool ok = tg >= 0;
    qtv[j]  = ok ? (float)qpre[(size_t)tg*1024 + h*64 + lane] : 0.f;
    ktv[j]  = ok ? (float)kpre[(size_t)tg*1024 + h*64 + lane] : 0.f;
    vtv0[j] = ok ? (float)vpre[(size_t)tg*2048 + h*128 + lane] : 0.f;
    vtv1[j] = ok ? (float)vpre[(size_t)tg*2048 + h*128 + 64 + lane] : 0.f;
  }

  if (tid < 64) {
    float g = graw[(size_t)(t0 + tid)*16 + h];
    float b = g;
#pragma unroll
    for (int off = 1; off < 64; off <<= 1) {
      float p = __shfl_up(b, off, 64);
      if (tid >= off) b += p;
    }
    bs[tid] = b;
    bts_s[tid] = beta[(size_t)(t0 + tid)*16 + h];
    float b63 = __shfl(b, 63, 64);
    es[tid] = __expf(b63 - b);
    gms[tid] = __expf(b);
  }

  // fused conv(K=4)+silu+norms; wave owns rows r0..r0+7, channel = lane
  float kreg[8], vreg[16];
  {
#pragma unroll
    for (int rr = 0; rr < 8; ++rr) {
      float y = qtv[rr]*wq.x + qtv[rr+1]*wq.y + qtv[rr+2]*wq.z + qtv[rr+3]*wq.w;
      y = y * sigmoidf_(y);
      float ssq = wredsum(y*y);
      y *= rsqrtf(ssq + 1e-6f) * 0.125f;
      qbf[sxy(r0+rr, lane)] = (bf16)y;
    }
#pragma unroll
    for (int rr = 0; rr < 8; ++rr) {
      float y = ktv[rr]*wk.x + ktv[rr+1]*wk.y + ktv[rr+2]*wk.z + ktv[rr+3]*wk.w;
      y = y * sigmoidf_(y);
      // joint (sum, sumsq) butterfly: centered ssq = s2 - s1^2/64
      float s1 = y, s2 = y*y;
#pragma unroll
      for (int off = 32; off > 0; off >>= 1) {
        s1 += __shfl_xor(s1, off, 64);
        s2 += __shfl_xor(s2, off, 64);
      }
      float m = s1 * (1.f/64.f);
      float ssq = s2 - s1*m;
      y -= m;
      y *= rsqrtf(ssq + 1e-6f);
      kreg[rr] = y;
      Kr[sxy(r0+rr, lane)] = (bf16)y;
    }
#pragma unroll
    for (int rr = 0; rr < 8; ++rr) {
      float y0 = vtv0[rr]*wv0.x + vtv0[rr+1]*wv0.y + vtv0[rr+2]*wv0.z + vtv0[rr+3]*wv0.w;
      float y1 = vtv1[rr]*wv1.x + vtv1[rr+1]*wv1.y + vtv1[rr+2]*wv1.z + vtv1[rr+3]*wv1.w;
      vreg[rr]   = y0 * sigmoidf_(y0);
      vreg[8+rr] = y1 * sigmoidf_(y1);
    }
  }
  __syncthreads();

  // A-build: N = -A from K K^T; prod0 = I + N
  {
    f32x4 acc[2];
    mm_band<2>(Kr, Kr, w16, chh*32, l16, quad, acc);
#pragma unroll
    for (int n = 0; n < 2; ++n) {
      int col = chh*32 + n*16 + l16;
      bf16x4v tv;
#pragma unroll
      for (int r = 0; r < 4; ++r) {
        int row = w16 + quad*4 + r;
        float nv = 0.f;
        if (row > col) nv = -bts_s[row] * __expf(bs[row] - bs[col]) * acc[n][r];
        bf16 nb = (bf16)nv;
        powR0[sxy(row, col)] = nb;
        tv[r] = nb;
        prod0[sxy(row, col)] = (row == col) ? (bf16)1.f : nb;
      }
      *(bf16x4v*)(powT0 + sxy(col, w16 + quad*4)) = tv;
    }
  }
  __syncthreads();

  // squaring chain: (I+A)^-1 = prod (I + N^(2^i))
  int pc = 0, rc = 0;
#pragma unroll 1
  for (int i = 1; i <= 5; ++i) {
    bf16* sqA = pc ? powR1 : powR0;
    bf16* sqB = pc ? powT1 : powT0;
    bf16* sqRo = pc ? powR0 : powR1;
    bf16* sqTo = pc ? powT0 : powT1;
    {
      f32x4 acc[2];
      mm_band<2>(sqA, sqB, w16, chh*32, l16, quad, acc);
#pragma unroll
      for (int n = 0; n < 2; ++n) {
        int col = chh*32 + n*16 + l16;
        bf16x4v tv;
#pragma unroll
        for (int r = 0; r < 4; ++r) {
          int row = w16 + quad*4 + r;
          bf16 vb = (bf16)acc[n][r];
          sqRo[sxy(row, col)] = vb;
          tv[r] = vb;
        }
        *(bf16x4v*)(sqTo + sxy(col, w16 + quad*4)) = tv;
      }
    }
    __syncthreads();
    bf16* prA = rc ? prod1 : prod0;
    bf16* prO = rc ? prod0 : prod1;
    {
      f32x4 acc[2];
      mm_band<2>(prA, sqTo, w16, chh*32, l16, quad, acc);
#pragma unroll
      for (int n = 0; n < 2; ++n) {
        int col = chh*32 + n*16 + l16;
        bf16x4v tv;
#pragma unroll
        for (int r = 0; r < 4; ++r) {
          int row = w16 + quad*4 + r;
          float val = acc[n][r] + (float)prA[sxy(row, col)];
          prO[sxy(row, col)] = (bf16)val;
          tv[r] = (bf16)(val * bts_s[col] * gms[col]);
        }
        if (i == 5) *(bf16x4v*)(T2T + sxy(col, w16 + quad*4)) = tv;
      }
    }
    __syncthreads();
    pc ^= 1; rc ^= 1;
  }
  // after chain: Mrow = prod1, pow planes dead

  // KT/KbT from registers; Pm build (reads Kr + qbf)
#pragma unroll
  for (int rr = 0; rr < 8; ++rr) {
    KT[sxy(lane, r0+rr)]  = (bf16)kreg[rr];
    KbT[sxy(lane, r0+rr)] = (bf16)(kreg[rr] * es[r0+rr]);
  }
  {
    f32x4 acc[2];
#pragma unroll
    for (int n = 0; n < 2; ++n) { acc[n][0]=0.f; acc[n][1]=0.f; acc[n][2]=0.f; acc[n][3]=0.f; }
#pragma unroll
    for (int kt = 0; kt < 2; ++kt) {
      bf16x8 af = *(const bf16x8*)(qbf + sx8(w16 + l16, kt*4 + quad));
#pragma unroll
      for (int n = 0; n < 2; ++n) {
        bf16x8 bf = *(const bf16x8*)(Kr + sx8(chh*32 + n*16 + l16, kt*4 + quad));
        acc[n] = __builtin_amdgcn_mfma_f32_16x16x32_bf16(af, bf, acc[n], 0, 0, 0);
      }
    }
#pragma unroll
    for (int n = 0; n < 2; ++n) {
      int col = chh*32 + n*16 + l16;
#pragma unroll
      for (int r = 0; r < 4; ++r) {
        int row = w16 + quad*4 + r;
        float pv = (row >= col) ? __expf(bs[row] - bs[col]) * acc[n][r] : 0.f;
        Pm[sxy(row, col)] = (bf16)pv;
      }
    }
  }
  __syncthreads();

  // W2 = Kbar^T T2 -> WR ; VT from vreg (Kr/powR0 dead)
  {
    f32x4 acc[2];
    mm_band<2>(KbT, T2T, w16, chh*32, l16, quad, acc);
#pragma unroll
    for (int n = 0; n < 2; ++n) {
      int col = chh*32 + n*16 + l16;
#pragma unroll
      for (int r = 0; r < 4; ++r)
        WR[sxy(w16 + quad*4 + r, col)] = (bf16)acc[n][r];
    }
  }
#pragma unroll
  for (int hf = 0; hf < 2; ++hf)
#pragma unroll
    for (int rr = 0; rr < 8; ++rr)
      VT[sxy(hf*64 + lane, r0+rr)] = (bf16)(bts_s[r0+rr] * vreg[hf*8+rr]);
  __syncthreads();
  // E = gamma_C I - W2 K -> EF planes 0/1 (hi/lo)
  {
    f32x4 acc[2];
    mm_band<2>(WR, KT, w16, chh*32, l16, quad, acc);
    float gC = gms[63];
    size_t eb = (size_t)bx * 13824;
#pragma unroll
    for (int n = 0; n < 2; ++n) {
      int col = chh*32 + n*16 + l16;
#pragma unroll
      for (int r = 0; r < 4; ++r) {
        int row = w16 + quad*4 + r;
        float ev = ((row == col) ? gC : 0.f) - acc[n][r];
        bf16 eh = (bf16)ev;
        EF[eb + row*S72 + col] = eh;
        EF[eb + 4608 + row*S72 + col] = (bf16)(ev - (float)eh);
      }
    }
  }
  __syncthreads();
  // R = P T2 -> WR
  {
    f32x4 acc[2];
    mm_band<2>(Pm, T2T, w16, chh*32, l16, quad, acc);
#pragma unroll
    for (int n = 0; n < 2; ++n) {
      int col = chh*32 + n*16 + l16;
#pragma unroll
      for (int r = 0; r < 4; ++r)
        WR[sxy(w16 + quad*4 + r, col)] = (bf16)acc[n][r];
    }
  }
  __syncthreads();
  // F = diag(gamma) Q - R K -> EF plane 2
  {
    f32x4 acc[2];
    mm_band<2>(WR, KT, w16, chh*32, l16, quad, acc);
    size_t eb = (size_t)bx * 13824;
#pragma unroll
    for (int n = 0; n < 2; ++n) {
      int col = chh*32 + n*16 + l16;
#pragma unroll
      for (int r = 0; r < 4; ++r) {
        int row = w16 + quad*4 + r;
        float qv = (float)qbf[sxy(row, col)];
        EF[eb + 9216 + row*S72 + col] = (bf16)(gms[row]*qv - acc[n][r]);
      }
    }
  }
  __syncthreads();   // WR/T2T reads done before VlT overwrites C+D
  // V_loc = M (beta V): write V_loc^T into VlT
  {
    f32x4 acc[4];
    mm_band<4>(Mrow, VT, w16, chh*64, l16, quad, acc);
#pragma unroll
    for (int n = 0; n < 4; ++n) {
      int col = chh*64 + n*16 + l16;
      bf16x4v tv;
#pragma unroll
      for (int r = 0; r < 4; ++r) tv[r] = (bf16)acc[n][r];
      *(bf16x4v*)(VlT + sxy(col, w16 + quad*4)) = tv;
    }
  }
  __syncthreads();
  // dS_loc = Kbar^T V_loc ; O_loc = P V_loc
  {
    f32x4 acc[4];
    mm_band<4>(KbT, VlT, w16, chh*64, l16, quad, acc);
#pragma unroll
    for (int n = 0; n < 4; ++n) {
      int col = chh*64 + n*16 + l16;
#pragma unroll
      for (int r = 0; r < 4; ++r)
        dSl[(size_t)bx*8192 + (size_t)(w16 + quad*4 + r)*128 + col] = acc[n][r];
    }
  }
  {
    f32x4 acc[4];
    mm_band<4>(Pm, VlT, w16, chh*64, l16, quad, acc);
#pragma unroll
    for (int n = 0; n < 4; ++n) {
      int col = chh*64 + n*16 + l16;
#pragma unroll
      for (int r = 0; r < 4; ++r)
        obuf[(size_t)(t0 + w16 + quad*4 + r)*2048 + h*128 + col] = acc[n][r];
    }
  }
}

// ---------------- MFMA sequential recurrence (named-register pipeline, raw barriers) ----
#define SEQ_LOAD(Cn, EHx, ELx, FFx, DSx)                                        \
  {                                                                             \
    const bf16* base_ = EF + (size_t)((Cn)*16 + h)*13824 + arow;                \
    _Pragma("unroll")                                                           \
    for (int kt = 0; kt < 2; ++kt) {                                            \
      EHx[kt] = *(const bf16x8*)(base_ + kt*32);                                \
      ELx[kt] = *(const bf16x8*)(base_ + 4608 + kt*32);                         \
      FFx[kt] = *(const bf16x8*)(base_ + 9216 + kt*32);                         \
    }                                                                           \
    const float* db_ = dSl + (size_t)((Cn)*16 + h)*8192 + drow;                 \
    _Pragma("unroll")                                                           \
    for (int nt = 0; nt < 2; ++nt)                                              \
      _Pragma("unroll")                                                         \
      for (int r = 0; r < 4; ++r)                                               \
        DSx[nt*4+r] = db_[(size_t)r*128 + nt*16];                               \
  }

#define SEQ_STEP(Cc, EHc, ELc, FFc, DSc, EHn, ELn, FFn, DSn, SRC, DST)          \
  {                                                                             \
    bf16x8 bh[2][2], bl[2][2];                                                  \
    _Pragma("unroll")                                                           \
    for (int nt = 0; nt < 2; ++nt)                                              \
      _Pragma("unroll")                                                         \
      for (int kt = 0; kt < 2; ++kt) {                                          \
        bh[nt][kt] = *(const bf16x8*)(&Sthi[SRC][(nt*16 + l16)*S72 + kt*32 + quad*8]); \
        bl[nt][kt] = *(const bf16x8*)(&Stlo[SRC][(nt*16 + l16)*S72 + kt*32 + quad*8]); \
      }                                                                         \
    if ((Cc) + 1 < 32) SEQ_LOAD((Cc) + 1, EHn, ELn, FFn, DSn);                  \
    f32x4 a1[2], a2[2], a3[2], o1[2], o2[2];                                    \
    _Pragma("unroll")                                                           \
    for (int nt = 0; nt < 2; ++nt)                                              \
      _Pragma("unroll")                                                         \
      for (int r = 0; r < 4; ++r) {                                             \
        a1[nt][r] = DSc[nt*4+r];                                                \
        a2[nt][r] = 0.f; a3[nt][r] = 0.f; o1[nt][r] = 0.f; o2[nt][r] = 0.f;     \
      }                                                                         \
    _Pragma("unroll")                                                           \
    for (int kt = 0; kt < 2; ++kt)                                              \
      _Pragma("unroll")                                                         \
      for (int nt = 0; nt < 2; ++nt) {                                          \
        a1[nt] = __builtin_amdgcn_mfma_f32_16x16x32_bf16(EHc[kt], bh[nt][kt], a1[nt], 0, 0, 0); \
        a2[nt] = __builtin_amdgcn_mfma_f32_16x16x32_bf16(EHc[kt], bl[nt][kt], a2[nt], 0, 0, 0); \
        a3[nt] = __builtin_amdgcn_mfma_f32_16x16x32_bf16(ELc[kt], bh[nt][kt], a3[nt], 0, 0, 0); \
        o1[nt] = __builtin_amdgcn_mfma_f32_16x16x32_bf16(FFc[kt], bh[nt][kt], o1[nt], 0, 0, 0); \
        o2[nt] = __builtin_amdgcn_mfma_f32_16x16x32_bf16(FFc[kt], bl[nt][kt], o2[nt], 0, 0, 0); \
      }                                                                         \
    {                                                                           \
      int t0c = (Cc)*64;                                                        \
      _Pragma("unroll")                                                         \
      for (int nt = 0; nt < 2; ++nt)                                            \
        _Pragma("unroll")                                                       \
        for (int r = 0; r < 4; ++r)                                             \
          osb[(size_t)(t0c + mb + quad*4 + r)*2048 + h*128 + dq*32 + nt*16 + l16] \
            = o1[nt][r] + o2[nt][r];                                            \
    }                                                                           \
    _Pragma("unroll")                                                           \
    for (int nt = 0; nt < 2; ++nt) {                                            \
      bf16x4v hv, lv;                                                           \
      _Pragma("unroll")                                                         \
      for (int r = 0; r < 4; ++r) {                                             \
        float v = a1[nt][r] + a2[nt][r] + a3[nt][r];                            \
        bf16 hb = (bf16)v;                                                      \
        hv[r] = hb;                                                             \
        lv[r] = (bf16)(v - (float)hb);                                          \
      }                                                                         \
      *(bf16x4v*)(&Sthi[DST][(nt*16 + l16)*S72 + mb + quad*4]) = hv;            \
      *(bf16x4v*)(&Stlo[DST][(nt*16 + l16)*S72 + mb + quad*4]) = lv;            \
    }                                                                           \
    asm volatile("s_waitcnt lgkmcnt(0)" ::: "memory");                          \
    __builtin_amdgcn_s_barrier();                                               \
  }

__global__ __launch_bounds__(256) void k_seq(const bf16* __restrict__ EF,
    const float* __restrict__ dSl, float* __restrict__ osb) {
  const int bid = blockIdx.x;
  const int h = (bid & 7) + 8*((bid >> 3) & 1);
  const int dq = bid >> 4;
  const int tid = threadIdx.x, wave = tid >> 6, lane = tid & 63;
  const int l16 = lane & 15, quad = lane >> 4;
  const int mb = wave * 16;
  __shared__ bf16 Sthi[2][32*S72], Stlo[2][32*S72];
  for (int i = tid; i < 2304; i += 256) { Sthi[0][i] = (bf16)0.f; Stlo[0][i] = (bf16)0.f; }

  const size_t arow = (size_t)(mb + l16)*S72 + quad*8;
  const size_t drow = (size_t)dq*32 + (size_t)(mb + quad*4)*128 + l16;

  bf16x8 ehA[2], elA[2], ffA[2], ehB[2], elB[2], ffB[2];
  float dsA[8], dsB[8];

  SEQ_LOAD(0, ehA, elA, ffA, dsA);
  asm volatile("s_waitcnt lgkmcnt(0)" ::: "memory");
  __builtin_amdgcn_s_barrier();

#pragma unroll 1
  for (int c = 0; c < 32; c += 2) {
    SEQ_STEP(c,     ehA, elA, ffA, dsA, ehB, elB, ffB, dsB, 0, 1);
    SEQ_STEP(c + 1, ehB, elB, ffB, dsB, ehA, elA, ffA, dsA, 1, 0);
  }
}

// ---------------- gated RMSNorm on o = O_loc + O_s, write bf16 ----------------
__global__ __launch_bounds__(256) void k_gatenorm(const float* __restrict__ o,
    const float* __restrict__ os, const bf16* __restrict__ gpre,
    const float* __restrict__ onw, bf16* __restrict__ og) {
  int t = blockIdx.x, wave = threadIdx.x >> 6, lane = threadIdx.x & 63;
  float2 nw = *(const float2*)(onw + lane*2);
#pragma unroll
  for (int hi = 0; hi < 4; ++hi) {
    int hh = wave*4 + hi;
    size_t base = (size_t)t*2048 + hh*128 + lane*2;
    float2 o2 = *(const float2*)(o + base);
    float2 s2 = *(const float2*)(os + base);
    o2.x += s2.x; o2.y += s2.y;
    float ss = wredsum(o2.x*o2.x + o2.y*o2.y);
    float rs = rsqrtf(ss * (1.f/128.f) + 1e-5f);
    bf16x2v g2 = *(const bf16x2v*)(gpre + base);
    float g0 = (float)g2[0], g1 = (float)g2[1];
    float r0 = o2.x * rs * nw.x * (g0 * sigmoidf_(g0));
    float r1 = o2.y * rs * nw.y * (g1 * sigmoidf_(g1));
    bf16x2v b; b[0] = (bf16)r0; b[1] = (bf16)r1;
    *(bf16x2v*)(og + base) = b;
  }
}

extern "C" void kernel_launch(void* const* d_in, const int* in_sizes, int n_in,
                              void* d_out, int out_size, void* d_ws, size_t ws_size,
                              hipStream_t stream) {
  const float* hs   = (const float*)d_in[0];
  const float* nw   = (const float*)d_in[1];
  const float* qw   = (const float*)d_in[2];
  const float* kw   = (const float*)d_in[3];
  const float* vw   = (const float*)d_in[4];
  const float* aw   = (const float*)d_in[5];
  const float* bw   = (const float*)d_in[6];
  const float* gw   = (const float*)d_in[7];
  const float* dtb  = (const float*)d_in[8];
  const float* alog = (const float*)d_in[9];
  const float* cqw  = (const float*)d_in[10];
  const float* ckw  = (const float*)d_in[11];
  const float* cvw  = (const float*)d_in[12];
  const float* onw  = (const float*)d_in[13];
  const float* opw  = (const float*)d_in[14];
  const float* ow   = (const float*)d_in[15];
  float* out = (float*)d_out;

  char* p = (char*)d_ws;
  auto alloc = [&](size_t bytes) { char* r = p; p += (bytes + 255) & ~255ull; return r; };
  bf16*  xb    = (bf16*) alloc((size_t)2048*1024*2);   // } dSl aliases xb..gwb (16 MB,
  bf16*  qwb   = (bf16*) alloc((size_t)1024*1024*2);   // } all dead after k_gemm_proj)
  bf16*  kwb   = (bf16*) alloc((size_t)1024*1024*2);
  bf16*  vwb   = (bf16*) alloc((size_t)2048*1024*2);
  bf16*  gwb   = (bf16*) alloc((size_t)2048*1024*2);
  bf16*  opwb  = (bf16*) alloc((size_t)1024*2048*2);
  bf16*  owb   = (bf16*) alloc((size_t)1024*1024*2);
  bf16*  qpre  = (bf16*) alloc((size_t)2048*1024*2);
  bf16*  kpre  = (bf16*) alloc((size_t)2048*1024*2);
  bf16*  vpre  = (bf16*) alloc((size_t)2048*2048*2);
  bf16*  gpre  = (bf16*) alloc((size_t)2048*2048*2);
  float* graw  = (float*)alloc((size_t)2048*16*4);
  float* btb   = (float*)alloc((size_t)2048*16*4);
  float* ob    = (float*)alloc((size_t)2048*2048*4);
  bf16*  ogb   = (bf16*) alloc((size_t)2048*2048*2);
  bf16*  h1b   = (bf16*) alloc((size_t)2048*1024*2);
  bf16*  EF    = (bf16*) alloc((size_t)512*13824*2);
  float* osb   = (float*)alloc((size_t)512*8192*4);
  float* dSl   = (float*)xb;   // 16 MB over xb..gwb (dead after k_gemm_proj)

  k_pre<<<2048+4608, 256, 0, stream>>>(hs, nw, aw, bw, dtb, alog, xb, graw, btb,
                                       qw, kw, vw, gw, opw, ow,
                                       qwb, kwb, vwb, gwb, opwb, owb);
  k_gemm_proj<<<dim3(24,8,1), 512, 0, stream>>>(xb, qwb, kwb, vwb, gwb, qpre, kpre, vpre, gpre);
  k_prepass<<<512, 512, 0, stream>>>(qpre, kpre, vpre, cqw, ckw, cvw, graw, btb, EF, dSl, ob);
  k_seq<<<64, 256, 0, stream>>>(EF, dSl, osb);
  k_gatenorm<<<2048, 256, 0, stream>>>(ob, osb, gpre, onw, ogb);
  k_gemm_bt64<bf16><<<dim3(16,16,1), 256, 0, stream>>>(ogb, opwb, h1b, 1024, 2048);
  k_gemm_bt64<float><<<dim3(16,16,1), 256, 0, stream>>>(h1b, owb, out, 1024, 1024);
}

// Round 7
// 265.437 us; speedup vs baseline: 1.0231x; 1.0025x over previous
//
#include <hip/hip_runtime.h>
#include <math.h>

#define S72 72

typedef __bf16 bf16;
typedef __bf16 bf16x8 __attribute__((ext_vector_type(8)));
typedef __bf16 bf16x4v __attribute__((ext_vector_type(4)));
typedef __bf16 bf16x2v __attribute__((ext_vector_type(2)));
typedef float f32x4 __attribute__((ext_vector_type(4)));

__device__ __forceinline__ float wredsum(float v) {
#pragma unroll
  for (int off = 32; off > 0; off >>= 1) v += __shfl_xor(v, off, 64);
  return v;
}
__device__ __forceinline__ float sigmoidf_(float x) { return 1.f / (1.f + __expf(-x)); }

// swizzled LDS addressing for 64-col planes: row stride 64, 8-elem chunks XOR'd by row&7
__device__ __forceinline__ int sxy(int row, int col) {
  return (row << 6) + ((((col >> 3) ^ (row & 7)) << 3) | (col & 7));
}
__device__ __forceinline__ int sx8(int row, int chunk) {
  return (row << 6) + ((chunk ^ (row & 7)) << 3);
}

// ---------------- fused: RMSNorm + a/b projections  |  weight cast ----------------
__global__ __launch_bounds__(256) void k_pre(const float* __restrict__ h,
    const float* __restrict__ nw, const float* __restrict__ aw,
    const float* __restrict__ bw, const float* __restrict__ dtb,
    const float* __restrict__ alog, bf16* __restrict__ xb,
    float* __restrict__ graw, float* __restrict__ btb,
    const float* __restrict__ qw, const float* __restrict__ kw,
    const float* __restrict__ vw, const float* __restrict__ gw,
    const float* __restrict__ opw, const float* __restrict__ ow,
    bf16* qwb, bf16* kwb, bf16* vwb, bf16* gwb, bf16* opwb, bf16* owb) {
  __shared__ float red[4];
  __shared__ __align__(16) float xs[1024];
  int tid = threadIdx.x;
  if (blockIdx.x >= 2048) {
    // weight cast part (4608 virtual blocks)
    long cb = blockIdx.x - 2048;
    for (long u = cb*256 + tid; u < 2359296; u += 4608l*256) {
      const float* src; bf16* dst; long l;
      if      (u <  262144) { src=qw;  dst=qwb;  l=u; }
      else if (u <  524288) { src=kw;  dst=kwb;  l=u-262144; }
      else if (u < 1048576) { src=vw;  dst=vwb;  l=u-524288; }
      else if (u < 1572864) { src=gw;  dst=gwb;  l=u-1048576; }
      else if (u < 2097152) { src=opw; dst=opwb; l=u-1572864; }
      else                  { src=ow;  dst=owb;  l=u-2097152; }
      float4 s = *(const float4*)(src + l*4);
      bf16x4v b; b[0]=(bf16)s.x; b[1]=(bf16)s.y; b[2]=(bf16)s.z; b[3]=(bf16)s.w;
      *(bf16x4v*)(dst + l*4) = b;
    }
    return;
  }
  int t = blockIdx.x;
  float4 hv = *(const float4*)(h + (size_t)t*1024 + tid*4);
  float ss = hv.x*hv.x + hv.y*hv.y + hv.z*hv.z + hv.w*hv.w;
  float wsum = wredsum(ss);
  if ((tid & 63) == 0) red[tid >> 6] = wsum;
  __syncthreads();
  float tot = red[0] + red[1] + red[2] + red[3];
  float rs = rsqrtf(tot * (1.f/1024.f) + 1e-6f);
  float4 w4 = *(const float4*)(nw + tid*4);
  float4 y;
  y.x = hv.x*rs*w4.x; y.y = hv.y*rs*w4.y; y.z = hv.z*rs*w4.z; y.w = hv.w*rs*w4.w;
  *(float4*)(xs + tid*4) = y;
  bf16x4v b; b[0]=(bf16)y.x; b[1]=(bf16)y.y; b[2]=(bf16)y.z; b[3]=(bf16)y.w;
  *(bf16x4v*)(xb + (size_t)t*1024 + tid*4) = b;
  __syncthreads();
  int wave = tid >> 6, lane = tid & 63;
  const float4* x4 = (const float4*)xs;
#pragma unroll
  for (int hi = 0; hi < 4; ++hi) {
    int hh = wave*4 + hi;
    float sa = 0.f, sb = 0.f;
#pragma unroll
    for (int i = 0; i < 4; ++i) {
      float4 xv = x4[i*64 + lane];
      float4 av = *(const float4*)(aw + hh*1024 + i*256 + lane*4);
      float4 bv = *(const float4*)(bw + hh*1024 + i*256 + lane*4);
      sa += xv.x*av.x + xv.y*av.y + xv.z*av.z + xv.w*av.w;
      sb += xv.x*bv.x + xv.y*bv.y + xv.z*bv.z + xv.w*bv.w;
    }
    sa = wredsum(sa); sb = wredsum(sb);
    if (lane == 0) {
      float ap = sa + dtb[hh];
      float sp = (ap > 20.f) ? ap : log1pf(expf(ap));
      graw[t*16 + hh] = -expf(alog[hh]) * sp;
      btb[t*16 + hh] = 1.f / (1.f + expf(-sb));
    }
  }
}

// ---------------- bf16 MFMA GEMM 256x256 / BK=64 / 4-phase schedule (T3+T4+T5) --------
#define PROJ_STAGE_HALF(BUF, MAT, HALF, GBASE)                                   \
  { _Pragma("unroll")                                                            \
    for (int rd_ = 0; rd_ < 2; ++rd_) {                                          \
      int row_ = srow + rd_*64;                                                  \
      __builtin_amdgcn_global_load_lds(                                          \
        (__attribute__((address_space(1))) void*)((GBASE) + (size_t)row_*1024 + ((schk ^ (row_ & 7))*8)), \
        (__attribute__((address_space(3))) void*)(&S[BUF][MAT][HALF][row_*64 + schk*8]), \
        16, 0, 0);                                                               \
    } }

#define PROJ_LDA(BUF, MT, KS) \
  (*(const bf16x8*)(&S[BUF][0][(wm + (MT)*16) >> 7][((wm + (MT)*16 + l16) & 127)*64 + ((((KS)*4 + quad) ^ (l16 & 7))*8)]))
#define PROJ_LDB(BUF, NT, KS) \
  (*(const bf16x8*)(&S[BUF][1][(wn + (NT)*16) >> 7][((wn + (NT)*16 + l16) & 127)*64 + ((((KS)*4 + quad) ^ (l16 & 7))*8)]))

__global__ __launch_bounds__(512, 2) void k_gemm_proj(const bf16* __restrict__ A,
    const bf16* __restrict__ qwb, const bf16* __restrict__ kwb,
    const bf16* __restrict__ vwb, const bf16* __restrict__ gwb,
    bf16* __restrict__ qpre, bf16* __restrict__ kpre,
    bf16* __restrict__ vpre, bf16* __restrict__ gpre) {
  // XCD-aware remap: dispatch index d -> XCD d%8; same-XCD blocks share one A row-panel
  const int d = blockIdx.y * 24 + blockIdx.x;    // 192 blocks, 192%8==0 -> bijective
  const int by = d & 7, bx = d >> 3;
  const bf16* B; bf16* C; int N, xt;
  if      (bx <  4) { B = qwb; C = qpre; N = 1024; xt = bx; }
  else if (bx <  8) { B = kwb; C = kpre; N = 1024; xt = bx - 4; }
  else if (bx < 16) { B = vwb; C = vpre; N = 2048; xt = bx - 8; }
  else              { B = gwb; C = gpre; N = 2048; xt = bx - 16; }
  const int m0 = by * 256, n0 = xt * 256;

  __shared__ bf16 S[2][2][2][128*64];   // 131072 B

  const int tid = threadIdx.x, lane = tid & 63, wave = tid >> 6;
  const int l16 = lane & 15, quad = lane >> 4;
  const int wm = (wave >> 2) * 128, wn = (wave & 3) * 64;
  const int srow = tid >> 3, schk = tid & 7;

  f32x4 acc[8][4] = {};

  // prologue: stage tile 0 into buf 0, drain once
  PROJ_STAGE_HALF(0, 0, 0, A + (size_t)m0*1024);
  PROJ_STAGE_HALF(0, 0, 1, A + (size_t)(m0+128)*1024);
  PROJ_STAGE_HALF(0, 1, 0, B + (size_t)n0*1024);
  PROJ_STAGE_HALF(0, 1, 1, B + (size_t)(n0+128)*1024);
  asm volatile("s_waitcnt vmcnt(0)" ::: "memory");
  __builtin_amdgcn_sched_barrier(0);
  __builtin_amdgcn_s_barrier();

#pragma unroll 1
  for (int kt = 0; kt < 16; ++kt) {
    const int cur = kt & 1, nxt = cur ^ 1;
    const bool pf = (kt + 1 < 16);
    const size_t knext = (size_t)(kt + 1) * 64;
    bf16x8 af[4][2], b0[2][2], b1[2][2];

    // ---- phase 0: quadrant (mh0, nh0); stage A halves of kt+1 ----
#pragma unroll
    for (int m = 0; m < 4; ++m) { af[m][0] = PROJ_LDA(cur, m, 0); af[m][1] = PROJ_LDA(cur, m, 1); }
#pragma unroll
    for (int n = 0; n < 2; ++n) { b0[n][0] = PROJ_LDB(cur, n, 0); b0[n][1] = PROJ_LDB(cur, n, 1); }
    if (pf) {
      PROJ_STAGE_HALF(nxt, 0, 0, A + (size_t)m0*1024 + knext);
      PROJ_STAGE_HALF(nxt, 0, 1, A + (size_t)(m0+128)*1024 + knext);
    }
    __builtin_amdgcn_s_barrier();
    asm volatile("s_waitcnt lgkmcnt(0)" ::: "memory");
    __builtin_amdgcn_sched_barrier(0);
    __builtin_amdgcn_s_setprio(1);
#pragma unroll
    for (int ks = 0; ks < 2; ++ks)
#pragma unroll
      for (int m = 0; m < 4; ++m)
#pragma unroll
        for (int n = 0; n < 2; ++n)
          acc[m][n] = __builtin_amdgcn_mfma_f32_16x16x32_bf16(af[m][ks], b0[n][ks], acc[m][n], 0, 0, 0);
    __builtin_amdgcn_s_setprio(0);
    __builtin_amdgcn_s_barrier();

    // ---- phase 1: quadrant (mh0, nh1); stage B halves of kt+1 ----
#pragma unroll
    for (int n = 0; n < 2; ++n) { b1[n][0] = PROJ_LDB(cur, 2+n, 0); b1[n][1] = PROJ_LDB(cur, 2+n, 1); }
    if (pf) {
      PROJ_STAGE_HALF(nxt, 1, 0, B + (size_t)n0*1024 + knext);
      PROJ_STAGE_HALF(nxt, 1, 1, B + (size_t)(n0+128)*1024 + knext);
    }
    __builtin_amdgcn_s_barrier();
    asm volatile("s_waitcnt lgkmcnt(0)" ::: "memory");
    __builtin_amdgcn_sched_barrier(0);
    __builtin_amdgcn_s_setprio(1);
#pragma unroll
    for (int ks = 0; ks < 2; ++ks)
#pragma unroll
      for (int m = 0; m < 4; ++m)
#pragma unroll
        for (int n = 0; n < 2; ++n)
          acc[m][2+n] = __builtin_amdgcn_mfma_f32_16x16x32_bf16(af[m][ks], b1[n][ks], acc[m][2+n], 0, 0, 0);
    __builtin_amdgcn_s_setprio(0);
    __builtin_amdgcn_s_barrier();

    // ---- phase 2: quadrant (mh1, nh1); reload A frags for mt 4..7 ----
#pragma unroll
    for (int m = 0; m < 4; ++m) { af[m][0] = PROJ_LDA(cur, 4+m, 0); af[m][1] = PROJ_LDA(cur, 4+m, 1); }
    __builtin_amdgcn_s_barrier();
    asm volatile("s_waitcnt lgkmcnt(0)" ::: "memory");
    __builtin_amdgcn_sched_barrier(0);
    __builtin_amdgcn_s_setprio(1);
#pragma unroll
    for (int ks = 0; ks < 2; ++ks)
#pragma unroll
      for (int m = 0; m < 4; ++m)
#pragma unroll
        for (int n = 0; n < 2; ++n)
          acc[4+m][2+n] = __builtin_amdgcn_mfma_f32_16x16x32_bf16(af[m][ks], b1[n][ks], acc[4+m][2+n], 0, 0, 0);
    __builtin_amdgcn_s_setprio(0);
    __builtin_amdgcn_s_barrier();

    // ---- phase 3: quadrant (mh1, nh0); end-of-tile vmcnt (loads issued >=2 phases ago) ----
    __builtin_amdgcn_s_setprio(1);
#pragma unroll
    for (int ks = 0; ks < 2; ++ks)
#pragma unroll
      for (int m = 0; m < 4; ++m)
#pragma unroll
        for (int n = 0; n < 2; ++n)
          acc[4+m][n] = __builtin_amdgcn_mfma_f32_16x16x32_bf16(af[m][ks], b0[n][ks], acc[4+m][n], 0, 0, 0);
    __builtin_amdgcn_s_setprio(0);
    if (pf) {
      asm volatile("s_waitcnt vmcnt(0)" ::: "memory");
      __builtin_amdgcn_sched_barrier(0);
    }
    __builtin_amdgcn_s_barrier();
  }

#pragma unroll
  for (int mt = 0; mt < 8; ++mt)
#pragma unroll
    for (int nt = 0; nt < 4; ++nt)
#pragma unroll
      for (int r = 0; r < 4; ++r) {
        int row = m0 + wm + mt*16 + quad*4 + r;
        int col = n0 + wn + nt*16 + l16;
        C[(size_t)row*N + col] = (bf16)acc[mt][nt][r];
      }
}

// ---------------- bf16 MFMA GEMM 128x64 (2x blocks for tail GEMMs) ----------------
template <typename OutT>
__global__ __launch_bounds__(256) void k_gemm_bt64(const bf16* __restrict__ A,
    const bf16* __restrict__ B, OutT* __restrict__ C, int N, int K) {
  __shared__ bf16 As[2][128*32];
  __shared__ bf16 Bs[2][64*32];
  const int tid = threadIdx.x, lane = tid & 63, wave = tid >> 6;
  const int wm = wave * 32;
  const int srow = wave*16 + (lane >> 2);
  const int swl = (((lane & 3) ^ ((lane >> 3) & 3))) * 8;
  const int sdst = (lane & 3) * 8;
  const int quad = lane >> 4, l16 = lane & 15;
  const int sw = (l16 >> 1) & 3;
  const int m0 = blockIdx.y * 128, n0 = blockIdx.x * 64;
  f32x4 acc[2][4] = {};
  const int nk = K >> 5;
#pragma unroll
  for (int i = 0; i < 2; ++i) {
    int r = i*64 + srow;
    __builtin_amdgcn_global_load_lds(
      (__attribute__((address_space(1))) void*)(A + (size_t)(m0 + r)*K + swl),
      (__attribute__((address_space(3))) void*)(&As[0][r*32 + sdst]), 16, 0, 0);
  }
  __builtin_amdgcn_global_load_lds(
    (__attribute__((address_space(1))) void*)(B + (size_t)(n0 + srow)*K + swl),
    (__attribute__((address_space(3))) void*)(&Bs[0][srow*32 + sdst]), 16, 0, 0);
  for (int kt = 0; kt < nk; ++kt) {
    const int cur = kt & 1;
    __syncthreads();
    bf16x8 af[2], bfr[4];
#pragma unroll
    for (int mt = 0; mt < 2; ++mt)
      af[mt] = *(const bf16x8*)(&As[cur][(wm + mt*16 + l16)*32 + (quad ^ sw)*8]);
#pragma unroll
    for (int nt = 0; nt < 4; ++nt)
      bfr[nt] = *(const bf16x8*)(&Bs[cur][(nt*16 + l16)*32 + (quad ^ sw)*8]);
    if (kt + 1 < nk) {
      int k0 = (kt + 1) << 5;
#pragma unroll
      for (int i = 0; i < 2; ++i) {
        int r = i*64 + srow;
        __builtin_amdgcn_global_load_lds(
          (__attribute__((address_space(1))) void*)(A + (size_t)(m0 + r)*K + k0 + swl),
          (__attribute__((address_space(3))) void*)(&As[cur^1][r*32 + sdst]), 16, 0, 0);
      }
      __builtin_amdgcn_global_load_lds(
        (__attribute__((address_space(1))) void*)(B + (size_t)(n0 + srow)*K + k0 + swl),
        (__attribute__((address_space(3))) void*)(&Bs[cur^1][srow*32 + sdst]), 16, 0, 0);
    }
#pragma unroll
    for (int mt = 0; mt < 2; ++mt)
#pragma unroll
      for (int nt = 0; nt < 4; ++nt)
        acc[mt][nt] = __builtin_amdgcn_mfma_f32_16x16x32_bf16(af[mt], bfr[nt], acc[mt][nt], 0, 0, 0);
  }
#pragma unroll
  for (int mt = 0; mt < 2; ++mt)
#pragma unroll
    for (int nt = 0; nt < 4; ++nt)
#pragma unroll
      for (int r = 0; r < 4; ++r) {
        int row = m0 + wm + mt*16 + quad*4 + r;
        int col = n0 + nt*16 + l16;
        C[(size_t)row*N + col] = (OutT)acc[mt][nt][r];
      }
}

// ---------------- MFMA chunked delta-rule pre-pass (r2 structure: 19 barriers) ----------------
template<int NT>
__device__ __forceinline__ void mm_band(const bf16* A_lds, const bf16* B_lds,
    int w16, int cb, int l16, int quad, f32x4* acc) {
#pragma unroll
  for (int n = 0; n < NT; ++n) { acc[n][0]=0.f; acc[n][1]=0.f; acc[n][2]=0.f; acc[n][3]=0.f; }
#pragma unroll
  for (int kt = 0; kt < 2; ++kt) {
    bf16x8 af = *(const bf16x8*)(A_lds + sx8(w16 + l16, kt*4 + quad));
#pragma unroll
    for (int n = 0; n < NT; ++n) {
      bf16x8 bf = *(const bf16x8*)(B_lds + sx8(cb + n*16 + l16, kt*4 + quad));
      acc[n] = __builtin_amdgcn_mfma_f32_16x16x32_bf16(af, bf, acc[n], 0, 0, 0);
    }
  }
}

__global__ __launch_bounds__(512, 4) void k_prepass(
    const bf16* __restrict__ qpre, const bf16* __restrict__ kpre,
    const bf16* __restrict__ vpre, const float* __restrict__ cqw,
    const float* __restrict__ ckw, const float* __restrict__ cvw,
    const float* __restrict__ graw, const float* __restrict__ beta,
    bf16* __restrict__ EF, float* __restrict__ dSl, float* __restrict__ obuf) {
  const int bx = blockIdx.x, c = bx >> 4, h = bx & 15, tid = threadIdx.x;
  const int t0 = c * 64;
  const int wave = tid >> 6, lane = tid & 63, l16 = lane & 15, quad = lane >> 4;
  const int w16 = (wave >> 1) * 16;
  const int chh = wave & 1;
  const int r0 = wave * 8;

  __shared__ bf16 SM[36864];
  __shared__ float bs[64], bts_s[64], es[64], gms[64];
  bf16* Kr    = SM;            // A
  bf16* powR0 = SM + 4096;     // B
  bf16* prod0 = SM + 8192;     // C
  bf16* T2T   = SM + 12288;    // D
  bf16* powT0 = SM + 16384;    // E
  bf16* powR1 = SM + 20480;    // F
  bf16* powT1 = SM + 24576;    // G
  bf16* prod1 = SM + 28672;    // H
  bf16* qbf   = SM + 32768;    // Q
  bf16* VT   = SM;             // rows 0..127 over A+B
  bf16* VlT  = SM + 8192;      // rows 0..127 over C+D
  bf16* KT   = powT0;
  bf16* KbT  = powR1;
  bf16* Pm   = powT1;
  bf16* WR   = prod0;
  bf16* Mrow = prod1;

  // issue all 44 conv tap loads FIRST so their HBM latency overlaps the scan below
  float4 wq  = *(const float4*)(cqw + (h*64 + lane)*4);
  float4 wk  = *(const float4*)(ckw + (h*64 + lane)*4);
  float4 wv0 = *(const float4*)(cvw + (h*128 + lane)*4);
  float4 wv1 = *(const float4*)(cvw + (h*128 + 64 + lane)*4);
  float qtv[11], ktv[11], vtv0[11], vtv1[11];
#pragma unroll
  for (int j = 0; j < 11; ++j) {
    int tg = t0 + r0 + j - 3;
    bool ok = tg >= 0;
    qtv[j]  = ok ? (float)qpre[(size_t)tg*1024 + h*64 + lane] : 0.f;
    ktv[j]  = ok ? (float)kpre[(size_t)tg*1024 + h*64 + lane] : 0.f;
    vtv0[j] = ok ? (float)vpre[(size_t)tg*2048 + h*128 + lane] : 0.f;
    vtv1[j] = ok ? (float)vpre[(size_t)tg*2048 + h*128 + 64 + lane] : 0.f;
  }

  if (tid < 64) {
    float g = graw[(size_t)(t0 + tid)*16 + h];
    float b = g;
#pragma unroll
    for (int off = 1; off < 64; off <<= 1) {
      float p = __shfl_up(b, off, 64);
      if (tid >= off) b += p;
    }
    bs[tid] = b;
    bts_s[tid] = beta[(size_t)(t0 + tid)*16 + h];
    float b63 = __shfl(b, 63, 64);
    es[tid] = __expf(b63 - b);
    gms[tid] = __expf(b);
  }

  // fused conv(K=4)+silu+norms; wave owns rows r0..r0+7, channel = lane
  float kreg[8], vreg[16];
  {
#pragma unroll
    for (int rr = 0; rr < 8; ++rr) {
      float y = qtv[rr]*wq.x + qtv[rr+1]*wq.y + qtv[rr+2]*wq.z + qtv[rr+3]*wq.w;
      y = y * sigmoidf_(y);
      float ssq = wredsum(y*y);
      y *= rsqrtf(ssq + 1e-6f) * 0.125f;
      qbf[sxy(r0+rr, lane)] = (bf16)y;
    }
#pragma unroll
    for (int rr = 0; rr < 8; ++rr) {
      float y = ktv[rr]*wk.x + ktv[rr+1]*wk.y + ktv[rr+2]*wk.z + ktv[rr+3]*wk.w;
      y = y * sigmoidf_(y);
      // joint (sum, sumsq) butterfly: centered ssq = s2 - s1^2/64
      float s1 = y, s2 = y*y;
#pragma unroll
      for (int off = 32; off > 0; off >>= 1) {
        s1 += __shfl_xor(s1, off, 64);
        s2 += __shfl_xor(s2, off, 64);
      }
      float m = s1 * (1.f/64.f);
      float ssq = s2 - s1*m;
      y -= m;
      y *= rsqrtf(ssq + 1e-6f);
      kreg[rr] = y;
      Kr[sxy(r0+rr, lane)] = (bf16)y;
    }
#pragma unroll
    for (int rr = 0; rr < 8; ++rr) {
      float y0 = vtv0[rr]*wv0.x + vtv0[rr+1]*wv0.y + vtv0[rr+2]*wv0.z + vtv0[rr+3]*wv0.w;
      float y1 = vtv1[rr]*wv1.x + vtv1[rr+1]*wv1.y + vtv1[rr+2]*wv1.z + vtv1[rr+3]*wv1.w;
      vreg[rr]   = y0 * sigmoidf_(y0);
      vreg[8+rr] = y1 * sigmoidf_(y1);
    }
  }
  __syncthreads();

  // A-build: N = -A from K K^T; prod0 = I + N
  {
    f32x4 acc[2];
    mm_band<2>(Kr, Kr, w16, chh*32, l16, quad, acc);
#pragma unroll
    for (int n = 0; n < 2; ++n) {
      int col = chh*32 + n*16 + l16;
      bf16x4v tv;
#pragma unroll
      for (int r = 0; r < 4; ++r) {
        int row = w16 + quad*4 + r;
        float nv = 0.f;
        if (row > col) nv = -bts_s[row] * __expf(bs[row] - bs[col]) * acc[n][r];
        bf16 nb = (bf16)nv;
        powR0[sxy(row, col)] = nb;
        tv[r] = nb;
        prod0[sxy(row, col)] = (row == col) ? (bf16)1.f : nb;
      }
      *(bf16x4v*)(powT0 + sxy(col, w16 + quad*4)) = tv;
    }
  }
  __syncthreads();

  // squaring chain: (I+A)^-1 = prod (I + N^(2^i))
  int pc = 0, rc = 0;
#pragma unroll 1
  for (int i = 1; i <= 5; ++i) {
    bf16* sqA = pc ? powR1 : powR0;
    bf16* sqB = pc ? powT1 : powT0;
    bf16* sqRo = pc ? powR0 : powR1;
    bf16* sqTo = pc ? powT0 : powT1;
    {
      f32x4 acc[2];
      mm_band<2>(sqA, sqB, w16, chh*32, l16, quad, acc);
#pragma unroll
      for (int n = 0; n < 2; ++n) {
        int col = chh*32 + n*16 + l16;
        bf16x4v tv;
#pragma unroll
        for (int r = 0; r < 4; ++r) {
          int row = w16 + quad*4 + r;
          bf16 vb = (bf16)acc[n][r];
          sqRo[sxy(row, col)] = vb;
          tv[r] = vb;
        }
        *(bf16x4v*)(sqTo + sxy(col, w16 + quad*4)) = tv;
      }
    }
    __syncthreads();
    bf16* prA = rc ? prod1 : prod0;
    bf16* prO = rc ? prod0 : prod1;
    {
      f32x4 acc[2];
      mm_band<2>(prA, sqTo, w16, chh*32, l16, quad, acc);
#pragma unroll
      for (int n = 0; n < 2; ++n) {
        int col = chh*32 + n*16 + l16;
        bf16x4v tv;
#pragma unroll
        for (int r = 0; r < 4; ++r) {
          int row = w16 + quad*4 + r;
          float val = acc[n][r] + (float)prA[sxy(row, col)];
          prO[sxy(row, col)] = (bf16)val;
          tv[r] = (bf16)(val * bts_s[col] * gms[col]);
        }
        if (i == 5) *(bf16x4v*)(T2T + sxy(col, w16 + quad*4)) = tv;
      }
    }
    __syncthreads();
    pc ^= 1; rc ^= 1;
  }
  // after chain: Mrow = prod1, pow planes dead

  // KT/KbT from registers; Pm build (reads Kr + qbf)
#pragma unroll
  for (int rr = 0; rr < 8; ++rr) {
    KT[sxy(lane, r0+rr)]  = (bf16)kreg[rr];
    KbT[sxy(lane, r0+rr)] = (bf16)(kreg[rr] * es[r0+rr]);
  }
  {
    f32x4 acc[2];
#pragma unroll
    for (int n = 0; n < 2; ++n) { acc[n][0]=0.f; acc[n][1]=0.f; acc[n][2]=0.f; acc[n][3]=0.f; }
#pragma unroll
    for (int kt = 0; kt < 2; ++kt) {
      bf16x8 af = *(const bf16x8*)(qbf + sx8(w16 + l16, kt*4 + quad));
#pragma unroll
      for (int n = 0; n < 2; ++n) {
        bf16x8 bf = *(const bf16x8*)(Kr + sx8(chh*32 + n*16 + l16, kt*4 + quad));
        acc[n] = __builtin_amdgcn_mfma_f32_16x16x32_bf16(af, bf, acc[n], 0, 0, 0);
      }
    }
#pragma unroll
    for (int n = 0; n < 2; ++n) {
      int col = chh*32 + n*16 + l16;
#pragma unroll
      for (int r = 0; r < 4; ++r) {
        int row = w16 + quad*4 + r;
        float pv = (row >= col) ? __expf(bs[row] - bs[col]) * acc[n][r] : 0.f;
        Pm[sxy(row, col)] = (bf16)pv;
      }
    }
  }
  __syncthreads();

  // W2 = Kbar^T T2 -> WR ; VT from vreg (Kr/powR0 dead)
  {
    f32x4 acc[2];
    mm_band<2>(KbT, T2T, w16, chh*32, l16, quad, acc);
#pragma unroll
    for (int n = 0; n < 2; ++n) {
      int col = chh*32 + n*16 + l16;
#pragma unroll
      for (int r = 0; r < 4; ++r)
        WR[sxy(w16 + quad*4 + r, col)] = (bf16)acc[n][r];
    }
  }
#pragma unroll
  for (int hf = 0; hf < 2; ++hf)
#pragma unroll
    for (int rr = 0; rr < 8; ++rr)
      VT[sxy(hf*64 + lane, r0+rr)] = (bf16)(bts_s[r0+rr] * vreg[hf*8+rr]);
  __syncthreads();
  // E = gamma_C I - W2 K -> EF planes 0/1 (hi/lo)
  {
    f32x4 acc[2];
    mm_band<2>(WR, KT, w16, chh*32, l16, quad, acc);
    float gC = gms[63];
    size_t eb = (size_t)bx * 13824;
#pragma unroll
    for (int n = 0; n < 2; ++n) {
      int col = chh*32 + n*16 + l16;
#pragma unroll
      for (int r = 0; r < 4; ++r) {
        int row = w16 + quad*4 + r;
        float ev = ((row == col) ? gC : 0.f) - acc[n][r];
        bf16 eh = (bf16)ev;
        EF[eb + row*S72 + col] = eh;
        EF[eb + 4608 + row*S72 + col] = (bf16)(ev - (float)eh);
      }
    }
  }
  __syncthreads();
  // R = P T2 -> WR
  {
    f32x4 acc[2];
    mm_band<2>(Pm, T2T, w16, chh*32, l16, quad, acc);
#pragma unroll
    for (int n = 0; n < 2; ++n) {
      int col = chh*32 + n*16 + l16;
#pragma unroll
      for (int r = 0; r < 4; ++r)
        WR[sxy(w16 + quad*4 + r, col)] = (bf16)acc[n][r];
    }
  }
  __syncthreads();
  // F = diag(gamma) Q - R K -> EF plane 2
  {
    f32x4 acc[2];
    mm_band<2>(WR, KT, w16, chh*32, l16, quad, acc);
    size_t eb = (size_t)bx * 13824;
#pragma unroll
    for (int n = 0; n < 2; ++n) {
      int col = chh*32 + n*16 + l16;
#pragma unroll
      for (int r = 0; r < 4; ++r) {
        int row = w16 + quad*4 + r;
        float qv = (float)qbf[sxy(row, col)];
        EF[eb + 9216 + row*S72 + col] = (bf16)(gms[row]*qv - acc[n][r]);
      }
    }
  }
  __syncthreads();   // WR/T2T reads done before VlT overwrites C+D
  // V_loc = M (beta V): write V_loc^T into VlT
  {
    f32x4 acc[4];
    mm_band<4>(Mrow, VT, w16, chh*64, l16, quad, acc);
#pragma unroll
    for (int n = 0; n < 4; ++n) {
      int col = chh*64 + n*16 + l16;
      bf16x4v tv;
#pragma unroll
      for (int r = 0; r < 4; ++r) tv[r] = (bf16)acc[n][r];
      *(bf16x4v*)(VlT + sxy(col, w16 + quad*4)) = tv;
    }
  }
  __syncthreads();
  // dS_loc = Kbar^T V_loc ; O_loc = P V_loc
  {
    f32x4 acc[4];
    mm_band<4>(KbT, VlT, w16, chh*64, l16, quad, acc);
#pragma unroll
    for (int n = 0; n < 4; ++n) {
      int col = chh*64 + n*16 + l16;
#pragma unroll
      for (int r = 0; r < 4; ++r)
        dSl[(size_t)bx*8192 + (size_t)(w16 + quad*4 + r)*128 + col] = acc[n][r];
    }
  }
  {
    f32x4 acc[4];
    mm_band<4>(Pm, VlT, w16, chh*64, l16, quad, acc);
#pragma unroll
    for (int n = 0; n < 4; ++n) {
      int col = chh*64 + n*16 + l16;
#pragma unroll
      for (int r = 0; r < 4; ++r)
        obuf[(size_t)(t0 + w16 + quad*4 + r)*2048 + h*128 + col] = acc[n][r];
    }
  }
}

// ---------------- MFMA sequential recurrence (2-deep register prefetch) ----------------
// EF/dSl prefetch distance raised to TWO iterations: prologue issues chunks 0 and 1;
// iteration c consumes set (c&1) and, after the MFMAs have read those registers,
// reissues the SAME named set with chunk c+2. Issue-to-use distance ~2 iteration
// bodies (>HBM 900cy), so the compiler-inserted vmcnt wait is satisfied on arrival.
#define SEQ_LOAD(Cn, EHx, ELx, FFx, DSx)                                        \
  {                                                                             \
    const bf16* base_ = EF + (size_t)((Cn)*16 + h)*13824 + arow;                \
    _Pragma("unroll")                                                           \
    for (int kt = 0; kt < 2; ++kt) {                                            \
      EHx[kt] = *(const bf16x8*)(base_ + kt*32);                                \
      ELx[kt] = *(const bf16x8*)(base_ + 4608 + kt*32);                         \
      FFx[kt] = *(const bf16x8*)(base_ + 9216 + kt*32);                         \
    }                                                                           \
    const float* db_ = dSl + (size_t)((Cn)*16 + h)*8192 + drow;                 \
    _Pragma("unroll")                                                           \
    for (int nt = 0; nt < 2; ++nt)                                              \
      _Pragma("unroll")                                                         \
      for (int r = 0; r < 4; ++r)                                               \
        DSx[nt*4+r] = db_[(size_t)r*128 + nt*16];                               \
  }

#define SEQ_STEP2(Cc, EHc, ELc, FFc, DSc, SRC, DST)                             \
  {                                                                             \
    bf16x8 bh[2][2], bl[2][2];                                                  \
    _Pragma("unroll")                                                           \
    for (int nt = 0; nt < 2; ++nt)                                              \
      _Pragma("unroll")                                                         \
      for (int kt = 0; kt < 2; ++kt) {                                          \
        bh[nt][kt] = *(const bf16x8*)(&Sthi[SRC][(nt*16 + l16)*S72 + kt*32 + quad*8]); \
        bl[nt][kt] = *(const bf16x8*)(&Stlo[SRC][(nt*16 + l16)*S72 + kt*32 + quad*8]); \
      }                                                                         \
    f32x4 a1[2], a2[2], a3[2], o1[2], o2[2];                                    \
    _Pragma("unroll")                                                           \
    for (int nt = 0; nt < 2; ++nt)                                              \
      _Pragma("unroll")                                                         \
      for (int r = 0; r < 4; ++r) {                                             \
        a1[nt][r] = DSc[nt*4+r];                                                \
        a2[nt][r] = 0.f; a3[nt][r] = 0.f; o1[nt][r] = 0.f; o2[nt][r] = 0.f;     \
      }                                                                         \
    _Pragma("unroll")                                                           \
    for (int kt = 0; kt < 2; ++kt)                                              \
      _Pragma("unroll")                                                         \
      for (int nt = 0; nt < 2; ++nt) {                                          \
        a1[nt] = __builtin_amdgcn_mfma_f32_16x16x32_bf16(EHc[kt], bh[nt][kt], a1[nt], 0, 0, 0); \
        a2[nt] = __builtin_amdgcn_mfma_f32_16x16x32_bf16(EHc[kt], bl[nt][kt], a2[nt], 0, 0, 0); \
        a3[nt] = __builtin_amdgcn_mfma_f32_16x16x32_bf16(ELc[kt], bh[nt][kt], a3[nt], 0, 0, 0); \
        o1[nt] = __builtin_amdgcn_mfma_f32_16x16x32_bf16(FFc[kt], bh[nt][kt], o1[nt], 0, 0, 0); \
        o2[nt] = __builtin_amdgcn_mfma_f32_16x16x32_bf16(FFc[kt], bl[nt][kt], o2[nt], 0, 0, 0); \
      }                                                                         \
    /* reload the just-consumed register set with chunk c+2 (2-deep pipeline) */ \
    if ((Cc) + 2 < 32) SEQ_LOAD((Cc) + 2, EHc, ELc, FFc, DSc);                  \
    {                                                                           \
      int t0c = (Cc)*64;                                                        \
      _Pragma("unroll")                                                         \
      for (int nt = 0; nt < 2; ++nt)                                            \
        _Pragma("unroll")                                                       \
        for (int r = 0; r < 4; ++r)                                             \
          osb[(size_t)(t0c + mb + quad*4 + r)*2048 + h*128 + dq*32 + nt*16 + l16] \
            = o1[nt][r] + o2[nt][r];                                            \
    }                                                                           \
    _Pragma("unroll")                                                           \
    for (int nt = 0; nt < 2; ++nt) {                                            \
      bf16x4v hv, lv;                                                           \
      _Pragma("unroll")                                                         \
      for (int r = 0; r < 4; ++r) {                                             \
        float v = a1[nt][r] + a2[nt][r] + a3[nt][r];                            \
        bf16 hb = (bf16)v;                                                      \
        hv[r] = hb;                                                             \
        lv[r] = (bf16)(v - (float)hb);                                          \
      }                                                                         \
      *(bf16x4v*)(&Sthi[DST][(nt*16 + l16)*S72 + mb + quad*4]) = hv;            \
      *(bf16x4v*)(&Stlo[DST][(nt*16 + l16)*S72 + mb + quad*4]) = lv;            \
    }                                                                           \
    asm volatile("s_waitcnt lgkmcnt(0)" ::: "memory");                          \
    __builtin_amdgcn_s_barrier();                                               \
  }

__global__ __launch_bounds__(256) void k_seq(const bf16* __restrict__ EF,
    const float* __restrict__ dSl, float* __restrict__ osb) {
  const int bid = blockIdx.x;
  const int h = (bid & 7) + 8*((bid >> 3) & 1);
  const int dq = bid >> 4;
  const int tid = threadIdx.x, wave = tid >> 6, lane = tid & 63;
  const int l16 = lane & 15, quad = lane >> 4;
  const int mb = wave * 16;
  __shared__ bf16 Sthi[2][32*S72], Stlo[2][32*S72];
  for (int i = tid; i < 2304; i += 256) { Sthi[0][i] = (bf16)0.f; Stlo[0][i] = (bf16)0.f; }

  const size_t arow = (size_t)(mb + l16)*S72 + quad*8;
  const size_t drow = (size_t)dq*32 + (size_t)(mb + quad*4)*128 + l16;

  bf16x8 ehA[2], elA[2], ffA[2], ehB[2], elB[2], ffB[2];
  float dsA[8], dsB[8];

  SEQ_LOAD(0, ehA, elA, ffA, dsA);
  SEQ_LOAD(1, ehB, elB, ffB, dsB);
  asm volatile("s_waitcnt lgkmcnt(0)" ::: "memory");
  __builtin_amdgcn_s_barrier();

#pragma unroll 1
  for (int c = 0; c < 32; c += 2) {
    SEQ_STEP2(c,     ehA, elA, ffA, dsA, 0, 1);
    SEQ_STEP2(c + 1, ehB, elB, ffB, dsB, 1, 0);
  }
}

// ---------------- gated RMSNorm on o = O_loc + O_s, write bf16 ----------------
__global__ __launch_bounds__(256) void k_gatenorm(const float* __restrict__ o,
    const float* __restrict__ os, const bf16* __restrict__ gpre,
    const float* __restrict__ onw, bf16* __restrict__ og) {
  int t = blockIdx.x, wave = threadIdx.x >> 6, lane = threadIdx.x & 63;
  float2 nw = *(const float2*)(onw + lane*2);
#pragma unroll
  for (int hi = 0; hi < 4; ++hi) {
    int hh = wave*4 + hi;
    size_t base = (size_t)t*2048 + hh*128 + lane*2;
    float2 o2 = *(const float2*)(o + base);
    float2 s2 = *(const float2*)(os + base);
    o2.x += s2.x; o2.y += s2.y;
    float ss = wredsum(o2.x*o2.x + o2.y*o2.y);
    float rs = rsqrtf(ss * (1.f/128.f) + 1e-5f);
    bf16x2v g2 = *(const bf16x2v*)(gpre + base);
    float g0 = (float)g2[0], g1 = (float)g2[1];
    float r0 = o2.x * rs * nw.x * (g0 * sigmoidf_(g0));
    float r1 = o2.y * rs * nw.y * (g1 * sigmoidf_(g1));
    bf16x2v b; b[0] = (bf16)r0; b[1] = (bf16)r1;
    *(bf16x2v*)(og + base) = b;
  }
}

extern "C" void kernel_launch(void* const* d_in, const int* in_sizes, int n_in,
                              void* d_out, int out_size, void* d_ws, size_t ws_size,
                              hipStream_t stream) {
  const float* hs   = (const float*)d_in[0];
  const float* nw   = (const float*)d_in[1];
  const float* qw   = (const float*)d_in[2];
  const float* kw   = (const float*)d_in[3];
  const float* vw   = (const float*)d_in[4];
  const float* aw   = (const float*)d_in[5];
  const float* bw   = (const float*)d_in[6];
  const float* gw   = (const float*)d_in[7];
  const float* dtb  = (const float*)d_in[8];
  const float* alog = (const float*)d_in[9];
  const float* cqw  = (const float*)d_in[10];
  const float* ckw  = (const float*)d_in[11];
  const float* cvw  = (const float*)d_in[12];
  const float* onw  = (const float*)d_in[13];
  const float* opw  = (const float*)d_in[14];
  const float* ow   = (const float*)d_in[15];
  float* out = (float*)d_out;

  char* p = (char*)d_ws;
  auto alloc = [&](size_t bytes) { char* r = p; p += (bytes + 255) & ~255ull; return r; };
  bf16*  xb    = (bf16*) alloc((size_t)2048*1024*2);   // } dSl aliases xb..gwb (16 MB,
  bf16*  qwb   = (bf16*) alloc((size_t)1024*1024*2);   // } all dead after k_gemm_proj)
  bf16*  kwb   = (bf16*) alloc((size_t)1024*1024*2);
  bf16*  vwb   = (bf16*) alloc((size_t)2048*1024*2);
  bf16*  gwb   = (bf16*) alloc((size_t)2048*1024*2);
  bf16*  opwb  = (bf16*) alloc((size_t)1024*2048*2);
  bf16*  owb   = (bf16*) alloc((size_t)1024*1024*2);
  bf16*  qpre  = (bf16*) alloc((size_t)2048*1024*2);
  bf16*  kpre  = (bf16*) alloc((size_t)2048*1024*2);
  bf16*  vpre  = (bf16*) alloc((size_t)2048*2048*2);
  bf16*  gpre  = (bf16*) alloc((size_t)2048*2048*2);
  float* graw  = (float*)alloc((size_t)2048*16*4);
  float* btb   = (float*)alloc((size_t)2048*16*4);
  float* ob    = (float*)alloc((size_t)2048*2048*4);
  bf16*  ogb   = (bf16*) alloc((size_t)2048*2048*2);
  bf16*  h1b   = (bf16*) alloc((size_t)2048*1024*2);
  bf16*  EF    = (bf16*) alloc((size_t)512*13824*2);
  float* osb   = (float*)alloc((size_t)512*8192*4);
  float* dSl   = (float*)xb;   // 16 MB over xb..gwb (dead after k_gemm_proj)

  k_pre<<<2048+4608, 256, 0, stream>>>(hs, nw, aw, bw, dtb, alog, xb, graw, btb,
                                       qw, kw, vw, gw, opw, ow,
                                       qwb, kwb, vwb, gwb, opwb, owb);
  k_gemm_proj<<<dim3(24,8,1), 512, 0, stream>>>(xb, qwb, kwb, vwb, gwb, qpre, kpre, vpre, gpre);
  k_prepass<<<512, 512, 0, stream>>>(qpre, kpre, vpre, cqw, ckw, cvw, graw, btb, EF, dSl, ob);
  k_seq<<<64, 256, 0, stream>>>(EF, dSl, osb);
  k_gatenorm<<<2048, 256, 0, stream>>>(ob, osb, gpre, onw, ogb);
  k_gemm_bt64<bf16><<<dim3(16,16,1), 256, 0, stream>>>(ogb, opwb, h1b, 1024, 2048);
  k_gemm_bt64<float><<<dim3(16,16,1), 256, 0, stream>>>(h1b, owb, out, 1024, 1024);
}